// Round 8
// baseline (545.294 us; speedup 1.0000x reference)
//
#include <hip/hip_runtime.h>
#include <cstddef>

typedef unsigned short u16;
typedef unsigned int   u32;
typedef short bf16x8 __attribute__((ext_vector_type(8)));
typedef float f32x4 __attribute__((ext_vector_type(4)));

#define B_ROWS 16384
#define D_FEAT 512
#define NB_    8

static __device__ __forceinline__ float b2f(u16 h) {
    union { u32 u; float f; } v; v.u = ((u32)h) << 16; return v.f;
}
static __device__ __forceinline__ u16 f2b(float f) {
    union { float f; u32 u; } v; v.f = f;
    u32 r = (v.u + 0x7fffu + ((v.u >> 16) & 1u)) >> 16;
    return (u16)r;
}
static __device__ __forceinline__ float ldf(const void* p, size_t i, int isb) {
    return isb ? b2f(((const u16*)p)[i]) : ((const float*)p)[i];
}
static __device__ __forceinline__ u16 cvtb(const void* p, size_t i, int isb) {
    return isb ? ((const u16*)p)[i] : f2b(((const float*)p)[i]);
}
static __device__ __forceinline__ float wred_sum(float v) {
    #pragma unroll
    for (int off = 32; off > 0; off >>= 1) v += __shfl_xor(v, off);
    return v;
}
static __device__ __forceinline__ float wred_max(float v) {
    #pragma unroll
    for (int off = 32; off > 0; off >>= 1) v = fmaxf(v, __shfl_xor(v, off));
    return v;
}

// ---------------- dtype detector ----------------
__global__ void detect_k(const void* __restrict__ x, int* __restrict__ flag) {
    int lane = threadIdx.x & 63;
    u16 h = ((const u16*)x)[lane * 2];
    int e = (h >> 7) & 0xff;
    int plaus = (e >= 110 && e <= 132) ? 1 : 0;
    unsigned long long m = __ballot(plaus != 0);
    if (lane == 0) *flag = (__popcll(m) >= 32) ? 1 : 0;
}

// ---------------- breakpoints (TRANSPOSED: bpsT[k][d]) ----------------
__global__ void prep_bps_k(const void* __restrict__ bp_min, const void* __restrict__ bp_dr,
                           float* __restrict__ bpsT, const int* __restrict__ flag) {
    const int isb = *flag;
    int d = threadIdx.x;
    if (d < D_FEAT) {
        float bp = ldf(bp_min, d, isb);
        #pragma unroll
        for (int k = 0; k < NB_; ++k) {
            float x = ldf(bp_dr, d * NB_ + k, isb);
            bp += fmaxf(x, 0.f) + log1pf(expf(-fabsf(x)));
            bpsT[k * 512 + d] = bp;
        }
    }
}

// ---------------- embedding tables TRANSPOSED f32 ----------------
__global__ void prep_embT_k(const void* __restrict__ bwt, const void* __restrict__ bbias,
                            float* __restrict__ bwT, float* __restrict__ bbT,
                            const int* __restrict__ flag) {
    const int isb = *flag;
    int t = blockIdx.x * 256 + threadIdx.x;
    if (t < 512 * 36) {
        int d = t / 36, j = t % 36;
        bwT[j * 512 + d] = ldf(bwt, t, isb);
    }
    if (t < 2048) {
        int d = t >> 2, e = t & 3;
        bbT[e * 512 + d] = ldf(bbias, t, isb);
    }
}

// Wbuf element offsets — ALL K-MAJOR: Bt[n][k], K padded to x64
#define WO_PROJ 0
#define WO_GW1  1048576
#define WO_GW2  1179648
#define WO_BW1  1310720
#define WO_BW2  1441792
#define WO_SW1  1507328
#define WO_SPW  1540096
#define WO_CFW  1581056
#define W_TOTAL 1622016

// K-major repack: dst[matrix + n*ldk + k] = src[k*N + n] (zero-pad k/n overflow)
__global__ void repackW_k(const void* pW, const void* gW1, const void* gW2,
                          const void* bW1, const void* bW2, const void* sW1,
                          const void* spW, const void* cfW,
                          u16* __restrict__ dst, const int* __restrict__ flag) {
    const int isb = *flag;
    size_t t = (size_t)blockIdx.x * 256 + threadIdx.x;
    if (t >= W_TOTAL) return;
    u16 v;
    if (t < WO_GW1) {                       // proj [512 n][2048 k] <- [2048][512]
        size_t i = t; int n = (int)(i >> 11), k = (int)(i & 2047);
        v = cvtb(pW, (size_t)k * 512 + n, isb);
    } else if (t < WO_GW2) {                // gW1 [256][512] <- [512][256]
        size_t i = t - WO_GW1; int n = (int)(i >> 9), k = (int)(i & 511);
        v = cvtb(gW1, (size_t)k * 256 + n, isb);
    } else if (t < WO_BW1) {                // gW2 [512][256] <- [256][512]
        size_t i = t - WO_GW2; int n = (int)(i >> 8), k = (int)(i & 255);
        v = cvtb(gW2, (size_t)k * 512 + n, isb);
    } else if (t < WO_BW2) {                // bW1 [256][512] <- [512][256]
        size_t i = t - WO_BW1; int n = (int)(i >> 9), k = (int)(i & 511);
        v = cvtb(bW1, (size_t)k * 256 + n, isb);
    } else if (t < WO_SW1) {                // bW2 [256][256] <- [256][256]
        size_t i = t - WO_BW2; int n = (int)(i >> 8), k = (int)(i & 255);
        v = cvtb(bW2, (size_t)k * 256 + n, isb);
    } else if (t < WO_SPW) {                // sW1 [128][256] <- [256][128]
        size_t i = t - WO_SW1; int n = (int)(i >> 8), k = (int)(i & 255);
        v = cvtb(sW1, (size_t)k * 128 + n, isb);
    } else if (t < WO_CFW) {                // spW [128 n][320 k] <- [272][68]
        size_t i = t - WO_SPW; int n = (int)(i / 320), k = (int)(i % 320);
        v = (n < 68 && k < 272) ? cvtb(spW, (size_t)k * 68 + n, isb) : (u16)0;
    } else {                                // cfW [128 n][320 k] <- [278][69]
        size_t i = t - WO_CFW; int n = (int)(i / 320), k = (int)(i % 320);
        v = (n < 69 && k < 278) ? cvtb(cfW, (size_t)k * 69 + n, isb) : (u16)0;
    }
    dst[t] = v;
}

__global__ void prep_bias_k(const void* pb, const void* g1, const void* g2,
                            const void* b1, const void* b2, const void* sb,
                            const void* spb, const void* cfb,
                            float* __restrict__ out, const int* __restrict__ flag) {
    const int isb = *flag;
    int t = blockIdx.x * 256 + threadIdx.x;
    if      (t < 512)  out[t] = ldf(pb, t, isb);
    else if (t < 768)  out[t] = ldf(g1, t - 512, isb);
    else if (t < 1280) out[t] = ldf(g2, t - 768, isb);
    else if (t < 1536) out[t] = ldf(b1, t - 1280, isb);
    else if (t < 1792) out[t] = ldf(b2, t - 1536, isb);
    else if (t < 1920) out[t] = ldf(sb, t - 1792, isb);
    else if (t < 2048) { int c = t - 1920; out[t] = (c < 68) ? ldf(spb, c, isb) : 0.f; }
    else if (t < 2176) { int c = t - 2048; out[t] = (c < 69) ? ldf(cfb, c, isb) : 0.f; }
}

// ---------------- embedding (half-batch), coalesced ----------------
__global__ __launch_bounds__(256) void emb_k(
    const void* __restrict__ xnum, const float* __restrict__ bwT,
    const float* __restrict__ bbT, const float* __restrict__ bpsT,
    u16* __restrict__ emb, const int* __restrict__ flag, int rowoff)
{
    const int isb = *flag;
    size_t t = (size_t)blockIdx.x * 256 + threadIdx.x;
    int d = (int)(t & 511);
    float x = ldf(xnum, (size_t)rowoff * D_FEAT + t, isb);
    float e0 = bbT[d], e1 = bbT[512 + d], e2 = bbT[1024 + d], e3 = bbT[1536 + d];
    e0 = fmaf(x, bwT[d], e0);
    e1 = fmaf(x, bwT[512 + d], e1);
    e2 = fmaf(x, bwT[1024 + d], e2);
    e3 = fmaf(x, bwT[1536 + d], e3);
    #pragma unroll
    for (int f = 1; f <= 8; ++f) {
        float bv = fmaxf(x - bpsT[(f - 1) * 512 + d], 0.f);
        e0 = fmaf(bv, bwT[(f * 4 + 0) * 512 + d], e0);
        e1 = fmaf(bv, bwT[(f * 4 + 1) * 512 + d], e1);
        e2 = fmaf(bv, bwT[(f * 4 + 2) * 512 + d], e2);
        e3 = fmaf(bv, bwT[(f * 4 + 3) * 512 + d], e3);
    }
    u16 o[4] = { f2b(e0), f2b(e1), f2b(e2), f2b(e3) };
    *(uint2*)&emb[t * 4] = *(const uint2*)o;
}

// ---------------- bf16 MFMA GEMM: 128x128 block, 4 waves 2x2, per-wave 64x64 ----
// B is K-MAJOR: Bt[n][k], leading dim ldk (K zero-padded).
template<int EMODE>
__global__ __launch_bounds__(256) void mgemm_k(
    const u16* __restrict__ A, const u16* __restrict__ Bt,
    const float* __restrict__ bias,
    void* __restrict__ out0, const void* __restrict__ aux0, void* __restrict__ aux1,
    int N, int Kdim, int lda, int ldk, int rowoff, const int* __restrict__ flagp)
{
    __shared__ __align__(16) u16 As[128][72];
    __shared__ __align__(16) u16 Bs[128][72];

    const int isb = (EMODE == 0) ? *flagp : 0;
    const int tid = threadIdx.x;
    const int row0 = blockIdx.x * 128, col0 = blockIdx.y * 128;
    const int w = tid >> 6, lane = tid & 63, q = lane >> 4, mr = lane & 15;
    const int wr = (w >> 1) * 64, wc = (w & 1) * 64;

    f32x4 acc[4][4];
    #pragma unroll
    for (int a = 0; a < 4; ++a)
        #pragma unroll
        for (int b = 0; b < 4; ++b) acc[a][b] = (f32x4){0.f, 0.f, 0.f, 0.f};

    const int sr = tid >> 3, kg = tid & 7;          // staging: 32 rows/pass, 8 k-groups
    const int kok = kg * 8;

    for (int kt = 0; kt < Kdim; kt += 64) {
        const bool kv = (kt + kok) < Kdim;          // 8-aligned guard (Kdim % 8 == 0)
        #pragma unroll
        for (int p = 0; p < 4; ++p) {
            int m = p * 32 + sr;
            uint4 v = make_uint4(0u, 0u, 0u, 0u);
            if (kv) v = *(const uint4*)(A + (size_t)(row0 + m) * lda + kt + kok);
            *(uint4*)&As[m][kok] = v;
        }
        #pragma unroll
        for (int p = 0; p < 4; ++p) {
            int n = p * 32 + sr;
            *(uint4*)&Bs[n][kok] =
                *(const uint4*)(Bt + (size_t)(col0 + n) * ldk + kt + kok);
        }
        __syncthreads();
        #pragma unroll
        for (int ks = 0; ks < 2; ++ks) {
            bf16x8 af[4], bf[4];
            #pragma unroll
            for (int rs = 0; rs < 4; ++rs)
                af[rs] = *(const bf16x8*)&As[wr + rs * 16 + mr][ks * 32 + q * 8];
            #pragma unroll
            for (int nt = 0; nt < 4; ++nt)
                bf[nt] = *(const bf16x8*)&Bs[wc + nt * 16 + mr][ks * 32 + q * 8];
            #pragma unroll
            for (int rs = 0; rs < 4; ++rs)
                #pragma unroll
                for (int nt = 0; nt < 4; ++nt)
                    acc[rs][nt] = __builtin_amdgcn_mfma_f32_16x16x32_bf16(
                        af[rs], bf[nt], acc[rs][nt], 0, 0, 0);
        }
        __syncthreads();
    }

    #pragma unroll
    for (int rs = 0; rs < 4; ++rs) {
        #pragma unroll
        for (int i = 0; i < 4; ++i) {
            size_t gr = (size_t)rowoff + row0 + wr + rs * 16 + q * 4 + i;
            #pragma unroll
            for (int nt = 0; nt < 4; ++nt) {
                int c = col0 + wc + nt * 16 + mr;
                float z = acc[rs][nt][i] + bias[c];
                size_t idx = gr * (size_t)N + c;
                if (EMODE == 0) {
                    ((u16*)out0)[idx] = f2b(ldf(aux0, idx, isb) + 0.1f * z);
                } else if (EMODE == 1) {
                    ((u16*)out0)[idx] = f2b(fmaxf(z, 0.f));
                } else if (EMODE == 2) {
                    float gv = 1.f / (1.f + expf(-z));
                    ((float*)out0)[idx] = gv;
                    ((u16*)aux1)[idx] = f2b(b2f(((const u16*)aux0)[idx]) * gv);
                } else {
                    ((float*)out0)[idx] = fmaxf(z, 0.f);
                }
            }
        }
    }
}

// ---------------- pre_k (unchanged from R7) ----------------
struct PreArgs {
    const u16 *x_in;
    const float *g, *h;
    const void *base_W, *base_b;
    const void *safe_ln_g, *safe_ln_b;
    const void *top_W1, *top_b1, *top_W2, *top_b2;
    const void *spec_ln_g, *spec_ln_b;
    u16 *ln_a, *ln_b;
    float *scal;
    const int *flag;
};

__global__ __launch_bounds__(256, 4) void pre_k(PreArgs P) {
    __shared__ float w_base[256], w_slg[256], w_slb[256], w_t2[256];
    __shared__ float w_plg[272], w_plb[272];
    __shared__ float w_t1[16], w_tb1[16], w_tb2[16];
    const int isb = *P.flag;
    const int tid = threadIdx.x;
    const int wid = tid >> 6;
    const int lane = tid & 63;
    const int row = blockIdx.x * 4 + wid;

    w_base[tid] = ldf(P.base_W, tid, isb);
    w_slg[tid]  = ldf(P.safe_ln_g, tid, isb);
    w_slb[tid]  = ldf(P.safe_ln_b, tid, isb);
    w_t2[tid]   = ldf(P.top_W2, tid, isb);
    if (tid < 272) {
        w_plg[tid] = ldf(P.spec_ln_g, tid, isb);
        w_plb[tid] = ldf(P.spec_ln_b, tid, isb);
    }
    if (tid < 16) {
        w_t1[tid]  = ldf(P.top_W1, tid, isb);
        w_tb1[tid] = ldf(P.top_b1, tid, isb);
        w_tb2[tid] = ldf(P.top_b2, tid, isb);
    }
    __syncthreads();

    float hv[4], gv[8];
    #pragma unroll
    for (int i = 0; i < 4; ++i) hv[i] = P.h[(size_t)row * 256 + lane + 64 * i];
    #pragma unroll
    for (int j = 0; j < 8; ++j) gv[j] = P.g[(size_t)row * 512 + lane + 64 * j];
    const float hsum = hv[0] + hv[1] + hv[2] + hv[3];

    float pb = 0.f;
    #pragma unroll
    for (int i = 0; i < 4; ++i) pb = fmaf(hv[i], w_base[lane + 64 * i], pb);
    const float yb = wred_sum(pb) + ldf(P.base_b, 0, isb);

    float s1 = 0.f, s2 = 0.f, mx = -1e30f;
    #pragma unroll
    for (int j = 0; j < 8; ++j) { s1 += gv[j]; s2 = fmaf(gv[j], gv[j], s2); mx = fmaxf(mx, gv[j]); }
    s1 = wred_sum(s1); s2 = wred_sum(s2); mx = wred_max(mx);
    const float gmean = s1 * (1.f / 512.f);
    const float gstd = sqrtf(fmaxf(s2 * (1.f / 512.f) - gmean * gmean, 0.f));

    const float hm = wred_sum(hsum) * (1.f / 256.f);
    float pv = 0.f;
    #pragma unroll
    for (int i = 0; i < 4; ++i) { float d = hv[i] - hm; pv = fmaf(d, d, pv); }
    const float hrstd = rsqrtf(wred_sum(pv) * (1.f / 256.f) + 1e-5f);
    #pragma unroll
    for (int i = 0; i < 4; ++i) {
        int k = lane + 64 * i;
        P.ln_a[(size_t)row * 288 + k] = f2b((hv[i] - hm) * hrstd * w_slg[k] + w_slb[k]);
    }

    float tg[8];
    #pragma unroll
    for (int j = 0; j < 8; ++j) tg[j] = gv[j];
    float myv = 0.f, sumtv = 0.f; int myi = 0;
    for (int r8 = 0; r8 < 8; ++r8) {
        float bv = -1e30f; int bi = 0x7fffffff;
        #pragma unroll
        for (int j = 0; j < 8; ++j) {
            int idx = lane + 64 * j;
            if (tg[j] > bv || (tg[j] == bv && idx < bi)) { bv = tg[j]; bi = idx; }
        }
        #pragma unroll
        for (int off = 32; off > 0; off >>= 1) {
            float ov = __shfl_xor(bv, off);
            int oi = __shfl_xor(bi, off);
            if (ov > bv || (ov == bv && oi < bi)) { bv = ov; bi = oi; }
        }
        sumtv += bv;
        if (lane == r8) { myv = bv; myi = bi; }
        if ((bi & 63) == lane) {
            int oj = bi >> 6;
            #pragma unroll
            for (int j = 0; j < 8; ++j) if (j == oj) tg[j] = -1e30f;
        }
    }

    float th[16];
    #pragma unroll
    for (int s = 0; s < 16; ++s) th[s] = 0.f;
    if (lane < 8) {
        float xi = b2f(P.x_in[(size_t)row * 512 + myi]);
        float xw = xi * (myv / (sumtv + 1e-6f));
        #pragma unroll
        for (int s = 0; s < 16; ++s)
            th[s] = fmaxf(fmaf(xw, w_t1[s], w_tb1[s]), 0.f);
    }
    #pragma unroll
    for (int s = 0; s < 16; ++s) {
        th[s] += __shfl_xor(th[s], 1);
        th[s] += __shfl_xor(th[s], 2);
        th[s] += __shfl_xor(th[s], 4);
    }
    const int tt = lane & 15;
    float zacc = w_tb2[tt];
    #pragma unroll
    for (int s = 0; s < 16; ++s)
        zacc = fmaf(__shfl(th[s], 0), w_t2[s * 16 + tt], zacc);
    const float ztl = zacc * 0.125f;

    float ps = hsum + ((lane < 16) ? ztl : 0.f);
    const float sm = wred_sum(ps) * (1.f / 272.f);
    float pv2 = 0.f;
    #pragma unroll
    for (int i = 0; i < 4; ++i) { float d = hv[i] - sm; pv2 = fmaf(d, d, pv2); }
    if (lane < 16) { float d = ztl - sm; pv2 = fmaf(d, d, pv2); }
    const float srstd = rsqrtf(wred_sum(pv2) * (1.f / 272.f) + 1e-5f);
    #pragma unroll
    for (int i = 0; i < 4; ++i) {
        int k = lane + 64 * i;
        P.ln_b[(size_t)row * 288 + k] = f2b((hv[i] - sm) * srstd * w_plg[k] + w_plb[k]);
    }
    if (lane < 16) {
        int k = 256 + lane;
        P.ln_b[(size_t)row * 288 + k] = f2b((ztl - sm) * srstd * w_plg[k] + w_plb[k]);
    } else if (lane < 32) {
        P.ln_b[(size_t)row * 288 + 256 + lane] = 0;
    }

    float* sc = P.scal + (size_t)row * 32;
    if (lane < 16) sc[8 + lane] = ztl;
    if (lane == 0) { sc[0] = yb; sc[1] = gmean; sc[2] = mx; sc[3] = gstd; }
}

// ---------------- mid_k (unchanged from R7) ----------------
struct MidArgs {
    const float *h, *scal_in;
    const u16 *sh, *sph;
    const void *safe_W2, *safe_b2, *spec_W2, *spec_b2;
    const void *conf_ln_g, *conf_ln_b;
    u16 *ln_c;
    float *scal;
    const int *flag;
};

__global__ __launch_bounds__(256, 4) void mid_k(MidArgs P) {
    __shared__ float w_clg[278], w_clb[278], w_sw2[128], w_spw2[68];
    const int isb = *P.flag;
    const int tid = threadIdx.x;
    const int wid = tid >> 6;
    const int lane = tid & 63;
    const int row = blockIdx.x * 4 + wid;

    if (tid < 278) { w_clg[tid] = ldf(P.conf_ln_g, tid, isb); w_clb[tid] = ldf(P.conf_ln_b, tid, isb); }
    if (tid < 128) w_sw2[tid]  = ldf(P.safe_W2, tid, isb);
    if (tid < 68)  w_spw2[tid] = ldf(P.spec_W2, tid, isb);
    __syncthreads();

    float s0 = b2f(P.sh[(size_t)row * 128 + lane]);
    float s1 = b2f(P.sh[(size_t)row * 128 + 64 + lane]);
    float psafe = s0 * w_sw2[lane] + s1 * w_sw2[64 + lane];
    const float dsafe = wred_sum(psafe) + ldf(P.safe_b2, 0, isb);

    float p0 = b2f(P.sph[(size_t)row * 128 + lane]) * ((lane < 68) ? w_spw2[lane] : 0.f);
    if (lane < 4) p0 += b2f(P.sph[(size_t)row * 128 + 64 + lane]) * w_spw2[64 + lane];
    const float dspec = wred_sum(p0) + ldf(P.spec_b2, 0, isb);

    const float* sc = P.scal_in + (size_t)row * 32;
    const float yb = sc[0], gmean = sc[1], mx = sc[2], gstd = sc[3];
    const float ztl = (lane < 16) ? sc[8 + lane] : 0.f;

    float hv[4];
    #pragma unroll
    for (int i = 0; i < 4; ++i) hv[i] = P.h[(size_t)row * 256 + lane + 64 * i];
    const float hsum = hv[0] + hv[1] + hv[2] + hv[3];

    const float ads = fabsf(dsafe), adsp = fabsf(dspec);
    float pc = hsum + ((lane < 16) ? ztl : 0.f)
             + ((lane == 0) ? (yb + gmean + mx + gstd + ads + adsp) : 0.f);
    const float cm = wred_sum(pc) * (1.f / 278.f);
    float pv3 = 0.f;
    #pragma unroll
    for (int i = 0; i < 4; ++i) { float d = hv[i] - cm; pv3 = fmaf(d, d, pv3); }
    if (lane < 16) { float d = ztl - cm; pv3 = fmaf(d, d, pv3); }
    if (lane == 0) {
        float vals[6] = { yb, gmean, mx, gstd, ads, adsp };
        #pragma unroll
        for (int q = 0; q < 6; ++q) { float d = vals[q] - cm; pv3 = fmaf(d, d, pv3); }
    }
    const float crstd = rsqrtf(wred_sum(pv3) * (1.f / 278.f) + 1e-5f);

    u16* la = P.ln_c + (size_t)row * 288;
    #pragma unroll
    for (int i = 0; i < 4; ++i) {
        int k = lane + 64 * i;
        la[k] = f2b((hv[i] - cm) * crstd * w_clg[k] + w_clb[k]);
    }
    if (lane < 16) {
        int k = 260 + lane;
        la[k] = f2b((ztl - cm) * crstd * w_clg[k] + w_clb[k]);
    } else if (lane >= 18 && lane < 28) {
        la[260 + lane] = 0;
    }
    if (lane == 0) {
        float vals[6] = { yb, gmean, mx, gstd, ads, adsp };
        int idxs[6] = { 256, 257, 258, 259, 276, 277 };
        #pragma unroll
        for (int q = 0; q < 6; ++q) {
            int k = idxs[q];
            la[k] = f2b((vals[q] - cm) * crstd * w_clg[k] + w_clb[k]);
        }
        float* so = P.scal + (size_t)row * 32;
        so[4] = dsafe; so[5] = dspec;
    }
}

// ---------------- post_k (unchanged from R7) ----------------
__global__ __launch_bounds__(256, 4) void post_k(
    const u16* __restrict__ ch, const float* __restrict__ scal,
    const void* __restrict__ conf_W2, const void* __restrict__ conf_b2,
    void* __restrict__ out, const int* __restrict__ flag)
{
    __shared__ float w_cw2[69];
    const int isb = *flag;
    const int tid = threadIdx.x;
    const int wid = tid >> 6;
    const int lane = tid & 63;
    const int row = blockIdx.x * 4 + wid;

    if (tid < 69) w_cw2[tid] = ldf(conf_W2, tid, isb);
    __syncthreads();

    float c0 = b2f(ch[(size_t)row * 128 + lane]) * ((lane < 69) ? w_cw2[lane] : 0.f);
    if (lane < 5) c0 += b2f(ch[(size_t)row * 128 + 64 + lane]) * w_cw2[64 + lane];
    const float zlin = wred_sum(c0) + ldf(conf_b2, 0, isb);
    const float gamma = 1.f / (1.f + expf(-zlin));
    if (lane == 0) {
        const float* sc = scal + (size_t)row * 32;
        float v = sc[0] + sc[4] + gamma * sc[5];
        if (isb) ((u16*)out)[row] = f2b(v);
        else     ((float*)out)[row] = v;
    }
}

extern "C" void kernel_launch(void* const* d_in, const int* in_sizes, int n_in,
                              void* d_out, int out_size, void* d_ws, size_t ws_size,
                              hipStream_t stream) {
    (void)in_sizes; (void)n_in; (void)out_size; (void)ws_size;
    const void* x_num  = d_in[0];
    const void* bas_W  = d_in[1];
    const void* bas_b  = d_in[2];
    const void* bp_min = d_in[3];
    const void* bp_dr  = d_in[4];

    char* p = (char*)d_ws;
    auto alloc = [&](size_t bytes) { char* r = p; p += (bytes + 15) & ~(size_t)15; return r; };

    // total footprint ~133.4 MB (< 140.8 MB proven-safe in R3)
    int*   flag    = (int*)alloc(16);
    float* bpsT    = (float*)alloc(8 * 512 * 4);
    float* bwT     = (float*)alloc(36 * 512 * 4);
    float* bbT     = (float*)alloc(4 * 512 * 4);
    float* biasbuf = (float*)alloc(2176 * 4);
    u16*   Wbuf    = (u16*)alloc((size_t)W_TOTAL * 2);
    u16*   ebuf    = (u16*)alloc((size_t)(B_ROWS / 2) * 2048 * 2);  // 33.55 MB; later g f32
    u16*   x_in    = (u16*)alloc((size_t)B_ROWS * 512 * 2);
    u16*   hid1    = (u16*)alloc((size_t)B_ROWS * 256 * 2);         // later chh
    float* hbuf    = (float*)alloc((size_t)B_ROWS * 256 * 4);
    u16*   ln_a    = (u16*)alloc((size_t)B_ROWS * 288 * 2);
    u16*   ln_b    = (u16*)alloc((size_t)B_ROWS * 288 * 2);
    float* scal    = (float*)alloc((size_t)B_ROWS * 32 * 4);
    u16*   sh      = (u16*)alloc((size_t)B_ROWS * 128 * 2);
    u16*   sph     = (u16*)alloc((size_t)B_ROWS * 128 * 2);
    u16*   xg      = (u16*)alloc((size_t)B_ROWS * 512 * 2);
    u16*   hid2    = (u16*)alloc((size_t)B_ROWS * 256 * 2);

    float* g   = (float*)ebuf;
    u16*   chh = hid1;

    detect_k<<<1, 64, 0, stream>>>(x_num, flag);
    prep_bps_k<<<1, 512, 0, stream>>>(bp_min, bp_dr, bpsT, flag);
    prep_embT_k<<<72, 256, 0, stream>>>(bas_W, bas_b, bwT, bbT, flag);
    repackW_k<<<(W_TOTAL + 255) / 256, 256, 0, stream>>>(
        d_in[5], d_in[7], d_in[9], d_in[11], d_in[13], d_in[19], d_in[29], d_in[35],
        Wbuf, flag);
    prep_bias_k<<<9, 256, 0, stream>>>(
        d_in[6], d_in[8], d_in[10], d_in[12], d_in[14], d_in[20], d_in[30], d_in[36],
        biasbuf, flag);

    const int HR = B_ROWS / 2;  // 8192
    for (int half = 0; half < 2; ++half) {
        int rowoff = half * HR;
        emb_k<<<(HR * D_FEAT) / 256, 256, 0, stream>>>(
            x_num, bwT, bbT, bpsT, ebuf, flag, rowoff);
        mgemm_k<0><<<dim3(HR / 128, 4), 256, 0, stream>>>(
            ebuf, Wbuf + WO_PROJ, biasbuf + 0, x_in, x_num, nullptr,
            512, 2048, 2048, 2048, rowoff, flag);
    }

    mgemm_k<1><<<dim3(B_ROWS / 128, 2), 256, 0, stream>>>(
        x_in, Wbuf + WO_GW1, biasbuf + 512, hid1, nullptr, nullptr,
        256, 512, 512, 512, 0, flag);
    mgemm_k<2><<<dim3(B_ROWS / 128, 4), 256, 0, stream>>>(
        hid1, Wbuf + WO_GW2, biasbuf + 768, g, x_in, xg,
        512, 256, 256, 256, 0, flag);
    mgemm_k<1><<<dim3(B_ROWS / 128, 2), 256, 0, stream>>>(
        xg, Wbuf + WO_BW1, biasbuf + 1280, hid2, nullptr, nullptr,
        256, 512, 512, 512, 0, flag);
    mgemm_k<3><<<dim3(B_ROWS / 128, 2), 256, 0, stream>>>(
        hid2, Wbuf + WO_BW2, biasbuf + 1536, hbuf, nullptr, nullptr,
        256, 256, 256, 256, 0, flag);

    {
        PreArgs pa;
        pa.x_in = x_in; pa.g = g; pa.h = hbuf;
        pa.base_W = d_in[15]; pa.base_b = d_in[16];
        pa.safe_ln_g = d_in[17]; pa.safe_ln_b = d_in[18];
        pa.top_W1 = d_in[23]; pa.top_b1 = d_in[24];
        pa.top_W2 = d_in[25]; pa.top_b2 = d_in[26];
        pa.spec_ln_g = d_in[27]; pa.spec_ln_b = d_in[28];
        pa.ln_a = ln_a; pa.ln_b = ln_b; pa.scal = scal; pa.flag = flag;
        pre_k<<<B_ROWS / 4, 256, 0, stream>>>(pa);
    }

    mgemm_k<1><<<dim3(B_ROWS / 128, 1), 256, 0, stream>>>(
        ln_a, Wbuf + WO_SW1, biasbuf + 1792, sh, nullptr, nullptr,
        128, 256, 288, 256, 0, flag);
    mgemm_k<1><<<dim3(B_ROWS / 128, 1), 256, 0, stream>>>(
        ln_b, Wbuf + WO_SPW, biasbuf + 1920, sph, nullptr, nullptr,
        128, 288, 288, 320, 0, flag);

    {
        MidArgs ma;
        ma.h = hbuf; ma.scal_in = scal; ma.sh = sh; ma.sph = sph;
        ma.safe_W2 = d_in[21]; ma.safe_b2 = d_in[22];
        ma.spec_W2 = d_in[31]; ma.spec_b2 = d_in[32];
        ma.conf_ln_g = d_in[33]; ma.conf_ln_b = d_in[34];
        ma.ln_c = ln_a; ma.scal = scal; ma.flag = flag;
        mid_k<<<B_ROWS / 4, 256, 0, stream>>>(ma);
    }

    mgemm_k<1><<<dim3(B_ROWS / 128, 1), 256, 0, stream>>>(
        ln_a, Wbuf + WO_CFW, biasbuf + 2048, chh, nullptr, nullptr,
        128, 288, 288, 320, 0, flag);

    post_k<<<B_ROWS / 4, 256, 0, stream>>>(chh, scal, d_in[37], d_in[38], d_out, flag);
}

// Round 9
// 504.301 us; speedup vs baseline: 1.0813x; 1.0813x over previous
//
#include <hip/hip_runtime.h>
#include <cstddef>

typedef unsigned short u16;
typedef unsigned int   u32;
typedef short bf16x8 __attribute__((ext_vector_type(8)));
typedef float f32x4 __attribute__((ext_vector_type(4)));

#define B_ROWS 16384
#define D_FEAT 512
#define NB_    8

static __device__ __forceinline__ float b2f(u16 h) {
    union { u32 u; float f; } v; v.u = ((u32)h) << 16; return v.f;
}
static __device__ __forceinline__ u16 f2b(float f) {
    union { float f; u32 u; } v; v.f = f;
    u32 r = (v.u + 0x7fffu + ((v.u >> 16) & 1u)) >> 16;
    return (u16)r;
}
static __device__ __forceinline__ float ldf(const void* p, size_t i, int isb) {
    return isb ? b2f(((const u16*)p)[i]) : ((const float*)p)[i];
}
static __device__ __forceinline__ u16 cvtb(const void* p, size_t i, int isb) {
    return isb ? ((const u16*)p)[i] : f2b(((const float*)p)[i]);
}
static __device__ __forceinline__ float wred_sum(float v) {
    #pragma unroll
    for (int off = 32; off > 0; off >>= 1) v += __shfl_xor(v, off);
    return v;
}
static __device__ __forceinline__ float wred_max(float v) {
    #pragma unroll
    for (int off = 32; off > 0; off >>= 1) v = fmaxf(v, __shfl_xor(v, off));
    return v;
}
// async global->LDS DMA, 16B per lane; LDS dest = wave-uniform base + lane*16
static __device__ __forceinline__ void async_copy16(const u16* g, u16* l) {
    __builtin_amdgcn_global_load_lds(
        (const __attribute__((address_space(1))) u32*)g,
        (__attribute__((address_space(3))) u32*)l, 16, 0, 0);
}

// ---------------- dtype detector ----------------
__global__ void detect_k(const void* __restrict__ x, int* __restrict__ flag) {
    int lane = threadIdx.x & 63;
    u16 h = ((const u16*)x)[lane * 2];
    int e = (h >> 7) & 0xff;
    int plaus = (e >= 110 && e <= 132) ? 1 : 0;
    unsigned long long m = __ballot(plaus != 0);
    if (lane == 0) *flag = (__popcll(m) >= 32) ? 1 : 0;
}

// ---------------- breakpoints (TRANSPOSED: bpsT[k][d]) ----------------
__global__ void prep_bps_k(const void* __restrict__ bp_min, const void* __restrict__ bp_dr,
                           float* __restrict__ bpsT, const int* __restrict__ flag) {
    const int isb = *flag;
    int d = threadIdx.x;
    if (d < D_FEAT) {
        float bp = ldf(bp_min, d, isb);
        #pragma unroll
        for (int k = 0; k < NB_; ++k) {
            float x = ldf(bp_dr, d * NB_ + k, isb);
            bp += fmaxf(x, 0.f) + log1pf(expf(-fabsf(x)));
            bpsT[k * 512 + d] = bp;
        }
    }
}

// ---------------- embedding tables TRANSPOSED f32 ----------------
__global__ void prep_embT_k(const void* __restrict__ bwt, const void* __restrict__ bbias,
                            float* __restrict__ bwT, float* __restrict__ bbT,
                            const int* __restrict__ flag) {
    const int isb = *flag;
    int t = blockIdx.x * 256 + threadIdx.x;
    if (t < 512 * 36) {
        int d = t / 36, j = t % 36;
        bwT[j * 512 + d] = ldf(bwt, t, isb);
    }
    if (t < 2048) {
        int d = t >> 2, e = t & 3;
        bbT[e * 512 + d] = ldf(bbias, t, isb);
    }
}

// Wbuf element offsets — ALL K-MAJOR: Bt[n][k], K padded to x64
#define WO_PROJ 0
#define WO_GW1  1048576
#define WO_GW2  1179648
#define WO_BW1  1310720
#define WO_BW2  1441792
#define WO_SW1  1507328
#define WO_SPW  1540096
#define WO_CFW  1581056
#define W_TOTAL 1622016

__global__ void repackW_k(const void* pW, const void* gW1, const void* gW2,
                          const void* bW1, const void* bW2, const void* sW1,
                          const void* spW, const void* cfW,
                          u16* __restrict__ dst, const int* __restrict__ flag) {
    const int isb = *flag;
    size_t t = (size_t)blockIdx.x * 256 + threadIdx.x;
    if (t >= W_TOTAL) return;
    u16 v;
    if (t < WO_GW1) {                       // proj [512 n][2048 k]
        size_t i = t; int n = (int)(i >> 11), k = (int)(i & 2047);
        v = cvtb(pW, (size_t)k * 512 + n, isb);
    } else if (t < WO_GW2) {                // gW1 [256][512]
        size_t i = t - WO_GW1; int n = (int)(i >> 9), k = (int)(i & 511);
        v = cvtb(gW1, (size_t)k * 256 + n, isb);
    } else if (t < WO_BW1) {                // gW2 [512][256]
        size_t i = t - WO_GW2; int n = (int)(i >> 8), k = (int)(i & 255);
        v = cvtb(gW2, (size_t)k * 512 + n, isb);
    } else if (t < WO_BW2) {                // bW1 [256][512]
        size_t i = t - WO_BW1; int n = (int)(i >> 9), k = (int)(i & 511);
        v = cvtb(bW1, (size_t)k * 256 + n, isb);
    } else if (t < WO_SW1) {                // bW2 [256][256]
        size_t i = t - WO_BW2; int n = (int)(i >> 8), k = (int)(i & 255);
        v = cvtb(bW2, (size_t)k * 256 + n, isb);
    } else if (t < WO_SPW) {                // sW1 [128][256]
        size_t i = t - WO_SW1; int n = (int)(i >> 8), k = (int)(i & 255);
        v = cvtb(sW1, (size_t)k * 128 + n, isb);
    } else if (t < WO_CFW) {                // spW [128 n][320 k]
        size_t i = t - WO_SPW; int n = (int)(i / 320), k = (int)(i % 320);
        v = (n < 68 && k < 272) ? cvtb(spW, (size_t)k * 68 + n, isb) : (u16)0;
    } else {                                // cfW [128 n][320 k]
        size_t i = t - WO_CFW; int n = (int)(i / 320), k = (int)(i % 320);
        v = (n < 69 && k < 278) ? cvtb(cfW, (size_t)k * 69 + n, isb) : (u16)0;
    }
    dst[t] = v;
}

__global__ void prep_bias_k(const void* pb, const void* g1, const void* g2,
                            const void* b1, const void* b2, const void* sb,
                            const void* spb, const void* cfb,
                            float* __restrict__ out, const int* __restrict__ flag) {
    const int isb = *flag;
    int t = blockIdx.x * 256 + threadIdx.x;
    if      (t < 512)  out[t] = ldf(pb, t, isb);
    else if (t < 768)  out[t] = ldf(g1, t - 512, isb);
    else if (t < 1280) out[t] = ldf(g2, t - 768, isb);
    else if (t < 1536) out[t] = ldf(b1, t - 1280, isb);
    else if (t < 1792) out[t] = ldf(b2, t - 1536, isb);
    else if (t < 1920) out[t] = ldf(sb, t - 1792, isb);
    else if (t < 2048) { int c = t - 1920; out[t] = (c < 68) ? ldf(spb, c, isb) : 0.f; }
    else if (t < 2176) { int c = t - 2048; out[t] = (c < 69) ? ldf(cfb, c, isb) : 0.f; }
}

// ---------------- embedding (half-batch), 4 elements/thread ----------------
__global__ __launch_bounds__(256) void emb_k(
    const void* __restrict__ xnum, const float* __restrict__ bwT,
    const float* __restrict__ bbT, const float* __restrict__ bpsT,
    u16* __restrict__ emb, const int* __restrict__ flag, int rowoff)
{
    const int isb = *flag;
    size_t gi = ((size_t)blockIdx.x * 256 + threadIdx.x) * 4;   // element base in half
    int d0 = (int)(gi & 511);
    float xv[4];
    if (isb) {
        u16 tmp[4];
        *(uint2*)tmp = *(const uint2*)((const u16*)xnum + (size_t)rowoff * 512 + gi);
        #pragma unroll
        for (int i = 0; i < 4; ++i) xv[i] = b2f(tmp[i]);
    } else {
        float4 f = *(const float4*)((const float*)xnum + (size_t)rowoff * 512 + gi);
        xv[0] = f.x; xv[1] = f.y; xv[2] = f.z; xv[3] = f.w;
    }
    float acc[4][4];   // [i=d-lane][e]
    #pragma unroll
    for (int e = 0; e < 4; ++e) {
        float4 b = *(const float4*)&bbT[e * 512 + d0];
        acc[0][e] = b.x; acc[1][e] = b.y; acc[2][e] = b.z; acc[3][e] = b.w;
    }
    #pragma unroll
    for (int f = 0; f <= 8; ++f) {
        float bv[4];
        if (f == 0) {
            #pragma unroll
            for (int i = 0; i < 4; ++i) bv[i] = xv[i];
        } else {
            float4 bp = *(const float4*)&bpsT[(f - 1) * 512 + d0];
            bv[0] = fmaxf(xv[0] - bp.x, 0.f); bv[1] = fmaxf(xv[1] - bp.y, 0.f);
            bv[2] = fmaxf(xv[2] - bp.z, 0.f); bv[3] = fmaxf(xv[3] - bp.w, 0.f);
        }
        #pragma unroll
        for (int e = 0; e < 4; ++e) {
            float4 w = *(const float4*)&bwT[(f * 4 + e) * 512 + d0];
            acc[0][e] = fmaf(bv[0], w.x, acc[0][e]);
            acc[1][e] = fmaf(bv[1], w.y, acc[1][e]);
            acc[2][e] = fmaf(bv[2], w.z, acc[2][e]);
            acc[3][e] = fmaf(bv[3], w.w, acc[3][e]);
        }
    }
    u16 o[16];
    #pragma unroll
    for (int i = 0; i < 4; ++i)
        #pragma unroll
        for (int e = 0; e < 4; ++e) o[i * 4 + e] = f2b(acc[i][e]);
    *(uint4*)&emb[gi * 4]     = *(const uint4*)&o[0];
    *(uint4*)&emb[gi * 4 + 8] = *(const uint4*)&o[8];
}

// ---------------- bf16 MFMA GEMM: 128x128 tile, DMA-staged double-buffered LDS ----
// B K-MAJOR Bt[n][k] (ldk). XOR-swizzled LDS (chunk c of row r stored at c^(r&7)).
// All Kdim/lda/ldk multiples of 64/8 resp.; no tail guards.
template<int EMODE>
__global__ __launch_bounds__(256) void mgemm_k(
    const u16* __restrict__ A, const u16* __restrict__ Bt,
    const float* __restrict__ bias,
    void* __restrict__ out0, const void* __restrict__ aux0, void* __restrict__ aux1,
    int N, int Kdim, int lda, int ldk, int rowoff, const int* __restrict__ flagp)
{
    __shared__ __align__(16) u16 As[2][128][64];
    __shared__ __align__(16) u16 Bs[2][128][64];

    const int isb = (EMODE == 0) ? *flagp : 0;
    const int tid = threadIdx.x;
    const int row0 = blockIdx.x * 128, col0 = blockIdx.y * 128;
    const int w = tid >> 6, lane = tid & 63, q = lane >> 4, mr = lane & 15;
    const int wr = (w >> 1) * 64, wc = (w & 1) * 64;
    const int rr = lane >> 3, kg = lane & 7;
    const int sc = kg ^ (rr & 7);               // xor-swizzled source chunk

    f32x4 acc[4][4];
    #pragma unroll
    for (int a = 0; a < 4; ++a)
        #pragma unroll
        for (int b = 0; b < 4; ++b) acc[a][b] = (f32x4){0.f, 0.f, 0.f, 0.f};

    const int T = Kdim >> 6;

    auto stage = [&](int kt, int bi) {
        #pragma unroll
        for (int j = 0; j < 4; ++j) {
            int m = w * 32 + j * 8;             // wave-uniform row base (8 rows/instr)
            async_copy16(A  + (size_t)(row0 + m + rr) * lda + kt + sc * 8,
                         &As[bi][m][0]);
            async_copy16(Bt + (size_t)(col0 + m + rr) * ldk + kt + sc * 8,
                         &Bs[bi][m][0]);
        }
    };

    stage(0, 0);
    __syncthreads();                            // drains tile 0

    for (int t = 0; t < T; ++t) {
        if (t + 1 < T) stage((t + 1) << 6, (t + 1) & 1);
        const int cb = t & 1;
        #pragma unroll
        for (int ks = 0; ks < 2; ++ks) {
            bf16x8 af[4], bf[4];
            #pragma unroll
            for (int rs = 0; rs < 4; ++rs) {
                int r = wr + rs * 16 + mr;
                int pc = (ks * 4 + q) ^ (r & 7);
                af[rs] = *(const bf16x8*)&As[cb][r][pc * 8];
            }
            #pragma unroll
            for (int nt = 0; nt < 4; ++nt) {
                int r = wc + nt * 16 + mr;
                int pc = (ks * 4 + q) ^ (r & 7);
                bf[nt] = *(const bf16x8*)&Bs[cb][r][pc * 8];
            }
            #pragma unroll
            for (int rs = 0; rs < 4; ++rs)
                #pragma unroll
                for (int nt = 0; nt < 4; ++nt)
                    acc[rs][nt] = __builtin_amdgcn_mfma_f32_16x16x32_bf16(
                        af[rs], bf[nt], acc[rs][nt], 0, 0, 0);
        }
        __syncthreads();                        // drains DMA(t+1) + releases buf cb
    }

    #pragma unroll
    for (int rs = 0; rs < 4; ++rs) {
        #pragma unroll
        for (int i = 0; i < 4; ++i) {
            size_t gr = (size_t)rowoff + row0 + wr + rs * 16 + q * 4 + i;
            #pragma unroll
            for (int nt = 0; nt < 4; ++nt) {
                int c = col0 + wc + nt * 16 + mr;
                float z = acc[rs][nt][i] + bias[c];
                size_t idx = gr * (size_t)N + c;
                if (EMODE == 0) {
                    ((u16*)out0)[idx] = f2b(ldf(aux0, idx, isb) + 0.1f * z);
                } else if (EMODE == 1) {
                    ((u16*)out0)[idx] = f2b(fmaxf(z, 0.f));
                } else if (EMODE == 2) {
                    float gv = 1.f / (1.f + expf(-z));
                    ((float*)out0)[idx] = gv;
                    ((u16*)aux1)[idx] = f2b(b2f(((const u16*)aux0)[idx]) * gv);
                } else {
                    ((float*)out0)[idx] = fmaxf(z, 0.f);
                }
            }
        }
    }
}

// ---------------- pre_k (ln stride 320, zero-pad to 320) ----------------
struct PreArgs {
    const u16 *x_in;
    const float *g, *h;
    const void *base_W, *base_b;
    const void *safe_ln_g, *safe_ln_b;
    const void *top_W1, *top_b1, *top_W2, *top_b2;
    const void *spec_ln_g, *spec_ln_b;
    u16 *ln_a, *ln_b;
    float *scal;
    const int *flag;
};

__global__ __launch_bounds__(256, 4) void pre_k(PreArgs P) {
    __shared__ float w_base[256], w_slg[256], w_slb[256], w_t2[256];
    __shared__ float w_plg[272], w_plb[272];
    __shared__ float w_t1[16], w_tb1[16], w_tb2[16];
    const int isb = *P.flag;
    const int tid = threadIdx.x;
    const int wid = tid >> 6;
    const int lane = tid & 63;
    const int row = blockIdx.x * 4 + wid;

    w_base[tid] = ldf(P.base_W, tid, isb);
    w_slg[tid]  = ldf(P.safe_ln_g, tid, isb);
    w_slb[tid]  = ldf(P.safe_ln_b, tid, isb);
    w_t2[tid]   = ldf(P.top_W2, tid, isb);
    if (tid < 272) {
        w_plg[tid] = ldf(P.spec_ln_g, tid, isb);
        w_plb[tid] = ldf(P.spec_ln_b, tid, isb);
    }
    if (tid < 16) {
        w_t1[tid]  = ldf(P.top_W1, tid, isb);
        w_tb1[tid] = ldf(P.top_b1, tid, isb);
        w_tb2[tid] = ldf(P.top_b2, tid, isb);
    }
    __syncthreads();

    float hv[4], gv[8];
    #pragma unroll
    for (int i = 0; i < 4; ++i) hv[i] = P.h[(size_t)row * 256 + lane + 64 * i];
    #pragma unroll
    for (int j = 0; j < 8; ++j) gv[j] = P.g[(size_t)row * 512 + lane + 64 * j];
    const float hsum = hv[0] + hv[1] + hv[2] + hv[3];

    float pb = 0.f;
    #pragma unroll
    for (int i = 0; i < 4; ++i) pb = fmaf(hv[i], w_base[lane + 64 * i], pb);
    const float yb = wred_sum(pb) + ldf(P.base_b, 0, isb);

    float s1 = 0.f, s2 = 0.f, mx = -1e30f;
    #pragma unroll
    for (int j = 0; j < 8; ++j) { s1 += gv[j]; s2 = fmaf(gv[j], gv[j], s2); mx = fmaxf(mx, gv[j]); }
    s1 = wred_sum(s1); s2 = wred_sum(s2); mx = wred_max(mx);
    const float gmean = s1 * (1.f / 512.f);
    const float gstd = sqrtf(fmaxf(s2 * (1.f / 512.f) - gmean * gmean, 0.f));

    const float hm = wred_sum(hsum) * (1.f / 256.f);
    float pv = 0.f;
    #pragma unroll
    for (int i = 0; i < 4; ++i) { float d = hv[i] - hm; pv = fmaf(d, d, pv); }
    const float hrstd = rsqrtf(wred_sum(pv) * (1.f / 256.f) + 1e-5f);
    #pragma unroll
    for (int i = 0; i < 4; ++i) {
        int k = lane + 64 * i;
        P.ln_a[(size_t)row * 320 + k] = f2b((hv[i] - hm) * hrstd * w_slg[k] + w_slb[k]);
    }

    float tg[8];
    #pragma unroll
    for (int j = 0; j < 8; ++j) tg[j] = gv[j];
    float myv = 0.f, sumtv = 0.f; int myi = 0;
    for (int r8 = 0; r8 < 8; ++r8) {
        float bv = -1e30f; int bi = 0x7fffffff;
        #pragma unroll
        for (int j = 0; j < 8; ++j) {
            int idx = lane + 64 * j;
            if (tg[j] > bv || (tg[j] == bv && idx < bi)) { bv = tg[j]; bi = idx; }
        }
        #pragma unroll
        for (int off = 32; off > 0; off >>= 1) {
            float ov = __shfl_xor(bv, off);
            int oi = __shfl_xor(bi, off);
            if (ov > bv || (ov == bv && oi < bi)) { bv = ov; bi = oi; }
        }
        sumtv += bv;
        if (lane == r8) { myv = bv; myi = bi; }
        if ((bi & 63) == lane) {
            int oj = bi >> 6;
            #pragma unroll
            for (int j = 0; j < 8; ++j) if (j == oj) tg[j] = -1e30f;
        }
    }

    float th[16];
    #pragma unroll
    for (int s = 0; s < 16; ++s) th[s] = 0.f;
    if (lane < 8) {
        float xi = b2f(P.x_in[(size_t)row * 512 + myi]);
        float xw = xi * (myv / (sumtv + 1e-6f));
        #pragma unroll
        for (int s = 0; s < 16; ++s)
            th[s] = fmaxf(fmaf(xw, w_t1[s], w_tb1[s]), 0.f);
    }
    #pragma unroll
    for (int s = 0; s < 16; ++s) {
        th[s] += __shfl_xor(th[s], 1);
        th[s] += __shfl_xor(th[s], 2);
        th[s] += __shfl_xor(th[s], 4);
    }
    const int tt = lane & 15;
    float zacc = w_tb2[tt];
    #pragma unroll
    for (int s = 0; s < 16; ++s)
        zacc = fmaf(__shfl(th[s], 0), w_t2[s * 16 + tt], zacc);
    const float ztl = zacc * 0.125f;

    float ps = hsum + ((lane < 16) ? ztl : 0.f);
    const float sm = wred_sum(ps) * (1.f / 272.f);
    float pv2 = 0.f;
    #pragma unroll
    for (int i = 0; i < 4; ++i) { float d = hv[i] - sm; pv2 = fmaf(d, d, pv2); }
    if (lane < 16) { float d = ztl - sm; pv2 = fmaf(d, d, pv2); }
    const float srstd = rsqrtf(wred_sum(pv2) * (1.f / 272.f) + 1e-5f);
    #pragma unroll
    for (int i = 0; i < 4; ++i) {
        int k = lane + 64 * i;
        P.ln_b[(size_t)row * 320 + k] = f2b((hv[i] - sm) * srstd * w_plg[k] + w_plb[k]);
    }
    if (lane < 16) {
        int k = 256 + lane;
        P.ln_b[(size_t)row * 320 + k] = f2b((ztl - sm) * srstd * w_plg[k] + w_plb[k]);
    } else {
        P.ln_b[(size_t)row * 320 + 256 + lane] = 0;   // zero 272..319
    }

    float* sc = P.scal + (size_t)row * 32;
    if (lane < 16) sc[8 + lane] = ztl;
    if (lane == 0) { sc[0] = yb; sc[1] = gmean; sc[2] = mx; sc[3] = gstd; }
}

// ---------------- mid_k (ln stride 320, zero-pad to 320) ----------------
struct MidArgs {
    const float *h, *scal_in;
    const u16 *sh, *sph;
    const void *safe_W2, *safe_b2, *spec_W2, *spec_b2;
    const void *conf_ln_g, *conf_ln_b;
    u16 *ln_c;
    float *scal;
    const int *flag;
};

__global__ __launch_bounds__(256, 4) void mid_k(MidArgs P) {
    __shared__ float w_clg[278], w_clb[278], w_sw2[128], w_spw2[68];
    const int isb = *P.flag;
    const int tid = threadIdx.x;
    const int wid = tid >> 6;
    const int lane = tid & 63;
    const int row = blockIdx.x * 4 + wid;

    if (tid < 278) { w_clg[tid] = ldf(P.conf_ln_g, tid, isb); w_clb[tid] = ldf(P.conf_ln_b, tid, isb); }
    if (tid < 128) w_sw2[tid]  = ldf(P.safe_W2, tid, isb);
    if (tid < 68)  w_spw2[tid] = ldf(P.spec_W2, tid, isb);
    __syncthreads();

    float s0 = b2f(P.sh[(size_t)row * 128 + lane]);
    float s1 = b2f(P.sh[(size_t)row * 128 + 64 + lane]);
    float psafe = s0 * w_sw2[lane] + s1 * w_sw2[64 + lane];
    const float dsafe = wred_sum(psafe) + ldf(P.safe_b2, 0, isb);

    float p0 = b2f(P.sph[(size_t)row * 128 + lane]) * ((lane < 68) ? w_spw2[lane] : 0.f);
    if (lane < 4) p0 += b2f(P.sph[(size_t)row * 128 + 64 + lane]) * w_spw2[64 + lane];
    const float dspec = wred_sum(p0) + ldf(P.spec_b2, 0, isb);

    const float* sc = P.scal_in + (size_t)row * 32;
    const float yb = sc[0], gmean = sc[1], mx = sc[2], gstd = sc[3];
    const float ztl = (lane < 16) ? sc[8 + lane] : 0.f;

    float hv[4];
    #pragma unroll
    for (int i = 0; i < 4; ++i) hv[i] = P.h[(size_t)row * 256 + lane + 64 * i];
    const float hsum = hv[0] + hv[1] + hv[2] + hv[3];

    const float ads = fabsf(dsafe), adsp = fabsf(dspec);
    float pc = hsum + ((lane < 16) ? ztl : 0.f)
             + ((lane == 0) ? (yb + gmean + mx + gstd + ads + adsp) : 0.f);
    const float cm = wred_sum(pc) * (1.f / 278.f);
    float pv3 = 0.f;
    #pragma unroll
    for (int i = 0; i < 4; ++i) { float d = hv[i] - cm; pv3 = fmaf(d, d, pv3); }
    if (lane < 16) { float d = ztl - cm; pv3 = fmaf(d, d, pv3); }
    if (lane == 0) {
        float vals[6] = { yb, gmean, mx, gstd, ads, adsp };
        #pragma unroll
        for (int q = 0; q < 6; ++q) { float d = vals[q] - cm; pv3 = fmaf(d, d, pv3); }
    }
    const float crstd = rsqrtf(wred_sum(pv3) * (1.f / 278.f) + 1e-5f);

    u16* la = P.ln_c + (size_t)row * 320;
    #pragma unroll
    for (int i = 0; i < 4; ++i) {
        int k = lane + 64 * i;
        la[k] = f2b((hv[i] - cm) * crstd * w_clg[k] + w_clb[k]);
    }
    if (lane < 16) {
        int k = 260 + lane;
        la[k] = f2b((ztl - cm) * crstd * w_clg[k] + w_clb[k]);
    } else if (lane >= 18 && lane < 60) {
        la[260 + lane] = 0;                    // zero 278..319
    }
    if (lane == 0) {
        float vals[6] = { yb, gmean, mx, gstd, ads, adsp };
        int idxs[6] = { 256, 257, 258, 259, 276, 277 };
        #pragma unroll
        for (int q = 0; q < 6; ++q) {
            int k = idxs[q];
            la[k] = f2b((vals[q] - cm) * crstd * w_clg[k] + w_clb[k]);
        }
        float* so = P.scal + (size_t)row * 32;
        so[4] = dsafe; so[5] = dspec;
    }
}

// ---------------- post_k ----------------
__global__ __launch_bounds__(256, 4) void post_k(
    const u16* __restrict__ ch, const float* __restrict__ scal,
    const void* __restrict__ conf_W2, const void* __restrict__ conf_b2,
    void* __restrict__ out, const int* __restrict__ flag)
{
    __shared__ float w_cw2[69];
    const int isb = *flag;
    const int tid = threadIdx.x;
    const int wid = tid >> 6;
    const int lane = tid & 63;
    const int row = blockIdx.x * 4 + wid;

    if (tid < 69) w_cw2[tid] = ldf(conf_W2, tid, isb);
    __syncthreads();

    float c0 = b2f(ch[(size_t)row * 128 + lane]) * ((lane < 69) ? w_cw2[lane] : 0.f);
    if (lane < 5) c0 += b2f(ch[(size_t)row * 128 + 64 + lane]) * w_cw2[64 + lane];
    const float zlin = wred_sum(c0) + ldf(conf_b2, 0, isb);
    const float gamma = 1.f / (1.f + expf(-zlin));
    if (lane == 0) {
        const float* sc = scal + (size_t)row * 32;
        float v = sc[0] + sc[4] + gamma * sc[5];
        if (isb) ((u16*)out)[row] = f2b(v);
        else     ((float*)out)[row] = v;
    }
}

extern "C" void kernel_launch(void* const* d_in, const int* in_sizes, int n_in,
                              void* d_out, int out_size, void* d_ws, size_t ws_size,
                              hipStream_t stream) {
    (void)in_sizes; (void)n_in; (void)out_size; (void)ws_size;
    const void* x_num  = d_in[0];
    const void* bas_W  = d_in[1];
    const void* bas_b  = d_in[2];
    const void* bp_min = d_in[3];
    const void* bp_dr  = d_in[4];

    char* p = (char*)d_ws;
    auto alloc = [&](size_t bytes) { char* r = p; p += (bytes + 15) & ~(size_t)15; return r; };

    // total footprint ~135.6 MB (< 140.8 MB proven-safe in R3)
    int*   flag    = (int*)alloc(16);
    float* bpsT    = (float*)alloc(8 * 512 * 4);
    float* bwT     = (float*)alloc(36 * 512 * 4);
    float* bbT     = (float*)alloc(4 * 512 * 4);
    float* biasbuf = (float*)alloc(2176 * 4);
    u16*   Wbuf    = (u16*)alloc((size_t)W_TOTAL * 2);
    u16*   ebuf    = (u16*)alloc((size_t)(B_ROWS / 2) * 2048 * 2);  // later g f32
    u16*   x_in    = (u16*)alloc((size_t)B_ROWS * 512 * 2);
    u16*   hid1    = (u16*)alloc((size_t)B_ROWS * 256 * 2);         // later chh
    float* hbuf    = (float*)alloc((size_t)B_ROWS * 256 * 4);
    u16*   ln_a    = (u16*)alloc((size_t)B_ROWS * 320 * 2);
    u16*   ln_b    = (u16*)alloc((size_t)B_ROWS * 320 * 2);
    float* scal    = (float*)alloc((size_t)B_ROWS * 32 * 4);
    u16*   sh      = (u16*)alloc((size_t)B_ROWS * 128 * 2);
    u16*   sph     = (u16*)alloc((size_t)B_ROWS * 128 * 2);
    u16*   xg      = (u16*)alloc((size_t)B_ROWS * 512 * 2);
    u16*   hid2    = (u16*)alloc((size_t)B_ROWS * 256 * 2);

    float* g   = (float*)ebuf;
    u16*   chh = hid1;

    detect_k<<<1, 64, 0, stream>>>(x_num, flag);
    prep_bps_k<<<1, 512, 0, stream>>>(bp_min, bp_dr, bpsT, flag);
    prep_embT_k<<<72, 256, 0, stream>>>(bas_W, bas_b, bwT, bbT, flag);
    repackW_k<<<(W_TOTAL + 255) / 256, 256, 0, stream>>>(
        d_in[5], d_in[7], d_in[9], d_in[11], d_in[13], d_in[19], d_in[29], d_in[35],
        Wbuf, flag);
    prep_bias_k<<<9, 256, 0, stream>>>(
        d_in[6], d_in[8], d_in[10], d_in[12], d_in[14], d_in[20], d_in[30], d_in[36],
        biasbuf, flag);

    const int HR = B_ROWS / 2;  // 8192
    for (int half = 0; half < 2; ++half) {
        int rowoff = half * HR;
        emb_k<<<(HR * D_FEAT / 4) / 256, 256, 0, stream>>>(
            x_num, bwT, bbT, bpsT, ebuf, flag, rowoff);
        mgemm_k<0><<<dim3(HR / 128, 4), 256, 0, stream>>>(
            ebuf, Wbuf + WO_PROJ, biasbuf + 0, x_in, x_num, nullptr,
            512, 2048, 2048, 2048, rowoff, flag);
    }

    mgemm_k<1><<<dim3(B_ROWS / 128, 2), 256, 0, stream>>>(
        x_in, Wbuf + WO_GW1, biasbuf + 512, hid1, nullptr, nullptr,
        256, 512, 512, 512, 0, flag);
    mgemm_k<2><<<dim3(B_ROWS / 128, 4), 256, 0, stream>>>(
        hid1, Wbuf + WO_GW2, biasbuf + 768, g, x_in, xg,
        512, 256, 256, 256, 0, flag);
    mgemm_k<1><<<dim3(B_ROWS / 128, 2), 256, 0, stream>>>(
        xg, Wbuf + WO_BW1, biasbuf + 1280, hid2, nullptr, nullptr,
        256, 512, 512, 512, 0, flag);
    mgemm_k<3><<<dim3(B_ROWS / 128, 2), 256, 0, stream>>>(
        hid2, Wbuf + WO_BW2, biasbuf + 1536, hbuf, nullptr, nullptr,
        256, 256, 256, 256, 0, flag);

    {
        PreArgs pa;
        pa.x_in = x_in; pa.g = g; pa.h = hbuf;
        pa.base_W = d_in[15]; pa.base_b = d_in[16];
        pa.safe_ln_g = d_in[17]; pa.safe_ln_b = d_in[18];
        pa.top_W1 = d_in[23]; pa.top_b1 = d_in[24];
        pa.top_W2 = d_in[25]; pa.top_b2 = d_in[26];
        pa.spec_ln_g = d_in[27]; pa.spec_ln_b = d_in[28];
        pa.ln_a = ln_a; pa.ln_b = ln_b; pa.scal = scal; pa.flag = flag;
        pre_k<<<B_ROWS / 4, 256, 0, stream>>>(pa);
    }

    // sh = relu(ln_a[:, :256] @ safe_W1)  K=256, lda=320
    mgemm_k<1><<<dim3(B_ROWS / 128, 1), 256, 0, stream>>>(
        ln_a, Wbuf + WO_SW1, biasbuf + 1792, sh, nullptr, nullptr,
        128, 256, 320, 256, 0, flag);
    // sph = relu(ln_b @ spec_W1p)  K=320 (zero-padded both sides)
    mgemm_k<1><<<dim3(B_ROWS / 128, 1), 256, 0, stream>>>(
        ln_b, Wbuf + WO_SPW, biasbuf + 1920, sph, nullptr, nullptr,
        128, 320, 320, 320, 0, flag);

    {
        MidArgs ma;
        ma.h = hbuf; ma.scal_in = scal; ma.sh = sh; ma.sph = sph;
        ma.safe_W2 = d_in[21]; ma.safe_b2 = d_in[22];
        ma.spec_W2 = d_in[31]; ma.spec_b2 = d_in[32];
        ma.conf_ln_g = d_in[33]; ma.conf_ln_b = d_in[34];
        ma.ln_c = ln_a; ma.scal = scal; ma.flag = flag;
        mid_k<<<B_ROWS / 4, 256, 0, stream>>>(ma);
    }

    // chh = relu(ln_c @ conf_W1p)  K=320
    mgemm_k<1><<<dim3(B_ROWS / 128, 1), 256, 0, stream>>>(
        ln_a, Wbuf + WO_CFW, biasbuf + 2048, chh, nullptr, nullptr,
        128, 320, 320, 320, 0, flag);

    post_k<<<B_ROWS / 4, 256, 0, stream>>>(chh, scal, d_in[37], d_in[38], d_out, flag);
}

// Round 10
// 492.253 us; speedup vs baseline: 1.1078x; 1.0245x over previous
//
#include <hip/hip_runtime.h>
#include <cstddef>

typedef unsigned short u16;
typedef unsigned int   u32;
typedef short bf16x8 __attribute__((ext_vector_type(8)));
typedef float f32x4 __attribute__((ext_vector_type(4)));

#define B_ROWS 16384
#define D_FEAT 512
#define NB_    8

static __device__ __forceinline__ float b2f(u16 h) {
    union { u32 u; float f; } v; v.u = ((u32)h) << 16; return v.f;
}
static __device__ __forceinline__ u16 f2b(float f) {
    union { float f; u32 u; } v; v.f = f;
    u32 r = (v.u + 0x7fffu + ((v.u >> 16) & 1u)) >> 16;
    return (u16)r;
}
static __device__ __forceinline__ float ldf(const void* p, size_t i, int isb) {
    return isb ? b2f(((const u16*)p)[i]) : ((const float*)p)[i];
}
static __device__ __forceinline__ u16 cvtb(const void* p, size_t i, int isb) {
    return isb ? ((const u16*)p)[i] : f2b(((const float*)p)[i]);
}
static __device__ __forceinline__ float wred_sum(float v) {
    #pragma unroll
    for (int off = 32; off > 0; off >>= 1) v += __shfl_xor(v, off);
    return v;
}
static __device__ __forceinline__ float wred_max(float v) {
    #pragma unroll
    for (int off = 32; off > 0; off >>= 1) v = fmaxf(v, __shfl_xor(v, off));
    return v;
}
static __device__ __forceinline__ void async_copy16(const u16* g, u16* l) {
    __builtin_amdgcn_global_load_lds(
        (const __attribute__((address_space(1))) u32*)g,
        (__attribute__((address_space(3))) u32*)l, 16, 0, 0);
}

// ---------------- dtype detector (flag for downstream kernels) ----------------
__global__ void detect_k(const void* __restrict__ x, int* __restrict__ flag) {
    int lane = threadIdx.x & 63;
    u16 h = ((const u16*)x)[lane * 2];
    int e = (h >> 7) & 0xff;
    int plaus = (e >= 110 && e <= 132) ? 1 : 0;
    unsigned long long m = __ballot(plaus != 0);
    if (lane == 0) *flag = (__popcll(m) >= 32) ? 1 : 0;
}

// Wbuf element offsets — ALL K-MAJOR: Bt[n][k], K padded to x64
#define WO_PROJ 0
#define WO_GW1  1048576
#define WO_GW2  1179648
#define WO_BW1  1310720
#define WO_BW2  1441792
#define WO_SW1  1507328
#define WO_SPW  1540096
#define WO_CFW  1581056
#define W_TOTAL 1622016
#define NB_REPACK 6336   // W_TOTAL / 256

// ---------------- unified prep: repackW + bias + embT + bps (local isb) ----------
struct PrepArgs {
    const void *xnum;
    const void *pW, *gW1, *gW2, *bW1, *bW2, *sW1, *spW, *cfW;
    const void *pb, *g1, *g2, *b1, *b2, *sb, *spb, *cfb;
    const void *bwt, *bbias, *bp_min, *bp_dr;
    u16 *Wbuf; float *biasbuf, *bwT, *bbT, *bpsT;
};

__global__ __launch_bounds__(256) void prep_all_k(PrepArgs P) {
    __shared__ int s_isb;
    if (threadIdx.x < 64) {
        int lane = threadIdx.x;
        u16 h = ((const u16*)P.xnum)[lane * 2];
        int e = (h >> 7) & 0xff;
        unsigned long long m = __ballot(e >= 110 && e <= 132);
        if (lane == 0) s_isb = (__popcll(m) >= 32) ? 1 : 0;
    }
    __syncthreads();
    const int isb = s_isb;
    const int bid = blockIdx.x;
    const int tid = threadIdx.x;

    if (bid < NB_REPACK) {
        size_t t = (size_t)bid * 256 + tid;
        u16 v;
        if (t < WO_GW1) {                       // proj [512 n][2048 k]
            size_t i = t; int n = (int)(i >> 11), k = (int)(i & 2047);
            v = cvtb(P.pW, (size_t)k * 512 + n, isb);
        } else if (t < WO_GW2) {                // gW1 [256][512]
            size_t i = t - WO_GW1; int n = (int)(i >> 9), k = (int)(i & 511);
            v = cvtb(P.gW1, (size_t)k * 256 + n, isb);
        } else if (t < WO_BW1) {                // gW2 [512][256]
            size_t i = t - WO_GW2; int n = (int)(i >> 8), k = (int)(i & 255);
            v = cvtb(P.gW2, (size_t)k * 512 + n, isb);
        } else if (t < WO_BW2) {                // bW1 [256][512]
            size_t i = t - WO_BW1; int n = (int)(i >> 9), k = (int)(i & 511);
            v = cvtb(P.bW1, (size_t)k * 256 + n, isb);
        } else if (t < WO_SW1) {                // bW2 [256][256]
            size_t i = t - WO_BW2; int n = (int)(i >> 8), k = (int)(i & 255);
            v = cvtb(P.bW2, (size_t)k * 256 + n, isb);
        } else if (t < WO_SPW) {                // sW1 [128][256]
            size_t i = t - WO_SW1; int n = (int)(i >> 8), k = (int)(i & 255);
            v = cvtb(P.sW1, (size_t)k * 128 + n, isb);
        } else if (t < WO_CFW) {                // spW [128 n][320 k]
            size_t i = t - WO_SPW; int n = (int)(i / 320), k = (int)(i % 320);
            v = (n < 68 && k < 272) ? cvtb(P.spW, (size_t)k * 68 + n, isb) : (u16)0;
        } else {                                // cfW [128 n][320 k]
            size_t i = t - WO_CFW; int n = (int)(i / 320), k = (int)(i % 320);
            v = (n < 69 && k < 278) ? cvtb(P.cfW, (size_t)k * 69 + n, isb) : (u16)0;
        }
        P.Wbuf[t] = v;
    } else if (bid < NB_REPACK + 9) {
        int t = (bid - NB_REPACK) * 256 + tid;
        float* out = P.biasbuf;
        if      (t < 512)  out[t] = ldf(P.pb, t, isb);
        else if (t < 768)  out[t] = ldf(P.g1, t - 512, isb);
        else if (t < 1280) out[t] = ldf(P.g2, t - 768, isb);
        else if (t < 1536) out[t] = ldf(P.b1, t - 1280, isb);
        else if (t < 1792) out[t] = ldf(P.b2, t - 1536, isb);
        else if (t < 1920) out[t] = ldf(P.sb, t - 1792, isb);
        else if (t < 2048) { int c = t - 1920; out[t] = (c < 68) ? ldf(P.spb, c, isb) : 0.f; }
        else if (t < 2176) { int c = t - 2048; out[t] = (c < 69) ? ldf(P.cfb, c, isb) : 0.f; }
    } else if (bid < NB_REPACK + 9 + 72) {
        int t = (bid - NB_REPACK - 9) * 256 + tid;
        if (t < 512 * 36) {
            int d = t / 36, j = t % 36;
            P.bwT[j * 512 + d] = ldf(P.bwt, t, isb);
        }
        if (t < 2048) {
            int d = t >> 2, e = t & 3;
            P.bbT[e * 512 + d] = ldf(P.bbias, t, isb);
        }
    } else {
        int d = (bid - NB_REPACK - 9 - 72) * 256 + tid;
        if (d < D_FEAT) {
            float bp = ldf(P.bp_min, d, isb);
            #pragma unroll
            for (int k = 0; k < NB_; ++k) {
                float x = ldf(P.bp_dr, d * NB_ + k, isb);
                bp += fmaxf(x, 0.f) + log1pf(expf(-fabsf(x)));
                P.bpsT[k * 512 + d] = bp;
            }
        }
    }
}

// ---------------- embedding (half-batch), 4 elements/thread ----------------
__global__ __launch_bounds__(256) void emb_k(
    const void* __restrict__ xnum, const float* __restrict__ bwT,
    const float* __restrict__ bbT, const float* __restrict__ bpsT,
    u16* __restrict__ emb, const int* __restrict__ flag, int rowoff)
{
    const int isb = *flag;
    size_t gi = ((size_t)blockIdx.x * 256 + threadIdx.x) * 4;
    int d0 = (int)(gi & 511);
    float xv[4];
    if (isb) {
        u16 tmp[4];
        *(uint2*)tmp = *(const uint2*)((const u16*)xnum + (size_t)rowoff * 512 + gi);
        #pragma unroll
        for (int i = 0; i < 4; ++i) xv[i] = b2f(tmp[i]);
    } else {
        float4 f = *(const float4*)((const float*)xnum + (size_t)rowoff * 512 + gi);
        xv[0] = f.x; xv[1] = f.y; xv[2] = f.z; xv[3] = f.w;
    }
    float acc[4][4];
    #pragma unroll
    for (int e = 0; e < 4; ++e) {
        float4 b = *(const float4*)&bbT[e * 512 + d0];
        acc[0][e] = b.x; acc[1][e] = b.y; acc[2][e] = b.z; acc[3][e] = b.w;
    }
    #pragma unroll
    for (int f = 0; f <= 8; ++f) {
        float bv[4];
        if (f == 0) {
            #pragma unroll
            for (int i = 0; i < 4; ++i) bv[i] = xv[i];
        } else {
            float4 bp = *(const float4*)&bpsT[(f - 1) * 512 + d0];
            bv[0] = fmaxf(xv[0] - bp.x, 0.f); bv[1] = fmaxf(xv[1] - bp.y, 0.f);
            bv[2] = fmaxf(xv[2] - bp.z, 0.f); bv[3] = fmaxf(xv[3] - bp.w, 0.f);
        }
        #pragma unroll
        for (int e = 0; e < 4; ++e) {
            float4 w = *(const float4*)&bwT[(f * 4 + e) * 512 + d0];
            acc[0][e] = fmaf(bv[0], w.x, acc[0][e]);
            acc[1][e] = fmaf(bv[1], w.y, acc[1][e]);
            acc[2][e] = fmaf(bv[2], w.z, acc[2][e]);
            acc[3][e] = fmaf(bv[3], w.w, acc[3][e]);
        }
    }
    u16 o[16];
    #pragma unroll
    for (int i = 0; i < 4; ++i)
        #pragma unroll
        for (int e = 0; e < 4; ++e) o[i * 4 + e] = f2b(acc[i][e]);
    *(uint4*)&emb[gi * 4]     = *(const uint4*)&o[0];
    *(uint4*)&emb[gi * 4 + 8] = *(const uint4*)&o[8];
}

// ---------------- bf16 MFMA GEMM: 128x128 tile, DMA dbuf, XOR swizzle ----------
// EMODE 0: residual -> bf16 (aux0 = xnum raw, isb)
//       1: relu -> bf16
//       2: sigmoid -> bf16 g (out0) + bf16 xg (aux1), aux0 = x_in bf16
template<int EMODE>
__global__ __launch_bounds__(256) void mgemm_k(
    const u16* __restrict__ A, const u16* __restrict__ Bt,
    const float* __restrict__ bias,
    void* __restrict__ out0, const void* __restrict__ aux0, void* __restrict__ aux1,
    int N, int Kdim, int lda, int ldk, int rowoff, const int* __restrict__ flagp)
{
    __shared__ __align__(16) u16 As[2][128][64];
    __shared__ __align__(16) u16 Bs[2][128][64];

    const int isb = (EMODE == 0) ? *flagp : 0;
    const int tid = threadIdx.x;
    const int row0 = blockIdx.x * 128, col0 = blockIdx.y * 128;
    const int w = tid >> 6, lane = tid & 63, q = lane >> 4, mr = lane & 15;
    const int wr = (w >> 1) * 64, wc = (w & 1) * 64;
    const int rr = lane >> 3, kg = lane & 7;
    const int sc = kg ^ (rr & 7);

    f32x4 acc[4][4];
    #pragma unroll
    for (int a = 0; a < 4; ++a)
        #pragma unroll
        for (int b = 0; b < 4; ++b) acc[a][b] = (f32x4){0.f, 0.f, 0.f, 0.f};

    const int T = Kdim >> 6;

    auto stage = [&](int kt, int bi) {
        #pragma unroll
        for (int j = 0; j < 4; ++j) {
            int m = w * 32 + j * 8;
            async_copy16(A  + (size_t)(row0 + m + rr) * lda + kt + sc * 8,
                         &As[bi][m][0]);
            async_copy16(Bt + (size_t)(col0 + m + rr) * ldk + kt + sc * 8,
                         &Bs[bi][m][0]);
        }
    };

    stage(0, 0);
    __syncthreads();

    for (int t = 0; t < T; ++t) {
        if (t + 1 < T) stage((t + 1) << 6, (t + 1) & 1);
        const int cb = t & 1;
        #pragma unroll
        for (int ks = 0; ks < 2; ++ks) {
            bf16x8 af[4], bf[4];
            #pragma unroll
            for (int rs = 0; rs < 4; ++rs) {
                int r = wr + rs * 16 + mr;
                int pc = (ks * 4 + q) ^ (r & 7);
                af[rs] = *(const bf16x8*)&As[cb][r][pc * 8];
            }
            #pragma unroll
            for (int nt = 0; nt < 4; ++nt) {
                int r = wc + nt * 16 + mr;
                int pc = (ks * 4 + q) ^ (r & 7);
                bf[nt] = *(const bf16x8*)&Bs[cb][r][pc * 8];
            }
            #pragma unroll
            for (int rs = 0; rs < 4; ++rs)
                #pragma unroll
                for (int nt = 0; nt < 4; ++nt)
                    acc[rs][nt] = __builtin_amdgcn_mfma_f32_16x16x32_bf16(
                        af[rs], bf[nt], acc[rs][nt], 0, 0, 0);
        }
        __syncthreads();
    }

    #pragma unroll
    for (int rs = 0; rs < 4; ++rs) {
        #pragma unroll
        for (int i = 0; i < 4; ++i) {
            size_t gr = (size_t)rowoff + row0 + wr + rs * 16 + q * 4 + i;
            #pragma unroll
            for (int nt = 0; nt < 4; ++nt) {
                int c = col0 + wc + nt * 16 + mr;
                float z = acc[rs][nt][i] + bias[c];
                size_t idx = gr * (size_t)N + c;
                if (EMODE == 0) {
                    ((u16*)out0)[idx] = f2b(ldf(aux0, idx, isb) + 0.1f * z);
                } else if (EMODE == 1) {
                    ((u16*)out0)[idx] = f2b(fmaxf(z, 0.f));
                } else {
                    float gv = 1.f / (1.f + expf(-z));
                    ((u16*)out0)[idx] = f2b(gv);
                    ((u16*)aux1)[idx] = f2b(b2f(((const u16*)aux0)[idx]) * gv);
                }
            }
        }
    }
}

// ---------------- pre_k: g,h bf16; LDS weights; ln stride 320 ----------------
struct PreArgs {
    const u16 *x_in, *g, *h;
    const void *base_W, *base_b;
    const void *safe_ln_g, *safe_ln_b;
    const void *top_W1, *top_b1, *top_W2, *top_b2;
    const void *spec_ln_g, *spec_ln_b;
    u16 *ln_a, *ln_b;
    float *scal;
    const int *flag;
};

__global__ __launch_bounds__(256, 4) void pre_k(PreArgs P) {
    __shared__ float w_base[256], w_slg[256], w_slb[256], w_t2[256];
    __shared__ float w_plg[272], w_plb[272];
    __shared__ float w_t1[16], w_tb1[16], w_tb2[16];
    const int isb = *P.flag;
    const int tid = threadIdx.x;
    const int wid = tid >> 6;
    const int lane = tid & 63;
    const int row = blockIdx.x * 4 + wid;

    w_base[tid] = ldf(P.base_W, tid, isb);
    w_slg[tid]  = ldf(P.safe_ln_g, tid, isb);
    w_slb[tid]  = ldf(P.safe_ln_b, tid, isb);
    w_t2[tid]   = ldf(P.top_W2, tid, isb);
    if (tid < 272) {
        w_plg[tid] = ldf(P.spec_ln_g, tid, isb);
        w_plb[tid] = ldf(P.spec_ln_b, tid, isb);
    }
    if (tid < 16) {
        w_t1[tid]  = ldf(P.top_W1, tid, isb);
        w_tb1[tid] = ldf(P.top_b1, tid, isb);
        w_tb2[tid] = ldf(P.top_b2, tid, isb);
    }
    __syncthreads();

    float hv[4], gv[8];
    #pragma unroll
    for (int i = 0; i < 4; ++i) hv[i] = b2f(P.h[(size_t)row * 256 + lane + 64 * i]);
    #pragma unroll
    for (int j = 0; j < 8; ++j) gv[j] = b2f(P.g[(size_t)row * 512 + lane + 64 * j]);
    const float hsum = hv[0] + hv[1] + hv[2] + hv[3];

    float pb = 0.f;
    #pragma unroll
    for (int i = 0; i < 4; ++i) pb = fmaf(hv[i], w_base[lane + 64 * i], pb);
    const float yb = wred_sum(pb) + ldf(P.base_b, 0, isb);

    float s1 = 0.f, s2 = 0.f, mx = -1e30f;
    #pragma unroll
    for (int j = 0; j < 8; ++j) { s1 += gv[j]; s2 = fmaf(gv[j], gv[j], s2); mx = fmaxf(mx, gv[j]); }
    s1 = wred_sum(s1); s2 = wred_sum(s2); mx = wred_max(mx);
    const float gmean = s1 * (1.f / 512.f);
    const float gstd = sqrtf(fmaxf(s2 * (1.f / 512.f) - gmean * gmean, 0.f));

    const float hm = wred_sum(hsum) * (1.f / 256.f);
    float pv = 0.f;
    #pragma unroll
    for (int i = 0; i < 4; ++i) { float d = hv[i] - hm; pv = fmaf(d, d, pv); }
    const float hrstd = rsqrtf(wred_sum(pv) * (1.f / 256.f) + 1e-5f);
    #pragma unroll
    for (int i = 0; i < 4; ++i) {
        int k = lane + 64 * i;
        P.ln_a[(size_t)row * 320 + k] = f2b((hv[i] - hm) * hrstd * w_slg[k] + w_slb[k]);
    }

    float tg[8];
    #pragma unroll
    for (int j = 0; j < 8; ++j) tg[j] = gv[j];
    float myv = 0.f, sumtv = 0.f; int myi = 0;
    for (int r8 = 0; r8 < 8; ++r8) {
        float bv = -1e30f; int bi = 0x7fffffff;
        #pragma unroll
        for (int j = 0; j < 8; ++j) {
            int idx = lane + 64 * j;
            if (tg[j] > bv || (tg[j] == bv && idx < bi)) { bv = tg[j]; bi = idx; }
        }
        #pragma unroll
        for (int off = 32; off > 0; off >>= 1) {
            float ov = __shfl_xor(bv, off);
            int oi = __shfl_xor(bi, off);
            if (ov > bv || (ov == bv && oi < bi)) { bv = ov; bi = oi; }
        }
        sumtv += bv;
        if (lane == r8) { myv = bv; myi = bi; }
        if ((bi & 63) == lane) {
            int oj = bi >> 6;
            #pragma unroll
            for (int j = 0; j < 8; ++j) if (j == oj) tg[j] = -1e30f;
        }
    }

    float th[16];
    #pragma unroll
    for (int s = 0; s < 16; ++s) th[s] = 0.f;
    if (lane < 8) {
        float xi = b2f(P.x_in[(size_t)row * 512 + myi]);
        float xw = xi * (myv / (sumtv + 1e-6f));
        #pragma unroll
        for (int s = 0; s < 16; ++s)
            th[s] = fmaxf(fmaf(xw, w_t1[s], w_tb1[s]), 0.f);
    }
    #pragma unroll
    for (int s = 0; s < 16; ++s) {
        th[s] += __shfl_xor(th[s], 1);
        th[s] += __shfl_xor(th[s], 2);
        th[s] += __shfl_xor(th[s], 4);
    }
    const int tt = lane & 15;
    float zacc = w_tb2[tt];
    #pragma unroll
    for (int s = 0; s < 16; ++s)
        zacc = fmaf(__shfl(th[s], 0), w_t2[s * 16 + tt], zacc);
    const float ztl = zacc * 0.125f;

    float ps = hsum + ((lane < 16) ? ztl : 0.f);
    const float sm = wred_sum(ps) * (1.f / 272.f);
    float pv2 = 0.f;
    #pragma unroll
    for (int i = 0; i < 4; ++i) { float d = hv[i] - sm; pv2 = fmaf(d, d, pv2); }
    if (lane < 16) { float d = ztl - sm; pv2 = fmaf(d, d, pv2); }
    const float srstd = rsqrtf(wred_sum(pv2) * (1.f / 272.f) + 1e-5f);
    #pragma unroll
    for (int i = 0; i < 4; ++i) {
        int k = lane + 64 * i;
        P.ln_b[(size_t)row * 320 + k] = f2b((hv[i] - sm) * srstd * w_plg[k] + w_plb[k]);
    }
    if (lane < 16) {
        int k = 256 + lane;
        P.ln_b[(size_t)row * 320 + k] = f2b((ztl - sm) * srstd * w_plg[k] + w_plb[k]);
    } else {
        P.ln_b[(size_t)row * 320 + 256 + lane] = 0;
    }

    float* sc = P.scal + (size_t)row * 32;
    if (lane < 16) sc[8 + lane] = ztl;
    if (lane == 0) { sc[0] = yb; sc[1] = gmean; sc[2] = mx; sc[3] = gstd; }
}

// ---------------- mid_k: h bf16; ln stride 320 ----------------
struct MidArgs {
    const u16 *h;
    const float *scal_in;
    const u16 *sh, *sph;
    const void *safe_W2, *safe_b2, *spec_W2, *spec_b2;
    const void *conf_ln_g, *conf_ln_b;
    u16 *ln_c;
    float *scal;
    const int *flag;
};

__global__ __launch_bounds__(256, 4) void mid_k(MidArgs P) {
    __shared__ float w_clg[278], w_clb[278], w_sw2[128], w_spw2[68];
    const int isb = *P.flag;
    const int tid = threadIdx.x;
    const int wid = tid >> 6;
    const int lane = tid & 63;
    const int row = blockIdx.x * 4 + wid;

    if (tid < 278) { w_clg[tid] = ldf(P.conf_ln_g, tid, isb); w_clb[tid] = ldf(P.conf_ln_b, tid, isb); }
    if (tid < 128) w_sw2[tid]  = ldf(P.safe_W2, tid, isb);
    if (tid < 68)  w_spw2[tid] = ldf(P.spec_W2, tid, isb);
    __syncthreads();

    float s0 = b2f(P.sh[(size_t)row * 128 + lane]);
    float s1 = b2f(P.sh[(size_t)row * 128 + 64 + lane]);
    float psafe = s0 * w_sw2[lane] + s1 * w_sw2[64 + lane];
    const float dsafe = wred_sum(psafe) + ldf(P.safe_b2, 0, isb);

    float p0 = b2f(P.sph[(size_t)row * 128 + lane]) * ((lane < 68) ? w_spw2[lane] : 0.f);
    if (lane < 4) p0 += b2f(P.sph[(size_t)row * 128 + 64 + lane]) * w_spw2[64 + lane];
    const float dspec = wred_sum(p0) + ldf(P.spec_b2, 0, isb);

    const float* sc = P.scal_in + (size_t)row * 32;
    const float yb = sc[0], gmean = sc[1], mx = sc[2], gstd = sc[3];
    const float ztl = (lane < 16) ? sc[8 + lane] : 0.f;

    float hv[4];
    #pragma unroll
    for (int i = 0; i < 4; ++i) hv[i] = b2f(P.h[(size_t)row * 256 + lane + 64 * i]);
    const float hsum = hv[0] + hv[1] + hv[2] + hv[3];

    const float ads = fabsf(dsafe), adsp = fabsf(dspec);
    float pc = hsum + ((lane < 16) ? ztl : 0.f)
             + ((lane == 0) ? (yb + gmean + mx + gstd + ads + adsp) : 0.f);
    const float cm = wred_sum(pc) * (1.f / 278.f);
    float pv3 = 0.f;
    #pragma unroll
    for (int i = 0; i < 4; ++i) { float d = hv[i] - cm; pv3 = fmaf(d, d, pv3); }
    if (lane < 16) { float d = ztl - cm; pv3 = fmaf(d, d, pv3); }
    if (lane == 0) {
        float vals[6] = { yb, gmean, mx, gstd, ads, adsp };
        #pragma unroll
        for (int q = 0; q < 6; ++q) { float d = vals[q] - cm; pv3 = fmaf(d, d, pv3); }
    }
    const float crstd = rsqrtf(wred_sum(pv3) * (1.f / 278.f) + 1e-5f);

    u16* la = P.ln_c + (size_t)row * 320;
    #pragma unroll
    for (int i = 0; i < 4; ++i) {
        int k = lane + 64 * i;
        la[k] = f2b((hv[i] - cm) * crstd * w_clg[k] + w_clb[k]);
    }
    if (lane < 16) {
        int k = 260 + lane;
        la[k] = f2b((ztl - cm) * crstd * w_clg[k] + w_clb[k]);
    } else if (lane >= 18 && lane < 60) {
        la[260 + lane] = 0;
    }
    if (lane == 0) {
        float vals[6] = { yb, gmean, mx, gstd, ads, adsp };
        int idxs[6] = { 256, 257, 258, 259, 276, 277 };
        #pragma unroll
        for (int q = 0; q < 6; ++q) {
            int k = idxs[q];
            la[k] = f2b((vals[q] - cm) * crstd * w_clg[k] + w_clb[k]);
        }
        float* so = P.scal + (size_t)row * 32;
        so[4] = dsafe; so[5] = dspec;
    }
}

// ---------------- post_k ----------------
__global__ __launch_bounds__(256, 4) void post_k(
    const u16* __restrict__ ch, const float* __restrict__ scal,
    const void* __restrict__ conf_W2, const void* __restrict__ conf_b2,
    void* __restrict__ out, const int* __restrict__ flag)
{
    __shared__ float w_cw2[69];
    const int isb = *flag;
    const int tid = threadIdx.x;
    const int wid = tid >> 6;
    const int lane = tid & 63;
    const int row = blockIdx.x * 4 + wid;

    if (tid < 69) w_cw2[tid] = ldf(conf_W2, tid, isb);
    __syncthreads();

    float c0 = b2f(ch[(size_t)row * 128 + lane]) * ((lane < 69) ? w_cw2[lane] : 0.f);
    if (lane < 5) c0 += b2f(ch[(size_t)row * 128 + 64 + lane]) * w_cw2[64 + lane];
    const float zlin = wred_sum(c0) + ldf(conf_b2, 0, isb);
    const float gamma = 1.f / (1.f + expf(-zlin));
    if (lane == 0) {
        const float* sc = scal + (size_t)row * 32;
        float v = sc[0] + sc[4] + gamma * sc[5];
        if (isb) ((u16*)out)[row] = f2b(v);
        else     ((float*)out)[row] = v;
    }
}

extern "C" void kernel_launch(void* const* d_in, const int* in_sizes, int n_in,
                              void* d_out, int out_size, void* d_ws, size_t ws_size,
                              hipStream_t stream) {
    (void)in_sizes; (void)n_in; (void)out_size; (void)ws_size;
    const void* x_num = d_in[0];

    char* p = (char*)d_ws;
    auto alloc = [&](size_t bytes) { char* r = p; p += (bytes + 15) & ~(size_t)15; return r; };

    // total footprint ~127.2 MB (< 140.8 MB proven-safe)
    int*   flag    = (int*)alloc(16);
    float* bpsT    = (float*)alloc(8 * 512 * 4);
    float* bwT     = (float*)alloc(36 * 512 * 4);
    float* bbT     = (float*)alloc(4 * 512 * 4);
    float* biasbuf = (float*)alloc(2176 * 4);
    u16*   Wbuf    = (u16*)alloc((size_t)W_TOTAL * 2);
    u16*   ebuf    = (u16*)alloc((size_t)(B_ROWS / 2) * 2048 * 2);  // later g bf16
    u16*   x_in    = (u16*)alloc((size_t)B_ROWS * 512 * 2);
    u16*   hid1    = (u16*)alloc((size_t)B_ROWS * 256 * 2);         // later chh
    u16*   hbuf    = (u16*)alloc((size_t)B_ROWS * 256 * 2);
    u16*   ln_a    = (u16*)alloc((size_t)B_ROWS * 320 * 2);
    u16*   ln_b    = (u16*)alloc((size_t)B_ROWS * 320 * 2);
    float* scal    = (float*)alloc((size_t)B_ROWS * 32 * 4);
    u16*   sh      = (u16*)alloc((size_t)B_ROWS * 128 * 2);
    u16*   sph     = (u16*)alloc((size_t)B_ROWS * 128 * 2);
    u16*   xg      = (u16*)alloc((size_t)B_ROWS * 512 * 2);
    u16*   hid2    = (u16*)alloc((size_t)B_ROWS * 256 * 2);

    u16*   g   = ebuf;      // bf16, 16.8 MB <= ebuf's 33.5 MB
    u16*   chh = hid1;

    detect_k<<<1, 64, 0, stream>>>(x_num, flag);

    {
        PrepArgs pr;
        pr.xnum = x_num;
        pr.pW = d_in[5];  pr.gW1 = d_in[7];  pr.gW2 = d_in[9];
        pr.bW1 = d_in[11]; pr.bW2 = d_in[13]; pr.sW1 = d_in[19];
        pr.spW = d_in[29]; pr.cfW = d_in[35];
        pr.pb = d_in[6];  pr.g1 = d_in[8];  pr.g2 = d_in[10];
        pr.b1 = d_in[12]; pr.b2 = d_in[14]; pr.sb = d_in[20];
        pr.spb = d_in[30]; pr.cfb = d_in[36];
        pr.bwt = d_in[1]; pr.bbias = d_in[2];
        pr.bp_min = d_in[3]; pr.bp_dr = d_in[4];
        pr.Wbuf = Wbuf; pr.biasbuf = biasbuf;
        pr.bwT = bwT; pr.bbT = bbT; pr.bpsT = bpsT;
        prep_all_k<<<NB_REPACK + 9 + 72 + 2, 256, 0, stream>>>(pr);
    }

    const int HR = B_ROWS / 2;  // 8192
    for (int half = 0; half < 2; ++half) {
        int rowoff = half * HR;
        emb_k<<<(HR * D_FEAT / 4) / 256, 256, 0, stream>>>(
            x_num, bwT, bbT, bpsT, ebuf, flag, rowoff);
        mgemm_k<0><<<dim3(HR / 128, 4), 256, 0, stream>>>(
            ebuf, Wbuf + WO_PROJ, biasbuf + 0, x_in, x_num, nullptr,
            512, 2048, 2048, 2048, rowoff, flag);
    }

    mgemm_k<1><<<dim3(B_ROWS / 128, 2), 256, 0, stream>>>(
        x_in, Wbuf + WO_GW1, biasbuf + 512, hid1, nullptr, nullptr,
        256, 512, 512, 512, 0, flag);
    mgemm_k<2><<<dim3(B_ROWS / 128, 4), 256, 0, stream>>>(
        hid1, Wbuf + WO_GW2, biasbuf + 768, g, x_in, xg,
        512, 256, 256, 256, 0, flag);
    mgemm_k<1><<<dim3(B_ROWS / 128, 2), 256, 0, stream>>>(
        xg, Wbuf + WO_BW1, biasbuf + 1280, hid2, nullptr, nullptr,
        256, 512, 512, 512, 0, flag);
    mgemm_k<1><<<dim3(B_ROWS / 128, 2), 256, 0, stream>>>(
        hid2, Wbuf + WO_BW2, biasbuf + 1536, hbuf, nullptr, nullptr,
        256, 256, 256, 256, 0, flag);

    {
        PreArgs pa;
        pa.x_in = x_in; pa.g = g; pa.h = hbuf;
        pa.base_W = d_in[15]; pa.base_b = d_in[16];
        pa.safe_ln_g = d_in[17]; pa.safe_ln_b = d_in[18];
        pa.top_W1 = d_in[23]; pa.top_b1 = d_in[24];
        pa.top_W2 = d_in[25]; pa.top_b2 = d_in[26];
        pa.spec_ln_g = d_in[27]; pa.spec_ln_b = d_in[28];
        pa.ln_a = ln_a; pa.ln_b = ln_b; pa.scal = scal; pa.flag = flag;
        pre_k<<<B_ROWS / 4, 256, 0, stream>>>(pa);
    }

    mgemm_k<1><<<dim3(B_ROWS / 128, 1), 256, 0, stream>>>(
        ln_a, Wbuf + WO_SW1, biasbuf + 1792, sh, nullptr, nullptr,
        128, 256, 320, 256, 0, flag);
    mgemm_k<1><<<dim3(B_ROWS / 128, 1), 256, 0, stream>>>(
        ln_b, Wbuf + WO_SPW, biasbuf + 1920, sph, nullptr, nullptr,
        128, 320, 320, 320, 0, flag);

    {
        MidArgs ma;
        ma.h = hbuf; ma.scal_in = scal; ma.sh = sh; ma.sph = sph;
        ma.safe_W2 = d_in[21]; ma.safe_b2 = d_in[22];
        ma.spec_W2 = d_in[31]; ma.spec_b2 = d_in[32];
        ma.conf_ln_g = d_in[33]; ma.conf_ln_b = d_in[34];
        ma.ln_c = ln_a; ma.scal = scal; ma.flag = flag;
        mid_k<<<B_ROWS / 4, 256, 0, stream>>>(ma);
    }

    mgemm_k<1><<<dim3(B_ROWS / 128, 1), 256, 0, stream>>>(
        ln_a, Wbuf + WO_CFW, biasbuf + 2048, chh, nullptr, nullptr,
        128, 320, 320, 320, 0, flag);

    post_k<<<B_ROWS / 4, 256, 0, stream>>>(chh, scal, d_in[37], d_in[38], d_out, flag);
}

// Round 11
// 454.034 us; speedup vs baseline: 1.2010x; 1.0842x over previous
//
#include <hip/hip_runtime.h>
#include <cstddef>

typedef unsigned short u16;
typedef unsigned int   u32;
typedef short bf16x8 __attribute__((ext_vector_type(8)));
typedef float f32x4 __attribute__((ext_vector_type(4)));

#define B_ROWS 16384
#define D_FEAT 512
#define NB_    8

static __device__ __forceinline__ float b2f(u16 h) {
    union { u32 u; float f; } v; v.u = ((u32)h) << 16; return v.f;
}
static __device__ __forceinline__ u16 f2b(float f) {
    union { float f; u32 u; } v; v.f = f;
    u32 r = (v.u + 0x7fffu + ((v.u >> 16) & 1u)) >> 16;
    return (u16)r;
}
static __device__ __forceinline__ float ldf(const void* p, size_t i, int isb) {
    return isb ? b2f(((const u16*)p)[i]) : ((const float*)p)[i];
}
static __device__ __forceinline__ u16 cvtb(const void* p, size_t i, int isb) {
    return isb ? ((const u16*)p)[i] : f2b(((const float*)p)[i]);
}
static __device__ __forceinline__ float wred_sum(float v) {
    #pragma unroll
    for (int off = 32; off > 0; off >>= 1) v += __shfl_xor(v, off);
    return v;
}
static __device__ __forceinline__ float wred_max(float v) {
    #pragma unroll
    for (int off = 32; off > 0; off >>= 1) v = fmaxf(v, __shfl_xor(v, off));
    return v;
}
static __device__ __forceinline__ void async_copy16(const u16* g, u16* l) {
    __builtin_amdgcn_global_load_lds(
        (const __attribute__((address_space(1))) u32*)g,
        (__attribute__((address_space(3))) u32*)l, 16, 0, 0);
}

// Wbuf element offsets — ALL K-MAJOR: Bt[n][k], K padded to x64
#define WO_PROJ 0
#define WO_GW1  1048576
#define WO_GW2  1179648
#define WO_BW1  1310720
#define WO_BW2  1441792
#define WO_SW1  1507328
#define WO_SPW  1540096
#define WO_CFW  1581056
#define W_TOTAL 1622016
#define NB_REPACK 6336   // W_TOTAL / 256

// ---------------- unified prep: repackW + bias + embT + bps + flag ----------
struct PrepArgs {
    const void *xnum;
    const void *pW, *gW1, *gW2, *bW1, *bW2, *sW1, *spW, *cfW;
    const void *pb, *g1, *g2, *b1, *b2, *sb, *spb, *cfb;
    const void *bwt, *bbias, *bp_min, *bp_dr;
    u16 *Wbuf; float *biasbuf, *bwT, *bbT, *bpsT;
    int *flag;
};

__global__ __launch_bounds__(256) void prep_all_k(PrepArgs P) {
    __shared__ int s_isb;
    if (threadIdx.x < 64) {
        int lane = threadIdx.x;
        u16 h = ((const u16*)P.xnum)[lane * 2];
        int e = (h >> 7) & 0xff;
        unsigned long long m = __ballot(e >= 110 && e <= 132);
        if (lane == 0) s_isb = (__popcll(m) >= 32) ? 1 : 0;
    }
    __syncthreads();
    const int isb = s_isb;
    const int bid = blockIdx.x;
    const int tid = threadIdx.x;

    if (bid < NB_REPACK) {
        size_t t = (size_t)bid * 256 + tid;
        u16 v;
        if (t < WO_GW1) {                       // proj [512 n][2048 k]
            size_t i = t; int n = (int)(i >> 11), k = (int)(i & 2047);
            v = cvtb(P.pW, (size_t)k * 512 + n, isb);
        } else if (t < WO_GW2) {                // gW1 [256][512]
            size_t i = t - WO_GW1; int n = (int)(i >> 9), k = (int)(i & 511);
            v = cvtb(P.gW1, (size_t)k * 256 + n, isb);
        } else if (t < WO_BW1) {                // gW2 [512][256]
            size_t i = t - WO_GW2; int n = (int)(i >> 8), k = (int)(i & 255);
            v = cvtb(P.gW2, (size_t)k * 512 + n, isb);
        } else if (t < WO_BW2) {                // bW1 [256][512]
            size_t i = t - WO_BW1; int n = (int)(i >> 9), k = (int)(i & 511);
            v = cvtb(P.bW1, (size_t)k * 256 + n, isb);
        } else if (t < WO_SW1) {                // bW2 [256][256]
            size_t i = t - WO_BW2; int n = (int)(i >> 8), k = (int)(i & 255);
            v = cvtb(P.bW2, (size_t)k * 256 + n, isb);
        } else if (t < WO_SPW) {                // sW1 [128][256]
            size_t i = t - WO_SW1; int n = (int)(i >> 8), k = (int)(i & 255);
            v = cvtb(P.sW1, (size_t)k * 128 + n, isb);
        } else if (t < WO_CFW) {                // spW [128 n][320 k]
            size_t i = t - WO_SPW; int n = (int)(i / 320), k = (int)(i % 320);
            v = (n < 68 && k < 272) ? cvtb(P.spW, (size_t)k * 68 + n, isb) : (u16)0;
        } else {                                // cfW [128 n][320 k]
            size_t i = t - WO_CFW; int n = (int)(i / 320), k = (int)(i % 320);
            v = (n < 69 && k < 278) ? cvtb(P.cfW, (size_t)k * 69 + n, isb) : (u16)0;
        }
        P.Wbuf[t] = v;
    } else if (bid < NB_REPACK + 9) {
        int t = (bid - NB_REPACK) * 256 + tid;
        float* out = P.biasbuf;
        if      (t < 512)  out[t] = ldf(P.pb, t, isb);
        else if (t < 768)  out[t] = ldf(P.g1, t - 512, isb);
        else if (t < 1280) out[t] = ldf(P.g2, t - 768, isb);
        else if (t < 1536) out[t] = ldf(P.b1, t - 1280, isb);
        else if (t < 1792) out[t] = ldf(P.b2, t - 1536, isb);
        else if (t < 1920) out[t] = ldf(P.sb, t - 1792, isb);
        else if (t < 2048) { int c = t - 1920; out[t] = (c < 68) ? ldf(P.spb, c, isb) : 0.f; }
        else if (t < 2176) { int c = t - 2048; out[t] = (c < 69) ? ldf(P.cfb, c, isb) : 0.f; }
    } else if (bid < NB_REPACK + 9 + 72) {
        int t = (bid - NB_REPACK - 9) * 256 + tid;
        if (t < 512 * 36) {
            int d = t / 36, j = t % 36;
            P.bwT[j * 512 + d] = ldf(P.bwt, t, isb);
        }
        if (t < 2048) {
            int d = t >> 2, e = t & 3;
            P.bbT[e * 512 + d] = ldf(P.bbias, t, isb);
        }
    } else {
        int d = (bid - NB_REPACK - 9 - 72) * 256 + tid;
        if (d < D_FEAT) {
            float bp = ldf(P.bp_min, d, isb);
            #pragma unroll
            for (int k = 0; k < NB_; ++k) {
                float x = ldf(P.bp_dr, d * NB_ + k, isb);
                bp += fmaxf(x, 0.f) + log1pf(expf(-fabsf(x)));
                P.bpsT[k * 512 + d] = bp;
            }
        }
        if (d == 0) *P.flag = isb;
    }
}

// ---------------- embedding (half-batch), 4 elements/thread ----------------
__global__ __launch_bounds__(256) void emb_k(
    const void* __restrict__ xnum, const float* __restrict__ bwT,
    const float* __restrict__ bbT, const float* __restrict__ bpsT,
    u16* __restrict__ emb, const int* __restrict__ flag, int rowoff)
{
    const int isb = *flag;
    size_t gi = ((size_t)blockIdx.x * 256 + threadIdx.x) * 4;
    int d0 = (int)(gi & 511);
    float xv[4];
    if (isb) {
        u16 tmp[4];
        *(uint2*)tmp = *(const uint2*)((const u16*)xnum + (size_t)rowoff * 512 + gi);
        #pragma unroll
        for (int i = 0; i < 4; ++i) xv[i] = b2f(tmp[i]);
    } else {
        float4 f = *(const float4*)((const float*)xnum + (size_t)rowoff * 512 + gi);
        xv[0] = f.x; xv[1] = f.y; xv[2] = f.z; xv[3] = f.w;
    }
    float acc[4][4];
    #pragma unroll
    for (int e = 0; e < 4; ++e) {
        float4 b = *(const float4*)&bbT[e * 512 + d0];
        acc[0][e] = b.x; acc[1][e] = b.y; acc[2][e] = b.z; acc[3][e] = b.w;
    }
    #pragma unroll
    for (int f = 0; f <= 8; ++f) {
        float bv[4];
        if (f == 0) {
            #pragma unroll
            for (int i = 0; i < 4; ++i) bv[i] = xv[i];
        } else {
            float4 bp = *(const float4*)&bpsT[(f - 1) * 512 + d0];
            bv[0] = fmaxf(xv[0] - bp.x, 0.f); bv[1] = fmaxf(xv[1] - bp.y, 0.f);
            bv[2] = fmaxf(xv[2] - bp.z, 0.f); bv[3] = fmaxf(xv[3] - bp.w, 0.f);
        }
        #pragma unroll
        for (int e = 0; e < 4; ++e) {
            float4 w = *(const float4*)&bwT[(f * 4 + e) * 512 + d0];
            acc[0][e] = fmaf(bv[0], w.x, acc[0][e]);
            acc[1][e] = fmaf(bv[1], w.y, acc[1][e]);
            acc[2][e] = fmaf(bv[2], w.z, acc[2][e]);
            acc[3][e] = fmaf(bv[3], w.w, acc[3][e]);
        }
    }
    u16 o[16];
    #pragma unroll
    for (int i = 0; i < 4; ++i)
        #pragma unroll
        for (int e = 0; e < 4; ++e) o[i * 4 + e] = f2b(acc[i][e]);
    *(uint4*)&emb[gi * 4]     = *(const uint4*)&o[0];
    *(uint4*)&emb[gi * 4 + 8] = *(const uint4*)&o[8];
}

// ---------------- bf16 MFMA GEMM: 64x64 tile, 4 waves (2x2, 32x32/wave) ----
// DMA dbuf + XOR swizzle. K-major B. Grid 4x larger than 128-tile version:
// multiple blocks/CU so barrier-drain latency overlaps across blocks (m114).
template<int EMODE>
__global__ __launch_bounds__(256) void mgemm_k(
    const u16* __restrict__ A, const u16* __restrict__ Bt,
    const float* __restrict__ bias,
    void* __restrict__ out0, const void* __restrict__ aux0, void* __restrict__ aux1,
    int N, int Kdim, int lda, int ldk, int rowoff, const int* __restrict__ flagp)
{
    __shared__ __align__(16) u16 As[2][64][64];
    __shared__ __align__(16) u16 Bs[2][64][64];

    const int isb = (EMODE == 0) ? *flagp : 0;
    const int tid = threadIdx.x;
    const int row0 = blockIdx.x * 64, col0 = blockIdx.y * 64;
    const int w = tid >> 6, lane = tid & 63, q = lane >> 4, mr = lane & 15;
    const int wr = (w >> 1) * 32, wc = (w & 1) * 32;
    const int rr = lane >> 3, kg = lane & 7;
    const int sc = kg ^ (rr & 7);

    f32x4 acc[2][2];
    #pragma unroll
    for (int a = 0; a < 2; ++a)
        #pragma unroll
        for (int b = 0; b < 2; ++b) acc[a][b] = (f32x4){0.f, 0.f, 0.f, 0.f};

    const int T = Kdim >> 6;

    // waves 0-1 stage A (rows 0..63), waves 2-3 stage B (rows 0..63)
    auto stage = [&](int kt, int bi) {
        if (w < 2) {
            #pragma unroll
            for (int j = 0; j < 4; ++j) {
                int m = w * 32 + j * 8;
                async_copy16(A + (size_t)(row0 + m + rr) * lda + kt + sc * 8,
                             &As[bi][m][0]);
            }
        } else {
            #pragma unroll
            for (int j = 0; j < 4; ++j) {
                int m = (w - 2) * 32 + j * 8;
                async_copy16(Bt + (size_t)(col0 + m + rr) * ldk + kt + sc * 8,
                             &Bs[bi][m][0]);
            }
        }
    };

    stage(0, 0);
    __syncthreads();

    for (int t = 0; t < T; ++t) {
        if (t + 1 < T) stage((t + 1) << 6, (t + 1) & 1);
        const int cb = t & 1;
        #pragma unroll
        for (int ks = 0; ks < 2; ++ks) {
            bf16x8 af[2], bf[2];
            #pragma unroll
            for (int rs = 0; rs < 2; ++rs) {
                int r = wr + rs * 16 + mr;
                int pc = (ks * 4 + q) ^ (r & 7);
                af[rs] = *(const bf16x8*)&As[cb][r][pc * 8];
            }
            #pragma unroll
            for (int nt = 0; nt < 2; ++nt) {
                int r = wc + nt * 16 + mr;
                int pc = (ks * 4 + q) ^ (r & 7);
                bf[nt] = *(const bf16x8*)&Bs[cb][r][pc * 8];
            }
            #pragma unroll
            for (int rs = 0; rs < 2; ++rs)
                #pragma unroll
                for (int nt = 0; nt < 2; ++nt)
                    acc[rs][nt] = __builtin_amdgcn_mfma_f32_16x16x32_bf16(
                        af[rs], bf[nt], acc[rs][nt], 0, 0, 0);
        }
        __syncthreads();
    }

    #pragma unroll
    for (int rs = 0; rs < 2; ++rs) {
        #pragma unroll
        for (int i = 0; i < 4; ++i) {
            size_t gr = (size_t)rowoff + row0 + wr + rs * 16 + q * 4 + i;
            #pragma unroll
            for (int nt = 0; nt < 2; ++nt) {
                int c = col0 + wc + nt * 16 + mr;
                float z = acc[rs][nt][i] + bias[c];
                size_t idx = gr * (size_t)N + c;
                if (EMODE == 0) {
                    ((u16*)out0)[idx] = f2b(ldf(aux0, idx, isb) + 0.1f * z);
                } else if (EMODE == 1) {
                    ((u16*)out0)[idx] = f2b(fmaxf(z, 0.f));
                } else {
                    float gv = 1.f / (1.f + expf(-z));
                    ((u16*)out0)[idx] = f2b(gv);
                    ((u16*)aux1)[idx] = f2b(b2f(((const u16*)aux0)[idx]) * gv);
                }
            }
        }
    }
}

// ---------------- pre_k (unchanged from R10) ----------------
struct PreArgs {
    const u16 *x_in, *g, *h;
    const void *base_W, *base_b;
    const void *safe_ln_g, *safe_ln_b;
    const void *top_W1, *top_b1, *top_W2, *top_b2;
    const void *spec_ln_g, *spec_ln_b;
    u16 *ln_a, *ln_b;
    float *scal;
    const int *flag;
};

__global__ __launch_bounds__(256, 4) void pre_k(PreArgs P) {
    __shared__ float w_base[256], w_slg[256], w_slb[256], w_t2[256];
    __shared__ float w_plg[272], w_plb[272];
    __shared__ float w_t1[16], w_tb1[16], w_tb2[16];
    const int isb = *P.flag;
    const int tid = threadIdx.x;
    const int wid = tid >> 6;
    const int lane = tid & 63;
    const int row = blockIdx.x * 4 + wid;

    w_base[tid] = ldf(P.base_W, tid, isb);
    w_slg[tid]  = ldf(P.safe_ln_g, tid, isb);
    w_slb[tid]  = ldf(P.safe_ln_b, tid, isb);
    w_t2[tid]   = ldf(P.top_W2, tid, isb);
    if (tid < 272) {
        w_plg[tid] = ldf(P.spec_ln_g, tid, isb);
        w_plb[tid] = ldf(P.spec_ln_b, tid, isb);
    }
    if (tid < 16) {
        w_t1[tid]  = ldf(P.top_W1, tid, isb);
        w_tb1[tid] = ldf(P.top_b1, tid, isb);
        w_tb2[tid] = ldf(P.top_b2, tid, isb);
    }
    __syncthreads();

    float hv[4], gv[8];
    #pragma unroll
    for (int i = 0; i < 4; ++i) hv[i] = b2f(P.h[(size_t)row * 256 + lane + 64 * i]);
    #pragma unroll
    for (int j = 0; j < 8; ++j) gv[j] = b2f(P.g[(size_t)row * 512 + lane + 64 * j]);
    const float hsum = hv[0] + hv[1] + hv[2] + hv[3];

    float pb = 0.f;
    #pragma unroll
    for (int i = 0; i < 4; ++i) pb = fmaf(hv[i], w_base[lane + 64 * i], pb);
    const float yb = wred_sum(pb) + ldf(P.base_b, 0, isb);

    float s1 = 0.f, s2 = 0.f, mx = -1e30f;
    #pragma unroll
    for (int j = 0; j < 8; ++j) { s1 += gv[j]; s2 = fmaf(gv[j], gv[j], s2); mx = fmaxf(mx, gv[j]); }
    s1 = wred_sum(s1); s2 = wred_sum(s2); mx = wred_max(mx);
    const float gmean = s1 * (1.f / 512.f);
    const float gstd = sqrtf(fmaxf(s2 * (1.f / 512.f) - gmean * gmean, 0.f));

    const float hm = wred_sum(hsum) * (1.f / 256.f);
    float pv = 0.f;
    #pragma unroll
    for (int i = 0; i < 4; ++i) { float d = hv[i] - hm; pv = fmaf(d, d, pv); }
    const float hrstd = rsqrtf(wred_sum(pv) * (1.f / 256.f) + 1e-5f);
    #pragma unroll
    for (int i = 0; i < 4; ++i) {
        int k = lane + 64 * i;
        P.ln_a[(size_t)row * 320 + k] = f2b((hv[i] - hm) * hrstd * w_slg[k] + w_slb[k]);
    }

    float tg[8];
    #pragma unroll
    for (int j = 0; j < 8; ++j) tg[j] = gv[j];
    float myv = 0.f, sumtv = 0.f; int myi = 0;
    for (int r8 = 0; r8 < 8; ++r8) {
        float bv = -1e30f; int bi = 0x7fffffff;
        #pragma unroll
        for (int j = 0; j < 8; ++j) {
            int idx = lane + 64 * j;
            if (tg[j] > bv || (tg[j] == bv && idx < bi)) { bv = tg[j]; bi = idx; }
        }
        #pragma unroll
        for (int off = 32; off > 0; off >>= 1) {
            float ov = __shfl_xor(bv, off);
            int oi = __shfl_xor(bi, off);
            if (ov > bv || (ov == bv && oi < bi)) { bv = ov; bi = oi; }
        }
        sumtv += bv;
        if (lane == r8) { myv = bv; myi = bi; }
        if ((bi & 63) == lane) {
            int oj = bi >> 6;
            #pragma unroll
            for (int j = 0; j < 8; ++j) if (j == oj) tg[j] = -1e30f;
        }
    }

    float th[16];
    #pragma unroll
    for (int s = 0; s < 16; ++s) th[s] = 0.f;
    if (lane < 8) {
        float xi = b2f(P.x_in[(size_t)row * 512 + myi]);
        float xw = xi * (myv / (sumtv + 1e-6f));
        #pragma unroll
        for (int s = 0; s < 16; ++s)
            th[s] = fmaxf(fmaf(xw, w_t1[s], w_tb1[s]), 0.f);
    }
    #pragma unroll
    for (int s = 0; s < 16; ++s) {
        th[s] += __shfl_xor(th[s], 1);
        th[s] += __shfl_xor(th[s], 2);
        th[s] += __shfl_xor(th[s], 4);
    }
    const int tt = lane & 15;
    float zacc = w_tb2[tt];
    #pragma unroll
    for (int s = 0; s < 16; ++s)
        zacc = fmaf(__shfl(th[s], 0), w_t2[s * 16 + tt], zacc);
    const float ztl = zacc * 0.125f;

    float ps = hsum + ((lane < 16) ? ztl : 0.f);
    const float sm = wred_sum(ps) * (1.f / 272.f);
    float pv2 = 0.f;
    #pragma unroll
    for (int i = 0; i < 4; ++i) { float d = hv[i] - sm; pv2 = fmaf(d, d, pv2); }
    if (lane < 16) { float d = ztl - sm; pv2 = fmaf(d, d, pv2); }
    const float srstd = rsqrtf(wred_sum(pv2) * (1.f / 272.f) + 1e-5f);
    #pragma unroll
    for (int i = 0; i < 4; ++i) {
        int k = lane + 64 * i;
        P.ln_b[(size_t)row * 320 + k] = f2b((hv[i] - sm) * srstd * w_plg[k] + w_plb[k]);
    }
    if (lane < 16) {
        int k = 256 + lane;
        P.ln_b[(size_t)row * 320 + k] = f2b((ztl - sm) * srstd * w_plg[k] + w_plb[k]);
    } else {
        P.ln_b[(size_t)row * 320 + 256 + lane] = 0;
    }

    float* sc = P.scal + (size_t)row * 32;
    if (lane < 16) sc[8 + lane] = ztl;
    if (lane == 0) { sc[0] = yb; sc[1] = gmean; sc[2] = mx; sc[3] = gstd; }
}

// ---------------- mid_k (unchanged from R10) ----------------
struct MidArgs {
    const u16 *h;
    const float *scal_in;
    const u16 *sh, *sph;
    const void *safe_W2, *safe_b2, *spec_W2, *spec_b2;
    const void *conf_ln_g, *conf_ln_b;
    u16 *ln_c;
    float *scal;
    const int *flag;
};

__global__ __launch_bounds__(256, 4) void mid_k(MidArgs P) {
    __shared__ float w_clg[278], w_clb[278], w_sw2[128], w_spw2[68];
    const int isb = *P.flag;
    const int tid = threadIdx.x;
    const int wid = tid >> 6;
    const int lane = tid & 63;
    const int row = blockIdx.x * 4 + wid;

    if (tid < 278) { w_clg[tid] = ldf(P.conf_ln_g, tid, isb); w_clb[tid] = ldf(P.conf_ln_b, tid, isb); }
    if (tid < 128) w_sw2[tid]  = ldf(P.safe_W2, tid, isb);
    if (tid < 68)  w_spw2[tid] = ldf(P.spec_W2, tid, isb);
    __syncthreads();

    float s0 = b2f(P.sh[(size_t)row * 128 + lane]);
    float s1 = b2f(P.sh[(size_t)row * 128 + 64 + lane]);
    float psafe = s0 * w_sw2[lane] + s1 * w_sw2[64 + lane];
    const float dsafe = wred_sum(psafe) + ldf(P.safe_b2, 0, isb);

    float p0 = b2f(P.sph[(size_t)row * 128 + lane]) * ((lane < 68) ? w_spw2[lane] : 0.f);
    if (lane < 4) p0 += b2f(P.sph[(size_t)row * 128 + 64 + lane]) * w_spw2[64 + lane];
    const float dspec = wred_sum(p0) + ldf(P.spec_b2, 0, isb);

    const float* sc = P.scal_in + (size_t)row * 32;
    const float yb = sc[0], gmean = sc[1], mx = sc[2], gstd = sc[3];
    const float ztl = (lane < 16) ? sc[8 + lane] : 0.f;

    float hv[4];
    #pragma unroll
    for (int i = 0; i < 4; ++i) hv[i] = b2f(P.h[(size_t)row * 256 + lane + 64 * i]);
    const float hsum = hv[0] + hv[1] + hv[2] + hv[3];

    const float ads = fabsf(dsafe), adsp = fabsf(dspec);
    float pc = hsum + ((lane < 16) ? ztl : 0.f)
             + ((lane == 0) ? (yb + gmean + mx + gstd + ads + adsp) : 0.f);
    const float cm = wred_sum(pc) * (1.f / 278.f);
    float pv3 = 0.f;
    #pragma unroll
    for (int i = 0; i < 4; ++i) { float d = hv[i] - cm; pv3 = fmaf(d, d, pv3); }
    if (lane < 16) { float d = ztl - cm; pv3 = fmaf(d, d, pv3); }
    if (lane == 0) {
        float vals[6] = { yb, gmean, mx, gstd, ads, adsp };
        #pragma unroll
        for (int q = 0; q < 6; ++q) { float d = vals[q] - cm; pv3 = fmaf(d, d, pv3); }
    }
    const float crstd = rsqrtf(wred_sum(pv3) * (1.f / 278.f) + 1e-5f);

    u16* la = P.ln_c + (size_t)row * 320;
    #pragma unroll
    for (int i = 0; i < 4; ++i) {
        int k = lane + 64 * i;
        la[k] = f2b((hv[i] - cm) * crstd * w_clg[k] + w_clb[k]);
    }
    if (lane < 16) {
        int k = 260 + lane;
        la[k] = f2b((ztl - cm) * crstd * w_clg[k] + w_clb[k]);
    } else if (lane >= 18 && lane < 60) {
        la[260 + lane] = 0;
    }
    if (lane == 0) {
        float vals[6] = { yb, gmean, mx, gstd, ads, adsp };
        int idxs[6] = { 256, 257, 258, 259, 276, 277 };
        #pragma unroll
        for (int q = 0; q < 6; ++q) {
            int k = idxs[q];
            la[k] = f2b((vals[q] - cm) * crstd * w_clg[k] + w_clb[k]);
        }
        float* so = P.scal + (size_t)row * 32;
        so[4] = dsafe; so[5] = dspec;
    }
}

// ---------------- post_k ----------------
__global__ __launch_bounds__(256, 4) void post_k(
    const u16* __restrict__ ch, const float* __restrict__ scal,
    const void* __restrict__ conf_W2, const void* __restrict__ conf_b2,
    void* __restrict__ out, const int* __restrict__ flag)
{
    __shared__ float w_cw2[69];
    const int isb = *flag;
    const int tid = threadIdx.x;
    const int wid = tid >> 6;
    const int lane = tid & 63;
    const int row = blockIdx.x * 4 + wid;

    if (tid < 69) w_cw2[tid] = ldf(conf_W2, tid, isb);
    __syncthreads();

    float c0 = b2f(ch[(size_t)row * 128 + lane]) * ((lane < 69) ? w_cw2[lane] : 0.f);
    if (lane < 5) c0 += b2f(ch[(size_t)row * 128 + 64 + lane]) * w_cw2[64 + lane];
    const float zlin = wred_sum(c0) + ldf(conf_b2, 0, isb);
    const float gamma = 1.f / (1.f + expf(-zlin));
    if (lane == 0) {
        const float* sc = scal + (size_t)row * 32;
        float v = sc[0] + sc[4] + gamma * sc[5];
        if (isb) ((u16*)out)[row] = f2b(v);
        else     ((float*)out)[row] = v;
    }
}

extern "C" void kernel_launch(void* const* d_in, const int* in_sizes, int n_in,
                              void* d_out, int out_size, void* d_ws, size_t ws_size,
                              hipStream_t stream) {
    (void)in_sizes; (void)n_in; (void)out_size; (void)ws_size;
    const void* x_num = d_in[0];

    char* p = (char*)d_ws;
    auto alloc = [&](size_t bytes) { char* r = p; p += (bytes + 15) & ~(size_t)15; return r; };

    // total footprint ~127.2 MB (< 140.8 MB proven-safe)
    int*   flag    = (int*)alloc(16);
    float* bpsT    = (float*)alloc(8 * 512 * 4);
    float* bwT     = (float*)alloc(36 * 512 * 4);
    float* bbT     = (float*)alloc(4 * 512 * 4);
    float* biasbuf = (float*)alloc(2176 * 4);
    u16*   Wbuf    = (u16*)alloc((size_t)W_TOTAL * 2);
    u16*   ebuf    = (u16*)alloc((size_t)(B_ROWS / 2) * 2048 * 2);  // later g bf16
    u16*   x_in    = (u16*)alloc((size_t)B_ROWS * 512 * 2);
    u16*   hid1    = (u16*)alloc((size_t)B_ROWS * 256 * 2);         // later chh
    u16*   hbuf    = (u16*)alloc((size_t)B_ROWS * 256 * 2);
    u16*   ln_a    = (u16*)alloc((size_t)B_ROWS * 320 * 2);
    u16*   ln_b    = (u16*)alloc((size_t)B_ROWS * 320 * 2);
    float* scal    = (float*)alloc((size_t)B_ROWS * 32 * 4);
    u16*   sh      = (u16*)alloc((size_t)B_ROWS * 128 * 2);
    u16*   sph     = (u16*)alloc((size_t)B_ROWS * 128 * 2);
    u16*   xg      = (u16*)alloc((size_t)B_ROWS * 512 * 2);
    u16*   hid2    = (u16*)alloc((size_t)B_ROWS * 256 * 2);

    u16*   g   = ebuf;      // bf16, 16.8 MB <= ebuf's 33.5 MB
    u16*   chh = hid1;

    {
        PrepArgs pr;
        pr.xnum = x_num;
        pr.pW = d_in[5];  pr.gW1 = d_in[7];  pr.gW2 = d_in[9];
        pr.bW1 = d_in[11]; pr.bW2 = d_in[13]; pr.sW1 = d_in[19];
        pr.spW = d_in[29]; pr.cfW = d_in[35];
        pr.pb = d_in[6];  pr.g1 = d_in[8];  pr.g2 = d_in[10];
        pr.b1 = d_in[12]; pr.b2 = d_in[14]; pr.sb = d_in[20];
        pr.spb = d_in[30]; pr.cfb = d_in[36];
        pr.bwt = d_in[1]; pr.bbias = d_in[2];
        pr.bp_min = d_in[3]; pr.bp_dr = d_in[4];
        pr.Wbuf = Wbuf; pr.biasbuf = biasbuf;
        pr.bwT = bwT; pr.bbT = bbT; pr.bpsT = bpsT;
        pr.flag = flag;
        prep_all_k<<<NB_REPACK + 9 + 72 + 2, 256, 0, stream>>>(pr);
    }

    const int HR = B_ROWS / 2;  // 8192
    for (int half = 0; half < 2; ++half) {
        int rowoff = half * HR;
        emb_k<<<(HR * D_FEAT / 4) / 256, 256, 0, stream>>>(
            x_num, bwT, bbT, bpsT, ebuf, flag, rowoff);
        mgemm_k<0><<<dim3(HR / 64, 8), 256, 0, stream>>>(
            ebuf, Wbuf + WO_PROJ, biasbuf + 0, x_in, x_num, nullptr,
            512, 2048, 2048, 2048, rowoff, flag);
    }

    mgemm_k<1><<<dim3(B_ROWS / 64, 4), 256, 0, stream>>>(
        x_in, Wbuf + WO_GW1, biasbuf + 512, hid1, nullptr, nullptr,
        256, 512, 512, 512, 0, flag);
    mgemm_k<2><<<dim3(B_ROWS / 64, 8), 256, 0, stream>>>(
        hid1, Wbuf + WO_GW2, biasbuf + 768, g, x_in, xg,
        512, 256, 256, 256, 0, flag);
    mgemm_k<1><<<dim3(B_ROWS / 64, 4), 256, 0, stream>>>(
        xg, Wbuf + WO_BW1, biasbuf + 1280, hid2, nullptr, nullptr,
        256, 512, 512, 512, 0, flag);
    mgemm_k<1><<<dim3(B_ROWS / 64, 4), 256, 0, stream>>>(
        hid2, Wbuf + WO_BW2, biasbuf + 1536, hbuf, nullptr, nullptr,
        256, 256, 256, 256, 0, flag);

    {
        PreArgs pa;
        pa.x_in = x_in; pa.g = g; pa.h = hbuf;
        pa.base_W = d_in[15]; pa.base_b = d_in[16];
        pa.safe_ln_g = d_in[17]; pa.safe_ln_b = d_in[18];
        pa.top_W1 = d_in[23]; pa.top_b1 = d_in[24];
        pa.top_W2 = d_in[25]; pa.top_b2 = d_in[26];
        pa.spec_ln_g = d_in[27]; pa.spec_ln_b = d_in[28];
        pa.ln_a = ln_a; pa.ln_b = ln_b; pa.scal = scal; pa.flag = flag;
        pre_k<<<B_ROWS / 4, 256, 0, stream>>>(pa);
    }

    mgemm_k<1><<<dim3(B_ROWS / 64, 2), 256, 0, stream>>>(
        ln_a, Wbuf + WO_SW1, biasbuf + 1792, sh, nullptr, nullptr,
        128, 256, 320, 256, 0, flag);
    mgemm_k<1><<<dim3(B_ROWS / 64, 2), 256, 0, stream>>>(
        ln_b, Wbuf + WO_SPW, biasbuf + 1920, sph, nullptr, nullptr,
        128, 320, 320, 320, 0, flag);

    {
        MidArgs ma;
        ma.h = hbuf; ma.scal_in = scal; ma.sh = sh; ma.sph = sph;
        ma.safe_W2 = d_in[21]; ma.safe_b2 = d_in[22];
        ma.spec_W2 = d_in[31]; ma.spec_b2 = d_in[32];
        ma.conf_ln_g = d_in[33]; ma.conf_ln_b = d_in[34];
        ma.ln_c = ln_a; ma.scal = scal; ma.flag = flag;
        mid_k<<<B_ROWS / 4, 256, 0, stream>>>(ma);
    }

    mgemm_k<1><<<dim3(B_ROWS / 64, 2), 256, 0, stream>>>(
        ln_a, Wbuf + WO_CFW, biasbuf + 2048, chh, nullptr, nullptr,
        128, 320, 320, 320, 0, flag);

    post_k<<<B_ROWS / 4, 256, 0, stream>>>(chh, scal, d_in[37], d_in[38], d_out, flag);
}

// Round 12
// 451.219 us; speedup vs baseline: 1.2085x; 1.0062x over previous
//
#include <hip/hip_runtime.h>
#include <cstddef>

typedef unsigned short u16;
typedef unsigned int   u32;
typedef short bf16x8 __attribute__((ext_vector_type(8)));
typedef float f32x4 __attribute__((ext_vector_type(4)));

#define B_ROWS 16384
#define D_FEAT 512
#define NB_    8

static __device__ __forceinline__ float b2f(u16 h) {
    union { u32 u; float f; } v; v.u = ((u32)h) << 16; return v.f;
}
static __device__ __forceinline__ u16 f2b(float f) {
    union { float f; u32 u; } v; v.f = f;
    u32 r = (v.u + 0x7fffu + ((v.u >> 16) & 1u)) >> 16;
    return (u16)r;
}
static __device__ __forceinline__ float ldf(const void* p, size_t i, int isb) {
    return isb ? b2f(((const u16*)p)[i]) : ((const float*)p)[i];
}
static __device__ __forceinline__ u16 cvtb(const void* p, size_t i, int isb) {
    return isb ? ((const u16*)p)[i] : f2b(((const float*)p)[i]);
}
static __device__ __forceinline__ float wred_sum(float v) {
    #pragma unroll
    for (int off = 32; off > 0; off >>= 1) v += __shfl_xor(v, off);
    return v;
}
static __device__ __forceinline__ float wred_max(float v) {
    #pragma unroll
    for (int off = 32; off > 0; off >>= 1) v = fmaxf(v, __shfl_xor(v, off));
    return v;
}
static __device__ __forceinline__ void async_copy16(const u16* g, u16* l) {
    __builtin_amdgcn_global_load_lds(
        (const __attribute__((address_space(1))) u32*)g,
        (__attribute__((address_space(3))) u32*)l, 16, 0, 0);
}
static __device__ __forceinline__ int detect_isb(const void* xnum) {
    int lane = threadIdx.x & 63;
    u16 h = ((const u16*)xnum)[lane * 2];
    int e = (h >> 7) & 0xff;
    unsigned long long m = __ballot(e >= 110 && e <= 132);
    return (__popcll(m) >= 32) ? 1 : 0;
}

// Wbuf element offsets — ALL K-MAJOR: Bt[n][k], K padded to x64
#define WO_PROJ 0
#define WO_GW1  1048576
#define WO_GW2  1179648
#define WO_BW1  1310720
#define WO_BW2  1441792
#define WO_SW1  1507328
#define WO_SPW  1540096
#define WO_CFW  1581056
#define W_TOTAL 1622016

// ---------------- tiled LDS transpose: 6 dense repacks, coalesced both sides ----
// tiles: proj 256, gW1 32, gW2 32, bW1 32, bW2 16, sW1 8  => 376 blocks
struct TransArgs {
    const void *xnum;
    const void *src[6];
    u16 *Wbuf;
};

__global__ __launch_bounds__(256) void transW_k(TransArgs P) {
    __shared__ int s_isb;
    __shared__ u16 tile[64][68];
    if (threadIdx.x < 64) { int r = detect_isb(P.xnum); if ((threadIdx.x & 63) == 0) s_isb = r; }
    __syncthreads();
    const int isb = s_isb;
    const int tid = threadIdx.x;

    const int Ks[6]   = {2048, 512, 256, 512, 256, 256};
    const int Nss[6]  = {512, 256, 512, 256, 256, 128};
    const int offs[6] = {WO_PROJ, WO_GW1, WO_GW2, WO_BW1, WO_BW2, WO_SW1};

    int bid = blockIdx.x, m = 0;
    #pragma unroll
    for (int i = 0; i < 6; ++i) {
        int nt = (Ks[i] >> 6) * (Nss[i] >> 6);
        if (bid >= nt && m == i) { bid -= nt; m = i + 1; }
    }
    const int K = Ks[m], N = Nss[m];
    const int ktiles = K >> 6;
    const int tn = bid / ktiles, tk = bid % ktiles;
    const int k0 = tk * 64, n0 = tn * 64;
    const void* src = P.src[m];
    u16* dst = P.Wbuf + offs[m];

    // read: lanes sweep n (coalesced); 4 k-rows per pass
    #pragma unroll
    for (int p = 0; p < 16; ++p) {
        int kk = p * 4 + (tid >> 6);
        int nn = tid & 63;
        tile[kk][nn] = cvtb(src, (size_t)(k0 + kk) * N + n0 + nn, isb);
    }
    __syncthreads();
    // write: lanes sweep k (coalesced u16)
    #pragma unroll
    for (int p = 0; p < 16; ++p) {
        int nn = p * 4 + (tid >> 6);
        int kk = tid & 63;
        dst[(size_t)(n0 + nn) * K + k0 + kk] = tile[kk][nn];
    }
}

// ---------------- slim prep: spW/cfW pad + bias + embT + bps + flag ----------
#define NB_SPW 160   // 128*320/256
struct PrepArgs {
    const void *xnum;
    const void *spW, *cfW;
    const void *pb, *g1, *g2, *b1, *b2, *sb, *spb, *cfb;
    const void *bwt, *bbias, *bp_min, *bp_dr;
    u16 *Wbuf; float *biasbuf, *bwT, *bbT, *bpsT;
    int *flag;
};

__global__ __launch_bounds__(256) void prep_all_k(PrepArgs P) {
    __shared__ int s_isb;
    if (threadIdx.x < 64) { int r = detect_isb(P.xnum); if ((threadIdx.x & 63) == 0) s_isb = r; }
    __syncthreads();
    const int isb = s_isb;
    const int bid = blockIdx.x;
    const int tid = threadIdx.x;

    if (bid < NB_SPW) {                               // spW [128 n][320 k]
        size_t i = (size_t)bid * 256 + tid;
        int n = (int)(i / 320), k = (int)(i % 320);
        P.Wbuf[WO_SPW + i] =
            (n < 68 && k < 272) ? cvtb(P.spW, (size_t)k * 68 + n, isb) : (u16)0;
    } else if (bid < 2 * NB_SPW) {                    // cfW [128 n][320 k]
        size_t i = (size_t)(bid - NB_SPW) * 256 + tid;
        int n = (int)(i / 320), k = (int)(i % 320);
        P.Wbuf[WO_CFW + i] =
            (n < 69 && k < 278) ? cvtb(P.cfW, (size_t)k * 69 + n, isb) : (u16)0;
    } else if (bid < 2 * NB_SPW + 9) {                // biases
        int t = (bid - 2 * NB_SPW) * 256 + tid;
        float* out = P.biasbuf;
        if      (t < 512)  out[t] = ldf(P.pb, t, isb);
        else if (t < 768)  out[t] = ldf(P.g1, t - 512, isb);
        else if (t < 1280) out[t] = ldf(P.g2, t - 768, isb);
        else if (t < 1536) out[t] = ldf(P.b1, t - 1280, isb);
        else if (t < 1792) out[t] = ldf(P.b2, t - 1536, isb);
        else if (t < 1920) out[t] = ldf(P.sb, t - 1792, isb);
        else if (t < 2048) { int c = t - 1920; out[t] = (c < 68) ? ldf(P.spb, c, isb) : 0.f; }
        else if (t < 2176) { int c = t - 2048; out[t] = (c < 69) ? ldf(P.cfb, c, isb) : 0.f; }
    } else if (bid < 2 * NB_SPW + 9 + 72) {           // embT
        int t = (bid - 2 * NB_SPW - 9) * 256 + tid;
        if (t < 512 * 36) {
            int d = t / 36, j = t % 36;
            P.bwT[j * 512 + d] = ldf(P.bwt, t, isb);
        }
        if (t < 2048) {
            int d = t >> 2, e = t & 3;
            P.bbT[e * 512 + d] = ldf(P.bbias, t, isb);
        }
    } else {                                          // bps + flag
        int d = (bid - 2 * NB_SPW - 9 - 72) * 256 + tid;
        if (d < D_FEAT) {
            float bp = ldf(P.bp_min, d, isb);
            #pragma unroll
            for (int k = 0; k < NB_; ++k) {
                float x = ldf(P.bp_dr, d * NB_ + k, isb);
                bp += fmaxf(x, 0.f) + log1pf(expf(-fabsf(x)));
                P.bpsT[k * 512 + d] = bp;
            }
        }
        if (d == 0) *P.flag = isb;
    }
}

// ---------------- embedding (half-batch), 4 elements/thread ----------------
__global__ __launch_bounds__(256) void emb_k(
    const void* __restrict__ xnum, const float* __restrict__ bwT,
    const float* __restrict__ bbT, const float* __restrict__ bpsT,
    u16* __restrict__ emb, const int* __restrict__ flag, int rowoff)
{
    const int isb = *flag;
    size_t gi = ((size_t)blockIdx.x * 256 + threadIdx.x) * 4;
    int d0 = (int)(gi & 511);
    float xv[4];
    if (isb) {
        u16 tmp[4];
        *(uint2*)tmp = *(const uint2*)((const u16*)xnum + (size_t)rowoff * 512 + gi);
        #pragma unroll
        for (int i = 0; i < 4; ++i) xv[i] = b2f(tmp[i]);
    } else {
        float4 f = *(const float4*)((const float*)xnum + (size_t)rowoff * 512 + gi);
        xv[0] = f.x; xv[1] = f.y; xv[2] = f.z; xv[3] = f.w;
    }
    float acc[4][4];
    #pragma unroll
    for (int e = 0; e < 4; ++e) {
        float4 b = *(const float4*)&bbT[e * 512 + d0];
        acc[0][e] = b.x; acc[1][e] = b.y; acc[2][e] = b.z; acc[3][e] = b.w;
    }
    #pragma unroll
    for (int f = 0; f <= 8; ++f) {
        float bv[4];
        if (f == 0) {
            #pragma unroll
            for (int i = 0; i < 4; ++i) bv[i] = xv[i];
        } else {
            float4 bp = *(const float4*)&bpsT[(f - 1) * 512 + d0];
            bv[0] = fmaxf(xv[0] - bp.x, 0.f); bv[1] = fmaxf(xv[1] - bp.y, 0.f);
            bv[2] = fmaxf(xv[2] - bp.z, 0.f); bv[3] = fmaxf(xv[3] - bp.w, 0.f);
        }
        #pragma unroll
        for (int e = 0; e < 4; ++e) {
            float4 w = *(const float4*)&bwT[(f * 4 + e) * 512 + d0];
            acc[0][e] = fmaf(bv[0], w.x, acc[0][e]);
            acc[1][e] = fmaf(bv[1], w.y, acc[1][e]);
            acc[2][e] = fmaf(bv[2], w.z, acc[2][e]);
            acc[3][e] = fmaf(bv[3], w.w, acc[3][e]);
        }
    }
    u16 o[16];
    #pragma unroll
    for (int i = 0; i < 4; ++i)
        #pragma unroll
        for (int e = 0; e < 4; ++e) o[i * 4 + e] = f2b(acc[i][e]);
    *(uint4*)&emb[gi * 4]     = *(const uint4*)&o[0];
    *(uint4*)&emb[gi * 4 + 8] = *(const uint4*)&o[8];
}

// ---------------- bf16 MFMA GEMM: 64x64 tile, DMA dbuf, XOR swizzle ----------
template<int EMODE>
__global__ __launch_bounds__(256) void mgemm_k(
    const u16* __restrict__ A, const u16* __restrict__ Bt,
    const float* __restrict__ bias,
    void* __restrict__ out0, const void* __restrict__ aux0, void* __restrict__ aux1,
    int N, int Kdim, int lda, int ldk, int rowoff, const int* __restrict__ flagp)
{
    __shared__ __align__(16) u16 As[2][64][64];
    __shared__ __align__(16) u16 Bs[2][64][64];

    const int isb = (EMODE == 0) ? *flagp : 0;
    const int tid = threadIdx.x;
    const int row0 = blockIdx.x * 64, col0 = blockIdx.y * 64;
    const int w = tid >> 6, lane = tid & 63, q = lane >> 4, mr = lane & 15;
    const int wr = (w >> 1) * 32, wc = (w & 1) * 32;
    const int rr = lane >> 3, kg = lane & 7;
    const int sc = kg ^ (rr & 7);

    f32x4 acc[2][2];
    #pragma unroll
    for (int a = 0; a < 2; ++a)
        #pragma unroll
        for (int b = 0; b < 2; ++b) acc[a][b] = (f32x4){0.f, 0.f, 0.f, 0.f};

    const int T = Kdim >> 6;

    auto stage = [&](int kt, int bi) {
        if (w < 2) {
            #pragma unroll
            for (int j = 0; j < 4; ++j) {
                int m = w * 32 + j * 8;
                async_copy16(A + (size_t)(row0 + m + rr) * lda + kt + sc * 8,
                             &As[bi][m][0]);
            }
        } else {
            #pragma unroll
            for (int j = 0; j < 4; ++j) {
                int m = (w - 2) * 32 + j * 8;
                async_copy16(Bt + (size_t)(col0 + m + rr) * ldk + kt + sc * 8,
                             &Bs[bi][m][0]);
            }
        }
    };

    stage(0, 0);
    __syncthreads();

    for (int t = 0; t < T; ++t) {
        if (t + 1 < T) stage((t + 1) << 6, (t + 1) & 1);
        const int cb = t & 1;
        #pragma unroll
        for (int ks = 0; ks < 2; ++ks) {
            bf16x8 af[2], bf[2];
            #pragma unroll
            for (int rs = 0; rs < 2; ++rs) {
                int r = wr + rs * 16 + mr;
                int pc = (ks * 4 + q) ^ (r & 7);
                af[rs] = *(const bf16x8*)&As[cb][r][pc * 8];
            }
            #pragma unroll
            for (int nt = 0; nt < 2; ++nt) {
                int r = wc + nt * 16 + mr;
                int pc = (ks * 4 + q) ^ (r & 7);
                bf[nt] = *(const bf16x8*)&Bs[cb][r][pc * 8];
            }
            #pragma unroll
            for (int rs = 0; rs < 2; ++rs)
                #pragma unroll
                for (int nt = 0; nt < 2; ++nt)
                    acc[rs][nt] = __builtin_amdgcn_mfma_f32_16x16x32_bf16(
                        af[rs], bf[nt], acc[rs][nt], 0, 0, 0);
        }
        __syncthreads();
    }

    #pragma unroll
    for (int rs = 0; rs < 2; ++rs) {
        #pragma unroll
        for (int i = 0; i < 4; ++i) {
            size_t gr = (size_t)rowoff + row0 + wr + rs * 16 + q * 4 + i;
            #pragma unroll
            for (int nt = 0; nt < 2; ++nt) {
                int c = col0 + wc + nt * 16 + mr;
                float z = acc[rs][nt][i] + bias[c];
                size_t idx = gr * (size_t)N + c;
                if (EMODE == 0) {
                    ((u16*)out0)[idx] = f2b(ldf(aux0, idx, isb) + 0.1f * z);
                } else if (EMODE == 1) {
                    ((u16*)out0)[idx] = f2b(fmaxf(z, 0.f));
                } else {
                    float gv = 1.f / (1.f + expf(-z));
                    ((u16*)out0)[idx] = f2b(gv);
                    ((u16*)aux1)[idx] = f2b(b2f(((const u16*)aux0)[idx]) * gv);
                }
            }
        }
    }
}

// ---------------- fused pair GEMM (relu->bf16): safe (x<nx1) | spec ----------
__global__ __launch_bounds__(256) void mgemm_pair_k(
    const u16* __restrict__ A1, const u16* __restrict__ B1,
    const float* __restrict__ bias1, u16* __restrict__ out1,
    int K1, int lda1, int ldk1,
    const u16* __restrict__ A2, const u16* __restrict__ B2,
    const float* __restrict__ bias2, u16* __restrict__ out2,
    int K2, int lda2, int ldk2,
    int N, int nx1)
{
    __shared__ __align__(16) u16 As[2][64][64];
    __shared__ __align__(16) u16 Bs[2][64][64];

    const int tid = threadIdx.x;
    const bool sec = blockIdx.x >= nx1;
    const u16* A = sec ? A2 : A1;
    const u16* Bt = sec ? B2 : B1;
    const float* bias = sec ? bias2 : bias1;
    u16* out0 = sec ? out2 : out1;
    const int Kdim = sec ? K2 : K1;
    const int lda = sec ? lda2 : lda1;
    const int ldk = sec ? ldk2 : ldk1;
    const int row0 = (sec ? blockIdx.x - nx1 : blockIdx.x) * 64;
    const int col0 = blockIdx.y * 64;
    const int w = tid >> 6, lane = tid & 63, q = lane >> 4, mr = lane & 15;
    const int wr = (w >> 1) * 32, wc = (w & 1) * 32;
    const int rr = lane >> 3, kg = lane & 7;
    const int sc = kg ^ (rr & 7);

    f32x4 acc[2][2];
    #pragma unroll
    for (int a = 0; a < 2; ++a)
        #pragma unroll
        for (int b = 0; b < 2; ++b) acc[a][b] = (f32x4){0.f, 0.f, 0.f, 0.f};

    const int T = Kdim >> 6;

    auto stage = [&](int kt, int bi) {
        if (w < 2) {
            #pragma unroll
            for (int j = 0; j < 4; ++j) {
                int m = w * 32 + j * 8;
                async_copy16(A + (size_t)(row0 + m + rr) * lda + kt + sc * 8,
                             &As[bi][m][0]);
            }
        } else {
            #pragma unroll
            for (int j = 0; j < 4; ++j) {
                int m = (w - 2) * 32 + j * 8;
                async_copy16(Bt + (size_t)(col0 + m + rr) * ldk + kt + sc * 8,
                             &Bs[bi][m][0]);
            }
        }
    };

    stage(0, 0);
    __syncthreads();

    for (int t = 0; t < T; ++t) {
        if (t + 1 < T) stage((t + 1) << 6, (t + 1) & 1);
        const int cb = t & 1;
        #pragma unroll
        for (int ks = 0; ks < 2; ++ks) {
            bf16x8 af[2], bf[2];
            #pragma unroll
            for (int rs = 0; rs < 2; ++rs) {
                int r = wr + rs * 16 + mr;
                int pc = (ks * 4 + q) ^ (r & 7);
                af[rs] = *(const bf16x8*)&As[cb][r][pc * 8];
            }
            #pragma unroll
            for (int nt = 0; nt < 2; ++nt) {
                int r = wc + nt * 16 + mr;
                int pc = (ks * 4 + q) ^ (r & 7);
                bf[nt] = *(const bf16x8*)&Bs[cb][r][pc * 8];
            }
            #pragma unroll
            for (int rs = 0; rs < 2; ++rs)
                #pragma unroll
                for (int nt = 0; nt < 2; ++nt)
                    acc[rs][nt] = __builtin_amdgcn_mfma_f32_16x16x32_bf16(
                        af[rs], bf[nt], acc[rs][nt], 0, 0, 0);
        }
        __syncthreads();
    }

    #pragma unroll
    for (int rs = 0; rs < 2; ++rs) {
        #pragma unroll
        for (int i = 0; i < 4; ++i) {
            size_t gr = (size_t)row0 + wr + rs * 16 + q * 4 + i;
            #pragma unroll
            for (int nt = 0; nt < 2; ++nt) {
                int c = col0 + wc + nt * 16 + mr;
                float z = acc[rs][nt][i] + bias[c];
                out0[gr * (size_t)N + c] = f2b(fmaxf(z, 0.f));
            }
        }
    }
}

// ---------------- pre_k (unchanged from R11) ----------------
struct PreArgs {
    const u16 *x_in, *g, *h;
    const void *base_W, *base_b;
    const void *safe_ln_g, *safe_ln_b;
    const void *top_W1, *top_b1, *top_W2, *top_b2;
    const void *spec_ln_g, *spec_ln_b;
    u16 *ln_a, *ln_b;
    float *scal;
    const int *flag;
};

__global__ __launch_bounds__(256, 4) void pre_k(PreArgs P) {
    __shared__ float w_base[256], w_slg[256], w_slb[256], w_t2[256];
    __shared__ float w_plg[272], w_plb[272];
    __shared__ float w_t1[16], w_tb1[16], w_tb2[16];
    const int isb = *P.flag;
    const int tid = threadIdx.x;
    const int wid = tid >> 6;
    const int lane = tid & 63;
    const int row = blockIdx.x * 4 + wid;

    w_base[tid] = ldf(P.base_W, tid, isb);
    w_slg[tid]  = ldf(P.safe_ln_g, tid, isb);
    w_slb[tid]  = ldf(P.safe_ln_b, tid, isb);
    w_t2[tid]   = ldf(P.top_W2, tid, isb);
    if (tid < 272) {
        w_plg[tid] = ldf(P.spec_ln_g, tid, isb);
        w_plb[tid] = ldf(P.spec_ln_b, tid, isb);
    }
    if (tid < 16) {
        w_t1[tid]  = ldf(P.top_W1, tid, isb);
        w_tb1[tid] = ldf(P.top_b1, tid, isb);
        w_tb2[tid] = ldf(P.top_b2, tid, isb);
    }
    __syncthreads();

    float hv[4], gv[8];
    #pragma unroll
    for (int i = 0; i < 4; ++i) hv[i] = b2f(P.h[(size_t)row * 256 + lane + 64 * i]);
    #pragma unroll
    for (int j = 0; j < 8; ++j) gv[j] = b2f(P.g[(size_t)row * 512 + lane + 64 * j]);
    const float hsum = hv[0] + hv[1] + hv[2] + hv[3];

    float pb = 0.f;
    #pragma unroll
    for (int i = 0; i < 4; ++i) pb = fmaf(hv[i], w_base[lane + 64 * i], pb);
    const float yb = wred_sum(pb) + ldf(P.base_b, 0, isb);

    float s1 = 0.f, s2 = 0.f, mx = -1e30f;
    #pragma unroll
    for (int j = 0; j < 8; ++j) { s1 += gv[j]; s2 = fmaf(gv[j], gv[j], s2); mx = fmaxf(mx, gv[j]); }
    s1 = wred_sum(s1); s2 = wred_sum(s2); mx = wred_max(mx);
    const float gmean = s1 * (1.f / 512.f);
    const float gstd = sqrtf(fmaxf(s2 * (1.f / 512.f) - gmean * gmean, 0.f));

    const float hm = wred_sum(hsum) * (1.f / 256.f);
    float pv = 0.f;
    #pragma unroll
    for (int i = 0; i < 4; ++i) { float d = hv[i] - hm; pv = fmaf(d, d, pv); }
    const float hrstd = rsqrtf(wred_sum(pv) * (1.f / 256.f) + 1e-5f);
    #pragma unroll
    for (int i = 0; i < 4; ++i) {
        int k = lane + 64 * i;
        P.ln_a[(size_t)row * 320 + k] = f2b((hv[i] - hm) * hrstd * w_slg[k] + w_slb[k]);
    }

    float tg[8];
    #pragma unroll
    for (int j = 0; j < 8; ++j) tg[j] = gv[j];
    float myv = 0.f, sumtv = 0.f; int myi = 0;
    for (int r8 = 0; r8 < 8; ++r8) {
        float bv = -1e30f; int bi = 0x7fffffff;
        #pragma unroll
        for (int j = 0; j < 8; ++j) {
            int idx = lane + 64 * j;
            if (tg[j] > bv || (tg[j] == bv && idx < bi)) { bv = tg[j]; bi = idx; }
        }
        #pragma unroll
        for (int off = 32; off > 0; off >>= 1) {
            float ov = __shfl_xor(bv, off);
            int oi = __shfl_xor(bi, off);
            if (ov > bv || (ov == bv && oi < bi)) { bv = ov; bi = oi; }
        }
        sumtv += bv;
        if (lane == r8) { myv = bv; myi = bi; }
        if ((bi & 63) == lane) {
            int oj = bi >> 6;
            #pragma unroll
            for (int j = 0; j < 8; ++j) if (j == oj) tg[j] = -1e30f;
        }
    }

    float th[16];
    #pragma unroll
    for (int s = 0; s < 16; ++s) th[s] = 0.f;
    if (lane < 8) {
        float xi = b2f(P.x_in[(size_t)row * 512 + myi]);
        float xw = xi * (myv / (sumtv + 1e-6f));
        #pragma unroll
        for (int s = 0; s < 16; ++s)
            th[s] = fmaxf(fmaf(xw, w_t1[s], w_tb1[s]), 0.f);
    }
    #pragma unroll
    for (int s = 0; s < 16; ++s) {
        th[s] += __shfl_xor(th[s], 1);
        th[s] += __shfl_xor(th[s], 2);
        th[s] += __shfl_xor(th[s], 4);
    }
    const int tt = lane & 15;
    float zacc = w_tb2[tt];
    #pragma unroll
    for (int s = 0; s < 16; ++s)
        zacc = fmaf(__shfl(th[s], 0), w_t2[s * 16 + tt], zacc);
    const float ztl = zacc * 0.125f;

    float ps = hsum + ((lane < 16) ? ztl : 0.f);
    const float sm = wred_sum(ps) * (1.f / 272.f);
    float pv2 = 0.f;
    #pragma unroll
    for (int i = 0; i < 4; ++i) { float d = hv[i] - sm; pv2 = fmaf(d, d, pv2); }
    if (lane < 16) { float d = ztl - sm; pv2 = fmaf(d, d, pv2); }
    const float srstd = rsqrtf(wred_sum(pv2) * (1.f / 272.f) + 1e-5f);
    #pragma unroll
    for (int i = 0; i < 4; ++i) {
        int k = lane + 64 * i;
        P.ln_b[(size_t)row * 320 + k] = f2b((hv[i] - sm) * srstd * w_plg[k] + w_plb[k]);
    }
    if (lane < 16) {
        int k = 256 + lane;
        P.ln_b[(size_t)row * 320 + k] = f2b((ztl - sm) * srstd * w_plg[k] + w_plb[k]);
    } else {
        P.ln_b[(size_t)row * 320 + 256 + lane] = 0;
    }

    float* sc = P.scal + (size_t)row * 32;
    if (lane < 16) sc[8 + lane] = ztl;
    if (lane == 0) { sc[0] = yb; sc[1] = gmean; sc[2] = mx; sc[3] = gstd; }
}

// ---------------- mid_k (unchanged from R11) ----------------
struct MidArgs {
    const u16 *h;
    const float *scal_in;
    const u16 *sh, *sph;
    const void *safe_W2, *safe_b2, *spec_W2, *spec_b2;
    const void *conf_ln_g, *conf_ln_b;
    u16 *ln_c;
    float *scal;
    const int *flag;
};

__global__ __launch_bounds__(256, 4) void mid_k(MidArgs P) {
    __shared__ float w_clg[278], w_clb[278], w_sw2[128], w_spw2[68];
    const int isb = *P.flag;
    const int tid = threadIdx.x;
    const int wid = tid >> 6;
    const int lane = tid & 63;
    const int row = blockIdx.x * 4 + wid;

    if (tid < 278) { w_clg[tid] = ldf(P.conf_ln_g, tid, isb); w_clb[tid] = ldf(P.conf_ln_b, tid, isb); }
    if (tid < 128) w_sw2[tid]  = ldf(P.safe_W2, tid, isb);
    if (tid < 68)  w_spw2[tid] = ldf(P.spec_W2, tid, isb);
    __syncthreads();

    float s0 = b2f(P.sh[(size_t)row * 128 + lane]);
    float s1 = b2f(P.sh[(size_t)row * 128 + 64 + lane]);
    float psafe = s0 * w_sw2[lane] + s1 * w_sw2[64 + lane];
    const float dsafe = wred_sum(psafe) + ldf(P.safe_b2, 0, isb);

    float p0 = b2f(P.sph[(size_t)row * 128 + lane]) * ((lane < 68) ? w_spw2[lane] : 0.f);
    if (lane < 4) p0 += b2f(P.sph[(size_t)row * 128 + 64 + lane]) * w_spw2[64 + lane];
    const float dspec = wred_sum(p0) + ldf(P.spec_b2, 0, isb);

    const float* sc = P.scal_in + (size_t)row * 32;
    const float yb = sc[0], gmean = sc[1], mx = sc[2], gstd = sc[3];
    const float ztl = (lane < 16) ? sc[8 + lane] : 0.f;

    float hv[4];
    #pragma unroll
    for (int i = 0; i < 4; ++i) hv[i] = b2f(P.h[(size_t)row * 256 + lane + 64 * i]);
    const float hsum = hv[0] + hv[1] + hv[2] + hv[3];

    const float ads = fabsf(dsafe), adsp = fabsf(dspec);
    float pc = hsum + ((lane < 16) ? ztl : 0.f)
             + ((lane == 0) ? (yb + gmean + mx + gstd + ads + adsp) : 0.f);
    const float cm = wred_sum(pc) * (1.f / 278.f);
    float pv3 = 0.f;
    #pragma unroll
    for (int i = 0; i < 4; ++i) { float d = hv[i] - cm; pv3 = fmaf(d, d, pv3); }
    if (lane < 16) { float d = ztl - cm; pv3 = fmaf(d, d, pv3); }
    if (lane == 0) {
        float vals[6] = { yb, gmean, mx, gstd, ads, adsp };
        #pragma unroll
        for (int q = 0; q < 6; ++q) { float d = vals[q] - cm; pv3 = fmaf(d, d, pv3); }
    }
    const float crstd = rsqrtf(wred_sum(pv3) * (1.f / 278.f) + 1e-5f);

    u16* la = P.ln_c + (size_t)row * 320;
    #pragma unroll
    for (int i = 0; i < 4; ++i) {
        int k = lane + 64 * i;
        la[k] = f2b((hv[i] - cm) * crstd * w_clg[k] + w_clb[k]);
    }
    if (lane < 16) {
        int k = 260 + lane;
        la[k] = f2b((ztl - cm) * crstd * w_clg[k] + w_clb[k]);
    } else if (lane >= 18 && lane < 60) {
        la[260 + lane] = 0;
    }
    if (lane == 0) {
        float vals[6] = { yb, gmean, mx, gstd, ads, adsp };
        int idxs[6] = { 256, 257, 258, 259, 276, 277 };
        #pragma unroll
        for (int q = 0; q < 6; ++q) {
            int k = idxs[q];
            la[k] = f2b((vals[q] - cm) * crstd * w_clg[k] + w_clb[k]);
        }
        float* so = P.scal + (size_t)row * 32;
        so[4] = dsafe; so[5] = dspec;
    }
}

// ---------------- post_k ----------------
__global__ __launch_bounds__(256, 4) void post_k(
    const u16* __restrict__ ch, const float* __restrict__ scal,
    const void* __restrict__ conf_W2, const void* __restrict__ conf_b2,
    void* __restrict__ out, const int* __restrict__ flag)
{
    __shared__ float w_cw2[69];
    const int isb = *flag;
    const int tid = threadIdx.x;
    const int wid = tid >> 6;
    const int lane = tid & 63;
    const int row = blockIdx.x * 4 + wid;

    if (tid < 69) w_cw2[tid] = ldf(conf_W2, tid, isb);
    __syncthreads();

    float c0 = b2f(ch[(size_t)row * 128 + lane]) * ((lane < 69) ? w_cw2[lane] : 0.f);
    if (lane < 5) c0 += b2f(ch[(size_t)row * 128 + 64 + lane]) * w_cw2[64 + lane];
    const float zlin = wred_sum(c0) + ldf(conf_b2, 0, isb);
    const float gamma = 1.f / (1.f + expf(-zlin));
    if (lane == 0) {
        const float* sc = scal + (size_t)row * 32;
        float v = sc[0] + sc[4] + gamma * sc[5];
        if (isb) ((u16*)out)[row] = f2b(v);
        else     ((float*)out)[row] = v;
    }
}

extern "C" void kernel_launch(void* const* d_in, const int* in_sizes, int n_in,
                              void* d_out, int out_size, void* d_ws, size_t ws_size,
                              hipStream_t stream) {
    (void)in_sizes; (void)n_in; (void)out_size; (void)ws_size;
    const void* x_num = d_in[0];

    char* p = (char*)d_ws;
    auto alloc = [&](size_t bytes) { char* r = p; p += (bytes + 15) & ~(size_t)15; return r; };

    // total footprint ~127.2 MB (< 140.8 MB proven-safe)
    int*   flag    = (int*)alloc(16);
    float* bpsT    = (float*)alloc(8 * 512 * 4);
    float* bwT     = (float*)alloc(36 * 512 * 4);
    float* bbT     = (float*)alloc(4 * 512 * 4);
    float* biasbuf = (float*)alloc(2176 * 4);
    u16*   Wbuf    = (u16*)alloc((size_t)W_TOTAL * 2);
    u16*   ebuf    = (u16*)alloc((size_t)(B_ROWS / 2) * 2048 * 2);  // later g bf16
    u16*   x_in    = (u16*)alloc((size_t)B_ROWS * 512 * 2);
    u16*   hid1    = (u16*)alloc((size_t)B_ROWS * 256 * 2);         // later chh
    u16*   hbuf    = (u16*)alloc((size_t)B_ROWS * 256 * 2);
    u16*   ln_a    = (u16*)alloc((size_t)B_ROWS * 320 * 2);
    u16*   ln_b    = (u16*)alloc((size_t)B_ROWS * 320 * 2);
    float* scal    = (float*)alloc((size_t)B_ROWS * 32 * 4);
    u16*   sh      = (u16*)alloc((size_t)B_ROWS * 128 * 2);
    u16*   sph     = (u16*)alloc((size_t)B_ROWS * 128 * 2);
    u16*   xg      = (u16*)alloc((size_t)B_ROWS * 512 * 2);
    u16*   hid2    = (u16*)alloc((size_t)B_ROWS * 256 * 2);

    u16*   g   = ebuf;      // bf16, 16.8 MB <= ebuf's 33.5 MB
    u16*   chh = hid1;

    {
        PrepArgs pr;
        pr.xnum = x_num;
        pr.spW = d_in[29]; pr.cfW = d_in[35];
        pr.pb = d_in[6];  pr.g1 = d_in[8];  pr.g2 = d_in[10];
        pr.b1 = d_in[12]; pr.b2 = d_in[14]; pr.sb = d_in[20];
        pr.spb = d_in[30]; pr.cfb = d_in[36];
        pr.bwt = d_in[1]; pr.bbias = d_in[2];
        pr.bp_min = d_in[3]; pr.bp_dr = d_in[4];
        pr.Wbuf = Wbuf; pr.biasbuf = biasbuf;
        pr.bwT = bwT; pr.bbT = bbT; pr.bpsT = bpsT;
        pr.flag = flag;
        prep_all_k<<<2 * NB_SPW + 9 + 72 + 2, 256, 0, stream>>>(pr);

        TransArgs tr;
        tr.xnum = x_num;
        tr.src[0] = d_in[5];  tr.src[1] = d_in[7];  tr.src[2] = d_in[9];
        tr.src[3] = d_in[11]; tr.src[4] = d_in[13]; tr.src[5] = d_in[19];
        tr.Wbuf = Wbuf;
        transW_k<<<376, 256, 0, stream>>>(tr);
    }

    const int HR = B_ROWS / 2;  // 8192
    for (int half = 0; half < 2; ++half) {
        int rowoff = half * HR;
        emb_k<<<(HR * D_FEAT / 4) / 256, 256, 0, stream>>>(
            x_num, bwT, bbT, bpsT, ebuf, flag, rowoff);
        mgemm_k<0><<<dim3(HR / 64, 8), 256, 0, stream>>>(
            ebuf, Wbuf + WO_PROJ, biasbuf + 0, x_in, x_num, nullptr,
            512, 2048, 2048, 2048, rowoff, flag);
    }

    mgemm_k<1><<<dim3(B_ROWS / 64, 4), 256, 0, stream>>>(
        x_in, Wbuf + WO_GW1, biasbuf + 512, hid1, nullptr, nullptr,
        256, 512, 512, 512, 0, flag);
    mgemm_k<2><<<dim3(B_ROWS / 64, 8), 256, 0, stream>>>(
        hid1, Wbuf + WO_GW2, biasbuf + 768, g, x_in, xg,
        512, 256, 256, 256, 0, flag);
    mgemm_k<1><<<dim3(B_ROWS / 64, 4), 256, 0, stream>>>(
        xg, Wbuf + WO_BW1, biasbuf + 1280, hid2, nullptr, nullptr,
        256, 512, 512, 512, 0, flag);
    mgemm_k<1><<<dim3(B_ROWS / 64, 4), 256, 0, stream>>>(
        hid2, Wbuf + WO_BW2, biasbuf + 1536, hbuf, nullptr, nullptr,
        256, 256, 256, 256, 0, flag);

    {
        PreArgs pa;
        pa.x_in = x_in; pa.g = g; pa.h = hbuf;
        pa.base_W = d_in[15]; pa.base_b = d_in[16];
        pa.safe_ln_g = d_in[17]; pa.safe_ln_b = d_in[18];
        pa.top_W1 = d_in[23]; pa.top_b1 = d_in[24];
        pa.top_W2 = d_in[25]; pa.top_b2 = d_in[26];
        pa.spec_ln_g = d_in[27]; pa.spec_ln_b = d_in[28];
        pa.ln_a = ln_a; pa.ln_b = ln_b; pa.scal = scal; pa.flag = flag;
        pre_k<<<B_ROWS / 4, 256, 0, stream>>>(pa);
    }

    // fused: sh = relu(ln_a[:, :256] @ safe_W1) | sph = relu(ln_b @ spec_W1p)
    mgemm_pair_k<<<dim3(2 * (B_ROWS / 64), 2), 256, 0, stream>>>(
        ln_a, Wbuf + WO_SW1, biasbuf + 1792, sh, 256, 320, 256,
        ln_b, Wbuf + WO_SPW, biasbuf + 1920, sph, 320, 320, 320,
        128, B_ROWS / 64);

    {
        MidArgs ma;
        ma.h = hbuf; ma.scal_in = scal; ma.sh = sh; ma.sph = sph;
        ma.safe_W2 = d_in[21]; ma.safe_b2 = d_in[22];
        ma.spec_W2 = d_in[31]; ma.spec_b2 = d_in[32];
        ma.conf_ln_g = d_in[33]; ma.conf_ln_b = d_in[34];
        ma.ln_c = ln_a; ma.scal = scal; ma.flag = flag;
        mid_k<<<B_ROWS / 4, 256, 0, stream>>>(ma);
    }

    mgemm_k<1><<<dim3(B_ROWS / 64, 2), 256, 0, stream>>>(
        ln_a, Wbuf + WO_CFW, biasbuf + 2048, chh, nullptr, nullptr,
        128, 320, 320, 320, 0, flag);

    post_k<<<B_ROWS / 4, 256, 0, stream>>>(chh, scal, d_in[37], d_in[38], d_out, flag);
}

// Round 13
// 419.857 us; speedup vs baseline: 1.2988x; 1.0747x over previous
//
#include <hip/hip_runtime.h>
#include <cstddef>

typedef unsigned short u16;
typedef unsigned int   u32;
typedef short bf16x8 __attribute__((ext_vector_type(8)));
typedef float f32x4 __attribute__((ext_vector_type(4)));

#define B_ROWS 16384
#define D_FEAT 512
#define NB_    8

static __device__ __forceinline__ float b2f(u16 h) {
    union { u32 u; float f; } v; v.u = ((u32)h) << 16; return v.f;
}
static __device__ __forceinline__ u16 f2b(float f) {
    union { float f; u32 u; } v; v.f = f;
    u32 r = (v.u + 0x7fffu + ((v.u >> 16) & 1u)) >> 16;
    return (u16)r;
}
static __device__ __forceinline__ float ldf(const void* p, size_t i, int isb) {
    return isb ? b2f(((const u16*)p)[i]) : ((const float*)p)[i];
}
static __device__ __forceinline__ u16 cvtb(const void* p, size_t i, int isb) {
    return isb ? ((const u16*)p)[i] : f2b(((const float*)p)[i]);
}
static __device__ __forceinline__ float wred_sum(float v) {
    #pragma unroll
    for (int off = 32; off > 0; off >>= 1) v += __shfl_xor(v, off);
    return v;
}
static __device__ __forceinline__ float wred_max(float v) {
    #pragma unroll
    for (int off = 32; off > 0; off >>= 1) v = fmaxf(v, __shfl_xor(v, off));
    return v;
}
static __device__ __forceinline__ u32 umax2(u32 a, u32 b) { return a > b ? a : b; }
static __device__ __forceinline__ void async_copy16(const u16* g, u16* l) {
    __builtin_amdgcn_global_load_lds(
        (const __attribute__((address_space(1))) u32*)g,
        (__attribute__((address_space(3))) u32*)l, 16, 0, 0);
}
static __device__ __forceinline__ int detect_isb(const void* xnum) {
    int lane = threadIdx.x & 63;
    u16 h = ((const u16*)xnum)[lane * 2];
    int e = (h >> 7) & 0xff;
    unsigned long long m = __ballot(e >= 110 && e <= 132);
    return (__popcll(m) >= 32) ? 1 : 0;
}

// Wbuf element offsets — ALL K-MAJOR: Bt[n][k], K padded to x64
#define WO_PROJ 0
#define WO_GW1  1048576
#define WO_GW2  1179648
#define WO_BW1  1310720
#define WO_BW2  1441792
#define WO_SW1  1507328
#define WO_SPW  1540096
#define WO_CFW  1581056
#define W_TOTAL 1622016

// ---------------- unified prep (one dispatch):
//  blocks [0,376): tiled LDS transpose of 6 dense weights (coalesced both sides)
//  blocks [376,...): spW/cfW pad + bias + embT + bps + flag
#define NB_TRANS 376
#define NB_SPW 160   // 128*320/256
struct PrepArgs {
    const void *xnum;
    const void *src[6];                      // pW,gW1,gW2,bW1,bW2,sW1
    const void *spW, *cfW;
    const void *pb, *g1, *g2, *b1, *b2, *sb, *spb, *cfb;
    const void *bwt, *bbias, *bp_min, *bp_dr;
    u16 *Wbuf; float *biasbuf, *bwT, *bbT, *bpsT;
    int *flag;
};

__global__ __launch_bounds__(256) void prep_all_k(PrepArgs P) {
    __shared__ int s_isb;
    __shared__ u16 tile[64][68];
    if (threadIdx.x < 64) { int r = detect_isb(P.xnum); if ((threadIdx.x & 63) == 0) s_isb = r; }
    __syncthreads();
    const int isb = s_isb;
    const int tid = threadIdx.x;

    if (blockIdx.x < NB_TRANS) {
        const int Ks[6]   = {2048, 512, 256, 512, 256, 256};
        const int Nss[6]  = {512, 256, 512, 256, 256, 128};
        const int offs[6] = {WO_PROJ, WO_GW1, WO_GW2, WO_BW1, WO_BW2, WO_SW1};
        int bid = blockIdx.x, m = 0;
        #pragma unroll
        for (int i = 0; i < 6; ++i) {
            int nt = (Ks[i] >> 6) * (Nss[i] >> 6);
            if (bid >= nt && m == i) { bid -= nt; m = i + 1; }
        }
        const int K = Ks[m], N = Nss[m];
        const int ktiles = K >> 6;
        const int tn = bid / ktiles, tk = bid % ktiles;
        const int k0 = tk * 64, n0 = tn * 64;
        const void* src = P.src[m];
        u16* dst = P.Wbuf + offs[m];
        #pragma unroll
        for (int p = 0; p < 16; ++p) {
            int kk = p * 4 + (tid >> 6);
            int nn = tid & 63;
            tile[kk][nn] = cvtb(src, (size_t)(k0 + kk) * N + n0 + nn, isb);
        }
        __syncthreads();
        #pragma unroll
        for (int p = 0; p < 16; ++p) {
            int nn = p * 4 + (tid >> 6);
            int kk = tid & 63;
            dst[(size_t)(n0 + nn) * K + k0 + kk] = tile[kk][nn];
        }
        return;
    }

    const int bid = blockIdx.x - NB_TRANS;
    if (bid < NB_SPW) {                               // spW [128 n][320 k]
        size_t i = (size_t)bid * 256 + tid;
        int n = (int)(i / 320), k = (int)(i % 320);
        P.Wbuf[WO_SPW + i] =
            (n < 68 && k < 272) ? cvtb(P.spW, (size_t)k * 68 + n, isb) : (u16)0;
    } else if (bid < 2 * NB_SPW) {                    // cfW [128 n][320 k]
        size_t i = (size_t)(bid - NB_SPW) * 256 + tid;
        int n = (int)(i / 320), k = (int)(i % 320);
        P.Wbuf[WO_CFW + i] =
            (n < 69 && k < 278) ? cvtb(P.cfW, (size_t)k * 69 + n, isb) : (u16)0;
    } else if (bid < 2 * NB_SPW + 9) {                // biases
        int t = (bid - 2 * NB_SPW) * 256 + tid;
        float* out = P.biasbuf;
        if      (t < 512)  out[t] = ldf(P.pb, t, isb);
        else if (t < 768)  out[t] = ldf(P.g1, t - 512, isb);
        else if (t < 1280) out[t] = ldf(P.g2, t - 768, isb);
        else if (t < 1536) out[t] = ldf(P.b1, t - 1280, isb);
        else if (t < 1792) out[t] = ldf(P.b2, t - 1536, isb);
        else if (t < 1920) out[t] = ldf(P.sb, t - 1792, isb);
        else if (t < 2048) { int c = t - 1920; out[t] = (c < 68) ? ldf(P.spb, c, isb) : 0.f; }
        else if (t < 2176) { int c = t - 2048; out[t] = (c < 69) ? ldf(P.cfb, c, isb) : 0.f; }
    } else if (bid < 2 * NB_SPW + 9 + 72) {           // embT
        int t = (bid - 2 * NB_SPW - 9) * 256 + tid;
        if (t < 512 * 36) {
            int d = t / 36, j = t % 36;
            P.bwT[j * 512 + d] = ldf(P.bwt, t, isb);
        }
        if (t < 2048) {
            int d = t >> 2, e = t & 3;
            P.bbT[e * 512 + d] = ldf(P.bbias, t, isb);
        }
    } else {                                          // bps + flag
        int d = (bid - 2 * NB_SPW - 9 - 72) * 256 + tid;
        if (d < D_FEAT) {
            float bp = ldf(P.bp_min, d, isb);
            #pragma unroll
            for (int k = 0; k < NB_; ++k) {
                float x = ldf(P.bp_dr, d * NB_ + k, isb);
                bp += fmaxf(x, 0.f) + log1pf(expf(-fabsf(x)));
                P.bpsT[k * 512 + d] = bp;
            }
        }
        if (d == 0) *P.flag = isb;
    }
}

// ---------------- embedding (half-batch), 4 elements/thread ----------------
__global__ __launch_bounds__(256) void emb_k(
    const void* __restrict__ xnum, const float* __restrict__ bwT,
    const float* __restrict__ bbT, const float* __restrict__ bpsT,
    u16* __restrict__ emb, const int* __restrict__ flag, int rowoff)
{
    const int isb = *flag;
    size_t gi = ((size_t)blockIdx.x * 256 + threadIdx.x) * 4;
    int d0 = (int)(gi & 511);
    float xv[4];
    if (isb) {
        u16 tmp[4];
        *(uint2*)tmp = *(const uint2*)((const u16*)xnum + (size_t)rowoff * 512 + gi);
        #pragma unroll
        for (int i = 0; i < 4; ++i) xv[i] = b2f(tmp[i]);
    } else {
        float4 f = *(const float4*)((const float*)xnum + (size_t)rowoff * 512 + gi);
        xv[0] = f.x; xv[1] = f.y; xv[2] = f.z; xv[3] = f.w;
    }
    float acc[4][4];
    #pragma unroll
    for (int e = 0; e < 4; ++e) {
        float4 b = *(const float4*)&bbT[e * 512 + d0];
        acc[0][e] = b.x; acc[1][e] = b.y; acc[2][e] = b.z; acc[3][e] = b.w;
    }
    #pragma unroll
    for (int f = 0; f <= 8; ++f) {
        float bv[4];
        if (f == 0) {
            #pragma unroll
            for (int i = 0; i < 4; ++i) bv[i] = xv[i];
        } else {
            float4 bp = *(const float4*)&bpsT[(f - 1) * 512 + d0];
            bv[0] = fmaxf(xv[0] - bp.x, 0.f); bv[1] = fmaxf(xv[1] - bp.y, 0.f);
            bv[2] = fmaxf(xv[2] - bp.z, 0.f); bv[3] = fmaxf(xv[3] - bp.w, 0.f);
        }
        #pragma unroll
        for (int e = 0; e < 4; ++e) {
            float4 w = *(const float4*)&bwT[(f * 4 + e) * 512 + d0];
            acc[0][e] = fmaf(bv[0], w.x, acc[0][e]);
            acc[1][e] = fmaf(bv[1], w.y, acc[1][e]);
            acc[2][e] = fmaf(bv[2], w.z, acc[2][e]);
            acc[3][e] = fmaf(bv[3], w.w, acc[3][e]);
        }
    }
    u16 o[16];
    #pragma unroll
    for (int i = 0; i < 4; ++i)
        #pragma unroll
        for (int e = 0; e < 4; ++e) o[i * 4 + e] = f2b(acc[i][e]);
    *(uint4*)&emb[gi * 4]     = *(const uint4*)&o[0];
    *(uint4*)&emb[gi * 4 + 8] = *(const uint4*)&o[8];
}

// ---------------- bf16 MFMA GEMM: 64x64 tile, DMA dbuf, XOR swizzle ----------
template<int EMODE>
__global__ __launch_bounds__(256) void mgemm_k(
    const u16* __restrict__ A, const u16* __restrict__ Bt,
    const float* __restrict__ bias,
    void* __restrict__ out0, const void* __restrict__ aux0, void* __restrict__ aux1,
    int N, int Kdim, int lda, int ldk, int rowoff, const int* __restrict__ flagp)
{
    __shared__ __align__(16) u16 As[2][64][64];
    __shared__ __align__(16) u16 Bs[2][64][64];

    const int isb = (EMODE == 0) ? *flagp : 0;
    const int tid = threadIdx.x;
    const int row0 = blockIdx.x * 64, col0 = blockIdx.y * 64;
    const int w = tid >> 6, lane = tid & 63, q = lane >> 4, mr = lane & 15;
    const int wr = (w >> 1) * 32, wc = (w & 1) * 32;
    const int rr = lane >> 3, kg = lane & 7;
    const int sc = kg ^ (rr & 7);

    f32x4 acc[2][2];
    #pragma unroll
    for (int a = 0; a < 2; ++a)
        #pragma unroll
        for (int b = 0; b < 2; ++b) acc[a][b] = (f32x4){0.f, 0.f, 0.f, 0.f};

    const int T = Kdim >> 6;

    auto stage = [&](int kt, int bi) {
        if (w < 2) {
            #pragma unroll
            for (int j = 0; j < 4; ++j) {
                int m = w * 32 + j * 8;
                async_copy16(A + (size_t)(row0 + m + rr) * lda + kt + sc * 8,
                             &As[bi][m][0]);
            }
        } else {
            #pragma unroll
            for (int j = 0; j < 4; ++j) {
                int m = (w - 2) * 32 + j * 8;
                async_copy16(Bt + (size_t)(col0 + m + rr) * ldk + kt + sc * 8,
                             &Bs[bi][m][0]);
            }
        }
    };

    stage(0, 0);
    __syncthreads();

    for (int t = 0; t < T; ++t) {
        if (t + 1 < T) stage((t + 1) << 6, (t + 1) & 1);
        const int cb = t & 1;
        #pragma unroll
        for (int ks = 0; ks < 2; ++ks) {
            bf16x8 af[2], bf[2];
            #pragma unroll
            for (int rs = 0; rs < 2; ++rs) {
                int r = wr + rs * 16 + mr;
                int pc = (ks * 4 + q) ^ (r & 7);
                af[rs] = *(const bf16x8*)&As[cb][r][pc * 8];
            }
            #pragma unroll
            for (int nt = 0; nt < 2; ++nt) {
                int r = wc + nt * 16 + mr;
                int pc = (ks * 4 + q) ^ (r & 7);
                bf[nt] = *(const bf16x8*)&Bs[cb][r][pc * 8];
            }
            #pragma unroll
            for (int rs = 0; rs < 2; ++rs)
                #pragma unroll
                for (int nt = 0; nt < 2; ++nt)
                    acc[rs][nt] = __builtin_amdgcn_mfma_f32_16x16x32_bf16(
                        af[rs], bf[nt], acc[rs][nt], 0, 0, 0);
        }
        __syncthreads();
    }

    #pragma unroll
    for (int rs = 0; rs < 2; ++rs) {
        #pragma unroll
        for (int i = 0; i < 4; ++i) {
            size_t gr = (size_t)rowoff + row0 + wr + rs * 16 + q * 4 + i;
            #pragma unroll
            for (int nt = 0; nt < 2; ++nt) {
                int c = col0 + wc + nt * 16 + mr;
                float z = acc[rs][nt][i] + bias[c];
                size_t idx = gr * (size_t)N + c;
                if (EMODE == 0) {
                    ((u16*)out0)[idx] = f2b(ldf(aux0, idx, isb) + 0.1f * z);
                } else if (EMODE == 1) {
                    ((u16*)out0)[idx] = f2b(fmaxf(z, 0.f));
                } else {
                    float gv = 1.f / (1.f + expf(-z));
                    ((u16*)out0)[idx] = f2b(gv);
                    ((u16*)aux1)[idx] = f2b(b2f(((const u16*)aux0)[idx]) * gv);
                }
            }
        }
    }
}

// ---------------- fused pair GEMM (relu->bf16): safe (x<nx1) | spec ----------
__global__ __launch_bounds__(256) void mgemm_pair_k(
    const u16* __restrict__ A1, const u16* __restrict__ B1,
    const float* __restrict__ bias1, u16* __restrict__ out1,
    int K1, int lda1, int ldk1,
    const u16* __restrict__ A2, const u16* __restrict__ B2,
    const float* __restrict__ bias2, u16* __restrict__ out2,
    int K2, int lda2, int ldk2,
    int N, int nx1)
{
    __shared__ __align__(16) u16 As[2][64][64];
    __shared__ __align__(16) u16 Bs[2][64][64];

    const int tid = threadIdx.x;
    const bool sec = blockIdx.x >= nx1;
    const u16* A = sec ? A2 : A1;
    const u16* Bt = sec ? B2 : B1;
    const float* bias = sec ? bias2 : bias1;
    u16* out0 = sec ? out2 : out1;
    const int Kdim = sec ? K2 : K1;
    const int lda = sec ? lda2 : lda1;
    const int ldk = sec ? ldk2 : ldk1;
    const int row0 = (sec ? blockIdx.x - nx1 : blockIdx.x) * 64;
    const int col0 = blockIdx.y * 64;
    const int w = tid >> 6, lane = tid & 63, q = lane >> 4, mr = lane & 15;
    const int wr = (w >> 1) * 32, wc = (w & 1) * 32;
    const int rr = lane >> 3, kg = lane & 7;
    const int sc = kg ^ (rr & 7);

    f32x4 acc[2][2];
    #pragma unroll
    for (int a = 0; a < 2; ++a)
        #pragma unroll
        for (int b = 0; b < 2; ++b) acc[a][b] = (f32x4){0.f, 0.f, 0.f, 0.f};

    const int T = Kdim >> 6;

    auto stage = [&](int kt, int bi) {
        if (w < 2) {
            #pragma unroll
            for (int j = 0; j < 4; ++j) {
                int m = w * 32 + j * 8;
                async_copy16(A + (size_t)(row0 + m + rr) * lda + kt + sc * 8,
                             &As[bi][m][0]);
            }
        } else {
            #pragma unroll
            for (int j = 0; j < 4; ++j) {
                int m = (w - 2) * 32 + j * 8;
                async_copy16(Bt + (size_t)(col0 + m + rr) * ldk + kt + sc * 8,
                             &Bs[bi][m][0]);
            }
        }
    };

    stage(0, 0);
    __syncthreads();

    for (int t = 0; t < T; ++t) {
        if (t + 1 < T) stage((t + 1) << 6, (t + 1) & 1);
        const int cb = t & 1;
        #pragma unroll
        for (int ks = 0; ks < 2; ++ks) {
            bf16x8 af[2], bf[2];
            #pragma unroll
            for (int rs = 0; rs < 2; ++rs) {
                int r = wr + rs * 16 + mr;
                int pc = (ks * 4 + q) ^ (r & 7);
                af[rs] = *(const bf16x8*)&As[cb][r][pc * 8];
            }
            #pragma unroll
            for (int nt = 0; nt < 2; ++nt) {
                int r = wc + nt * 16 + mr;
                int pc = (ks * 4 + q) ^ (r & 7);
                bf[nt] = *(const bf16x8*)&Bs[cb][r][pc * 8];
            }
            #pragma unroll
            for (int rs = 0; rs < 2; ++rs)
                #pragma unroll
                for (int nt = 0; nt < 2; ++nt)
                    acc[rs][nt] = __builtin_amdgcn_mfma_f32_16x16x32_bf16(
                        af[rs], bf[nt], acc[rs][nt], 0, 0, 0);
        }
        __syncthreads();
    }

    #pragma unroll
    for (int rs = 0; rs < 2; ++rs) {
        #pragma unroll
        for (int i = 0; i < 4; ++i) {
            size_t gr = (size_t)row0 + wr + rs * 16 + q * 4 + i;
            #pragma unroll
            for (int nt = 0; nt < 2; ++nt) {
                int c = col0 + wc + nt * 16 + mr;
                float z = acc[rs][nt][i] + bias[c];
                out0[gr * (size_t)N + c] = f2b(fmaxf(z, 0.f));
            }
        }
    }
}

// ---------------- pre_k: integer-key top-8 + broadcast token MLP ----------------
struct PreArgs {
    const u16 *x_in, *g, *h;
    const void *base_W, *base_b;
    const void *safe_ln_g, *safe_ln_b;
    const void *top_W1, *top_b1, *top_W2, *top_b2;
    const void *spec_ln_g, *spec_ln_b;
    u16 *ln_a, *ln_b;
    float *scal;
    const int *flag;
};

__global__ __launch_bounds__(256, 4) void pre_k(PreArgs P) {
    __shared__ float w_base[256], w_slg[256], w_slb[256], w_t2[256];
    __shared__ float w_plg[272], w_plb[272];
    __shared__ float w_t1[16], w_tb1[16], w_tb2[16];
    const int isb = *P.flag;
    const int tid = threadIdx.x;
    const int wid = tid >> 6;
    const int lane = tid & 63;
    const int row = blockIdx.x * 4 + wid;

    w_base[tid] = ldf(P.base_W, tid, isb);
    w_slg[tid]  = ldf(P.safe_ln_g, tid, isb);
    w_slb[tid]  = ldf(P.safe_ln_b, tid, isb);
    w_t2[tid]   = ldf(P.top_W2, tid, isb);
    if (tid < 272) {
        w_plg[tid] = ldf(P.spec_ln_g, tid, isb);
        w_plb[tid] = ldf(P.spec_ln_b, tid, isb);
    }
    if (tid < 16) {
        w_t1[tid]  = ldf(P.top_W1, tid, isb);
        w_tb1[tid] = ldf(P.top_b1, tid, isb);
        w_tb2[tid] = ldf(P.top_b2, tid, isb);
    }
    __syncthreads();

    float hv[4], gv[8];
    u16 graw[8];
    #pragma unroll
    for (int i = 0; i < 4; ++i) hv[i] = b2f(P.h[(size_t)row * 256 + lane + 64 * i]);
    #pragma unroll
    for (int j = 0; j < 8; ++j) {
        graw[j] = P.g[(size_t)row * 512 + lane + 64 * j];
        gv[j] = b2f(graw[j]);
    }
    const float hsum = hv[0] + hv[1] + hv[2] + hv[3];

    float pb = 0.f;
    #pragma unroll
    for (int i = 0; i < 4; ++i) pb = fmaf(hv[i], w_base[lane + 64 * i], pb);
    const float yb = wred_sum(pb) + ldf(P.base_b, 0, isb);

    float s1 = 0.f, s2 = 0.f, mx = -1e30f;
    #pragma unroll
    for (int j = 0; j < 8; ++j) { s1 += gv[j]; s2 = fmaf(gv[j], gv[j], s2); mx = fmaxf(mx, gv[j]); }
    s1 = wred_sum(s1); s2 = wred_sum(s2); mx = wred_max(mx);
    const float gmean = s1 * (1.f / 512.f);
    const float gstd = sqrtf(fmaxf(s2 * (1.f / 512.f) - gmean * gmean, 0.f));

    const float hm = wred_sum(hsum) * (1.f / 256.f);
    float pv = 0.f;
    #pragma unroll
    for (int i = 0; i < 4; ++i) { float d = hv[i] - hm; pv = fmaf(d, d, pv); }
    const float hrstd = rsqrtf(wred_sum(pv) * (1.f / 256.f) + 1e-5f);
    #pragma unroll
    for (int i = 0; i < 4; ++i) {
        int k = lane + 64 * i;
        P.ln_a[(size_t)row * 320 + k] = f2b((hv[i] - hm) * hrstd * w_slg[k] + w_slb[k]);
    }

    // ---- integer-key top-8: key = (gbits<<9) | (511-idx).
    // g>0 => bit-compare == value-compare; low bits give asc-index tie-break.
    u32 keys[8];
    #pragma unroll
    for (int j = 0; j < 8; ++j)
        keys[j] = ((u32)graw[j] << 9) | (u32)(511 - (lane + 64 * j));

    float myv = 0.f, sumtv = 0.f; int myi = 0;
    for (int r8 = 0; r8 < 8; ++r8) {
        u32 a = umax2(umax2(umax2(keys[0], keys[1]), umax2(keys[2], keys[3])),
                      umax2(umax2(keys[4], keys[5]), umax2(keys[6], keys[7])));
        #pragma unroll
        for (int off = 32; off > 0; off >>= 1)
            a = umax2(a, (u32)__shfl_xor((int)a, off));
        const int widx = 511 - (int)(a & 511u);
        const float wval = b2f((u16)(a >> 9));
        sumtv += wval;
        if (lane == r8) { myv = wval; myi = widx; }
        if ((widx & 63) == lane) {
            int oj = widx >> 6;
            #pragma unroll
            for (int j = 0; j < 8; ++j) if (j == oj) keys[j] = 0;
        }
    }

    // ---- token MLP via broadcast: S[t] on lane t; z[t] from shfl(S, s) ----
    float xw = 0.f;
    if (lane < 8) {
        float xi = b2f(P.x_in[(size_t)row * 512 + myi]);
        xw = xi * (myv / (sumtv + 1e-6f));
    }
    const int tt = lane & 15;
    float Sv = 0.f;
    #pragma unroll
    for (int k = 0; k < 8; ++k) {
        float xwk = __shfl(xw, k);
        Sv += fmaxf(fmaf(xwk, w_t1[tt], w_tb1[tt]), 0.f);
    }
    float zacc = w_tb2[tt];
    #pragma unroll
    for (int s = 0; s < 16; ++s)
        zacc = fmaf(__shfl(Sv, s), w_t2[s * 16 + tt], zacc);
    const float ztl = zacc * 0.125f;   // z_top[lane&15], valid on every lane

    float ps = hsum + ((lane < 16) ? ztl : 0.f);
    const float sm = wred_sum(ps) * (1.f / 272.f);
    float pv2 = 0.f;
    #pragma unroll
    for (int i = 0; i < 4; ++i) { float d = hv[i] - sm; pv2 = fmaf(d, d, pv2); }
    if (lane < 16) { float d = ztl - sm; pv2 = fmaf(d, d, pv2); }
    const float srstd = rsqrtf(wred_sum(pv2) * (1.f / 272.f) + 1e-5f);
    #pragma unroll
    for (int i = 0; i < 4; ++i) {
        int k = lane + 64 * i;
        P.ln_b[(size_t)row * 320 + k] = f2b((hv[i] - sm) * srstd * w_plg[k] + w_plb[k]);
    }
    if (lane < 16) {
        int k = 256 + lane;
        P.ln_b[(size_t)row * 320 + k] = f2b((ztl - sm) * srstd * w_plg[k] + w_plb[k]);
    } else {
        P.ln_b[(size_t)row * 320 + 256 + lane] = 0;
    }

    float* sc = P.scal + (size_t)row * 32;
    if (lane < 16) sc[8 + lane] = ztl;
    if (lane == 0) { sc[0] = yb; sc[1] = gmean; sc[2] = mx; sc[3] = gstd; }
}

// ---------------- mid_k (unchanged) ----------------
struct MidArgs {
    const u16 *h;
    const float *scal_in;
    const u16 *sh, *sph;
    const void *safe_W2, *safe_b2, *spec_W2, *spec_b2;
    const void *conf_ln_g, *conf_ln_b;
    u16 *ln_c;
    float *scal;
    const int *flag;
};

__global__ __launch_bounds__(256, 4) void mid_k(MidArgs P) {
    __shared__ float w_clg[278], w_clb[278], w_sw2[128], w_spw2[68];
    const int isb = *P.flag;
    const int tid = threadIdx.x;
    const int wid = tid >> 6;
    const int lane = tid & 63;
    const int row = blockIdx.x * 4 + wid;

    if (tid < 278) { w_clg[tid] = ldf(P.conf_ln_g, tid, isb); w_clb[tid] = ldf(P.conf_ln_b, tid, isb); }
    if (tid < 128) w_sw2[tid]  = ldf(P.safe_W2, tid, isb);
    if (tid < 68)  w_spw2[tid] = ldf(P.spec_W2, tid, isb);
    __syncthreads();

    float s0 = b2f(P.sh[(size_t)row * 128 + lane]);
    float s1 = b2f(P.sh[(size_t)row * 128 + 64 + lane]);
    float psafe = s0 * w_sw2[lane] + s1 * w_sw2[64 + lane];
    const float dsafe = wred_sum(psafe) + ldf(P.safe_b2, 0, isb);

    float p0 = b2f(P.sph[(size_t)row * 128 + lane]) * ((lane < 68) ? w_spw2[lane] : 0.f);
    if (lane < 4) p0 += b2f(P.sph[(size_t)row * 128 + 64 + lane]) * w_spw2[64 + lane];
    const float dspec = wred_sum(p0) + ldf(P.spec_b2, 0, isb);

    const float* sc = P.scal_in + (size_t)row * 32;
    const float yb = sc[0], gmean = sc[1], mx = sc[2], gstd = sc[3];
    const float ztl = (lane < 16) ? sc[8 + lane] : 0.f;

    float hv[4];
    #pragma unroll
    for (int i = 0; i < 4; ++i) hv[i] = b2f(P.h[(size_t)row * 256 + lane + 64 * i]);
    const float hsum = hv[0] + hv[1] + hv[2] + hv[3];

    const float ads = fabsf(dsafe), adsp = fabsf(dspec);
    float pc = hsum + ((lane < 16) ? ztl : 0.f)
             + ((lane == 0) ? (yb + gmean + mx + gstd + ads + adsp) : 0.f);
    const float cm = wred_sum(pc) * (1.f / 278.f);
    float pv3 = 0.f;
    #pragma unroll
    for (int i = 0; i < 4; ++i) { float d = hv[i] - cm; pv3 = fmaf(d, d, pv3); }
    if (lane < 16) { float d = ztl - cm; pv3 = fmaf(d, d, pv3); }
    if (lane == 0) {
        float vals[6] = { yb, gmean, mx, gstd, ads, adsp };
        #pragma unroll
        for (int q = 0; q < 6; ++q) { float d = vals[q] - cm; pv3 = fmaf(d, d, pv3); }
    }
    const float crstd = rsqrtf(wred_sum(pv3) * (1.f / 278.f) + 1e-5f);

    u16* la = P.ln_c + (size_t)row * 320;
    #pragma unroll
    for (int i = 0; i < 4; ++i) {
        int k = lane + 64 * i;
        la[k] = f2b((hv[i] - cm) * crstd * w_clg[k] + w_clb[k]);
    }
    if (lane < 16) {
        int k = 260 + lane;
        la[k] = f2b((ztl - cm) * crstd * w_clg[k] + w_clb[k]);
    } else if (lane >= 18 && lane < 60) {
        la[260 + lane] = 0;
    }
    if (lane == 0) {
        float vals[6] = { yb, gmean, mx, gstd, ads, adsp };
        int idxs[6] = { 256, 257, 258, 259, 276, 277 };
        #pragma unroll
        for (int q = 0; q < 6; ++q) {
            int k = idxs[q];
            la[k] = f2b((vals[q] - cm) * crstd * w_clg[k] + w_clb[k]);
        }
        float* so = P.scal + (size_t)row * 32;
        so[4] = dsafe; so[5] = dspec;
    }
}

// ---------------- post_k ----------------
__global__ __launch_bounds__(256, 4) void post_k(
    const u16* __restrict__ ch, const float* __restrict__ scal,
    const void* __restrict__ conf_W2, const void* __restrict__ conf_b2,
    void* __restrict__ out, const int* __restrict__ flag)
{
    __shared__ float w_cw2[69];
    const int isb = *flag;
    const int tid = threadIdx.x;
    const int wid = tid >> 6;
    const int lane = tid & 63;
    const int row = blockIdx.x * 4 + wid;

    if (tid < 69) w_cw2[tid] = ldf(conf_W2, tid, isb);
    __syncthreads();

    float c0 = b2f(ch[(size_t)row * 128 + lane]) * ((lane < 69) ? w_cw2[lane] : 0.f);
    if (lane < 5) c0 += b2f(ch[(size_t)row * 128 + 64 + lane]) * w_cw2[64 + lane];
    const float zlin = wred_sum(c0) + ldf(conf_b2, 0, isb);
    const float gamma = 1.f / (1.f + expf(-zlin));
    if (lane == 0) {
        const float* sc = scal + (size_t)row * 32;
        float v = sc[0] + sc[4] + gamma * sc[5];
        if (isb) ((u16*)out)[row] = f2b(v);
        else     ((float*)out)[row] = v;
    }
}

extern "C" void kernel_launch(void* const* d_in, const int* in_sizes, int n_in,
                              void* d_out, int out_size, void* d_ws, size_t ws_size,
                              hipStream_t stream) {
    (void)in_sizes; (void)n_in; (void)out_size; (void)ws_size;
    const void* x_num = d_in[0];

    char* p = (char*)d_ws;
    auto alloc = [&](size_t bytes) { char* r = p; p += (bytes + 15) & ~(size_t)15; return r; };

    // total footprint ~127.2 MB (< 140.8 MB proven-safe)
    int*   flag    = (int*)alloc(16);
    float* bpsT    = (float*)alloc(8 * 512 * 4);
    float* bwT     = (float*)alloc(36 * 512 * 4);
    float* bbT     = (float*)alloc(4 * 512 * 4);
    float* biasbuf = (float*)alloc(2176 * 4);
    u16*   Wbuf    = (u16*)alloc((size_t)W_TOTAL * 2);
    u16*   ebuf    = (u16*)alloc((size_t)(B_ROWS / 2) * 2048 * 2);  // later g bf16
    u16*   x_in    = (u16*)alloc((size_t)B_ROWS * 512 * 2);
    u16*   hid1    = (u16*)alloc((size_t)B_ROWS * 256 * 2);         // later chh
    u16*   hbuf    = (u16*)alloc((size_t)B_ROWS * 256 * 2);
    u16*   ln_a    = (u16*)alloc((size_t)B_ROWS * 320 * 2);
    u16*   ln_b    = (u16*)alloc((size_t)B_ROWS * 320 * 2);
    float* scal    = (float*)alloc((size_t)B_ROWS * 32 * 4);
    u16*   sh      = (u16*)alloc((size_t)B_ROWS * 128 * 2);
    u16*   sph     = (u16*)alloc((size_t)B_ROWS * 128 * 2);
    u16*   xg      = (u16*)alloc((size_t)B_ROWS * 512 * 2);
    u16*   hid2    = (u16*)alloc((size_t)B_ROWS * 256 * 2);

    u16*   g   = ebuf;      // bf16, 16.8 MB <= ebuf's 33.5 MB
    u16*   chh = hid1;

    {
        PrepArgs pr;
        pr.xnum = x_num;
        pr.src[0] = d_in[5];  pr.src[1] = d_in[7];  pr.src[2] = d_in[9];
        pr.src[3] = d_in[11]; pr.src[4] = d_in[13]; pr.src[5] = d_in[19];
        pr.spW = d_in[29]; pr.cfW = d_in[35];
        pr.pb = d_in[6];  pr.g1 = d_in[8];  pr.g2 = d_in[10];
        pr.b1 = d_in[12]; pr.b2 = d_in[14]; pr.sb = d_in[20];
        pr.spb = d_in[30]; pr.cfb = d_in[36];
        pr.bwt = d_in[1]; pr.bbias = d_in[2];
        pr.bp_min = d_in[3]; pr.bp_dr = d_in[4];
        pr.Wbuf = Wbuf; pr.biasbuf = biasbuf;
        pr.bwT = bwT; pr.bbT = bbT; pr.bpsT = bpsT;
        pr.flag = flag;
        prep_all_k<<<NB_TRANS + 2 * NB_SPW + 9 + 72 + 2, 256, 0, stream>>>(pr);
    }

    const int HR = B_ROWS / 2;  // 8192
    for (int half = 0; half < 2; ++half) {
        int rowoff = half * HR;
        emb_k<<<(HR * D_FEAT / 4) / 256, 256, 0, stream>>>(
            x_num, bwT, bbT, bpsT, ebuf, flag, rowoff);
        mgemm_k<0><<<dim3(HR / 64, 8), 256, 0, stream>>>(
            ebuf, Wbuf + WO_PROJ, biasbuf + 0, x_in, x_num, nullptr,
            512, 2048, 2048, 2048, rowoff, flag);
    }

    mgemm_k<1><<<dim3(B_ROWS / 64, 4), 256, 0, stream>>>(
        x_in, Wbuf + WO_GW1, biasbuf + 512, hid1, nullptr, nullptr,
        256, 512, 512, 512, 0, flag);
    mgemm_k<2><<<dim3(B_ROWS / 64, 8), 256, 0, stream>>>(
        hid1, Wbuf + WO_GW2, biasbuf + 768, g, x_in, xg,
        512, 256, 256, 256, 0, flag);
    mgemm_k<1><<<dim3(B_ROWS / 64, 4), 256, 0, stream>>>(
        xg, Wbuf + WO_BW1, biasbuf + 1280, hid2, nullptr, nullptr,
        256, 512, 512, 512, 0, flag);
    mgemm_k<1><<<dim3(B_ROWS / 64, 4), 256, 0, stream>>>(
        hid2, Wbuf + WO_BW2, biasbuf + 1536, hbuf, nullptr, nullptr,
        256, 256, 256, 256, 0, flag);

    {
        PreArgs pa;
        pa.x_in = x_in; pa.g = g; pa.h = hbuf;
        pa.base_W = d_in[15]; pa.base_b = d_in[16];
        pa.safe_ln_g = d_in[17]; pa.safe_ln_b = d_in[18];
        pa.top_W1 = d_in[23]; pa.top_b1 = d_in[24];
        pa.top_W2 = d_in[25]; pa.top_b2 = d_in[26];
        pa.spec_ln_g = d_in[27]; pa.spec_ln_b = d_in[28];
        pa.ln_a = ln_a; pa.ln_b = ln_b; pa.scal = scal; pa.flag = flag;
        pre_k<<<B_ROWS / 4, 256, 0, stream>>>(pa);
    }

    // fused: sh = relu(ln_a[:, :256] @ safe_W1) | sph = relu(ln_b @ spec_W1p)
    mgemm_pair_k<<<dim3(2 * (B_ROWS / 64), 2), 256, 0, stream>>>(
        ln_a, Wbuf + WO_SW1, biasbuf + 1792, sh, 256, 320, 256,
        ln_b, Wbuf + WO_SPW, biasbuf + 1920, sph, 320, 320, 320,
        128, B_ROWS / 64);

    {
        MidArgs ma;
        ma.h = hbuf; ma.scal_in = scal; ma.sh = sh; ma.sph = sph;
        ma.safe_W2 = d_in[21]; ma.safe_b2 = d_in[22];
        ma.spec_W2 = d_in[31]; ma.spec_b2 = d_in[32];
        ma.conf_ln_g = d_in[33]; ma.conf_ln_b = d_in[34];
        ma.ln_c = ln_a; ma.scal = scal; ma.flag = flag;
        mid_k<<<B_ROWS / 4, 256, 0, stream>>>(ma);
    }

    mgemm_k<1><<<dim3(B_ROWS / 64, 2), 256, 0, stream>>>(
        ln_a, Wbuf + WO_CFW, biasbuf + 2048, chh, nullptr, nullptr,
        128, 320, 320, 320, 0, flag);

    post_k<<<B_ROWS / 4, 256, 0, stream>>>(chh, scal, d_in[37], d_in[38], d_out, flag);
}